// Round 1
// baseline (1225.842 us; speedup 1.0000x reference)
//
#include <hip/hip_runtime.h>
#include <hip/hip_bf16.h>

#define N_USER 150000
#define M_ITEM 30000
#define N_NODES 180000
#define D_FEAT 64
#define E2 1200000
#define BATCH 1024
#define AUX_W 10246
#define SCAN_BS 256
#define SCAN_EPB 2048
#define SCAN_NBLK 88   // ceil(180001/2048)

// ---------------- dtype detector: bf16 vs f32 float inputs ----------------
// Read user_rel (~N(0,0.1)) as bf16. If data is really f32, the low 16 bits of
// each float land in the bf16 exponent field -> ~half the values are huge.
__global__ void k_detect(const void* probe, int* flag) {
    int lane = threadIdx.x;
    float v = __bfloat162float(((const __hip_bfloat16*)probe)[lane]);
    bool big = !(fabsf(v) < 1000.0f);   // also catches NaN
    unsigned long long m = __ballot(big);
    if (lane == 0) *flag = (__popcll(m) > 8) ? 1 : 0;
}

// ---------------- batched float-input conversion to f32 ----------------
struct CvtSeg { const void* src; float* dst; int n; int blk0; };
struct CvtBatch { CvtSeg seg[16]; };

__global__ void __launch_bounds__(256) k_cvt_batch(CvtBatch cb, const int* flag) {
    int blk = blockIdx.x;
    int si = 0;
    #pragma unroll
    for (int i = 0; i < 16; ++i) if (blk >= cb.seg[i].blk0) si = i;
    const CvtSeg sg = cb.seg[si];
    int i = (blk - sg.blk0) * 256 + threadIdx.x;
    if (i >= sg.n) return;
    if (*flag) sg.dst[i] = ((const float*)sg.src)[i];
    else       sg.dst[i] = __bfloat162float(((const __hip_bfloat16*)sg.src)[i]);
}

// ---------------- CSR build ----------------
__global__ void __launch_bounds__(256) k_zero(int* p, int n) {
    int i = blockIdx.x * 256 + threadIdx.x;
    if (i < n) p[i] = 0;
}

__global__ void __launch_bounds__(256) k_hist(const int* __restrict__ row, int* __restrict__ cnt) {
    int i = blockIdx.x * 256 + threadIdx.x;
    if (i < E2) atomicAdd(&cnt[row[i]], 1);
}

__global__ void __launch_bounds__(SCAN_BS) k_scan_partial(const int* __restrict__ cnt, int* __restrict__ part, int n) {
    __shared__ int sd[SCAN_BS];
    int base = blockIdx.x * SCAN_EPB;
    int s = 0;
    #pragma unroll
    for (int j = 0; j < 8; ++j) {
        int idx = base + j * SCAN_BS + threadIdx.x;
        if (idx < n) s += cnt[idx];
    }
    sd[threadIdx.x] = s; __syncthreads();
    for (int off = SCAN_BS / 2; off; off >>= 1) {
        if (threadIdx.x < off) sd[threadIdx.x] += sd[threadIdx.x + off];
        __syncthreads();
    }
    if (threadIdx.x == 0) part[blockIdx.x] = sd[0];
}

__global__ void k_scan_part_ex(int* part) {
    if (threadIdx.x == 0) {
        int s = 0;
        for (int i = 0; i < SCAN_NBLK; ++i) { int v = part[i]; part[i] = s; s += v; }
    }
}

__global__ void __launch_bounds__(SCAN_BS) k_scan_final(const int* __restrict__ cnt, const int* __restrict__ part,
                                                        int* __restrict__ offs, int* __restrict__ cursor, int n) {
    __shared__ int sw[SCAN_BS];
    int base = blockIdx.x * SCAN_EPB + threadIdx.x * 8;
    int v[8];
    int s = 0;
    #pragma unroll
    for (int j = 0; j < 8; ++j) { int idx = base + j; v[j] = (idx < n) ? cnt[idx] : 0; }
    #pragma unroll
    for (int j = 0; j < 8; ++j) { int t = v[j]; v[j] = s; s += t; }  // exclusive within thread
    sw[threadIdx.x] = s; __syncthreads();
    for (int off = 1; off < SCAN_BS; off <<= 1) {
        int t = (threadIdx.x >= off) ? sw[threadIdx.x - off] : 0;
        __syncthreads();
        sw[threadIdx.x] += t;
        __syncthreads();
    }
    int toff = (threadIdx.x > 0 ? sw[threadIdx.x - 1] : 0) + part[blockIdx.x];
    #pragma unroll
    for (int j = 0; j < 8; ++j) {
        int idx = base + j;
        if (idx < n) {
            int val = v[j] + toff;
            offs[idx] = val;
            if (idx < N_NODES) cursor[idx] = val;
        }
    }
}

__global__ void __launch_bounds__(256) k_scatter(const int* __restrict__ row, const int* __restrict__ col,
                                                 const void* __restrict__ gval, int* __restrict__ cursor,
                                                 int2* __restrict__ pairs, const int* flag) {
    int i = blockIdx.x * 256 + threadIdx.x;
    if (i >= E2) return;
    float v;
    if (*flag) v = ((const float*)gval)[i];
    else       v = __bfloat162float(((const __hip_bfloat16*)gval)[i]);
    int r = row[i];
    int p = atomicAdd(&cursor[r], 1);
    pairs[p] = make_int2(col[i], __float_as_int(v));
}

// ---------------- SpMV: one wave per row, lane = feature ----------------
__global__ void __launch_bounds__(256) k_spmv(const float* __restrict__ src, float* __restrict__ dst,
                                              const int* __restrict__ offs, const int2* __restrict__ pairs) {
    int lane = threadIdx.x & 63;
    int wid = blockIdx.x * 4 + (threadIdx.x >> 6);
    if (wid >= N_NODES) return;
    int s = offs[wid], e = offs[wid + 1];
    float acc = 0.f;
    for (int j = s; j < e; ++j) {
        int2 p = pairs[j];
        acc += __int_as_float(p.y) * src[(size_t)p.x * 64 + lane];
    }
    dst[(size_t)wid * 64 + lane] = acc;
}

// ---------------- target-row accumulation (only 2048 rows of acc needed) ----
__global__ void __launch_bounds__(256) k_tacc(const float* __restrict__ emb, float* __restrict__ tacc,
                                              const int* __restrict__ uids, const int* __restrict__ iids,
                                              int zero_init) {
    int lane = threadIdx.x & 63;
    int t = blockIdx.x * 4 + (threadIdx.x >> 6);
    if (t >= 2048) return;
    int r = (t < BATCH) ? uids[t] : (N_USER + iids[t - BATCH]);
    float v = emb[(size_t)r * 64 + lane];
    if (zero_init) tacc[(size_t)t * 64 + lane] = v;
    else           tacc[(size_t)t * 64 + lane] += v;
}

// ---------------- X assembly: trivial gathers + light/4 ----------------
__global__ void __launch_bounds__(256) k_xsmall(const int* __restrict__ aux,
                                                const float* __restrict__ ratef, const float* __restrict__ genderf,
                                                const float* __restrict__ agef, const float* __restrict__ occf,
                                                const float* __restrict__ areaf, const float* __restrict__ tacc,
                                                float* __restrict__ X) {
    int lane = threadIdx.x & 63;
    int b = blockIdx.x * 4 + (threadIdx.x >> 6);
    if (b >= BATCH) return;
    const int* arow = aux + (size_t)b * AUX_W;
    float* xr = X + (size_t)b * 640;
    xr[0   + lane] = ratef[arow[0] * 64 + lane];
    xr[256 + lane] = genderf[arow[10242] * 64 + lane];
    xr[320 + lane] = agef[arow[10243] * 64 + lane];
    xr[384 + lane] = occf[arow[10244] * 64 + lane];
    xr[448 + lane] = areaf[arow[10245] * 64 + lane];
    xr[512 + lane] = tacc[(size_t)b * 64 + lane] * 0.25f;
    xr[576 + lane] = tacc[(size_t)(BATCH + b) * 64 + lane] * 0.25f;
}

// ---------------- multi-hot: x @ W / sum(x); one block per batch row --------
__global__ void __launch_bounds__(256) k_multihot(const int* __restrict__ aux, const float* __restrict__ Wf,
                                                  float* __restrict__ X, int K, int auxoff, int outcol) {
    int lane = threadIdx.x & 63, w = threadIdx.x >> 6, b = blockIdx.x;
    const int* xr = aux + (size_t)b * AUX_W + auxoff;
    int chunk = (K + 3) >> 2;
    int k0 = w * chunk, k1 = min(K, k0 + chunk);
    float acc = 0.f, cnt = 0.f;
    int k = k0;
    for (; k + 3 < k1; k += 4) {
        int x0 = xr[k], x1 = xr[k + 1], x2 = xr[k + 2], x3 = xr[k + 3];
        if (x0) { acc += (float)x0 * Wf[(size_t)(k    ) * 64 + lane]; cnt += (float)x0; }
        if (x1) { acc += (float)x1 * Wf[(size_t)(k + 1) * 64 + lane]; cnt += (float)x1; }
        if (x2) { acc += (float)x2 * Wf[(size_t)(k + 2) * 64 + lane]; cnt += (float)x2; }
        if (x3) { acc += (float)x3 * Wf[(size_t)(k + 3) * 64 + lane]; cnt += (float)x3; }
    }
    for (; k < k1; ++k) {
        int x = xr[k];
        if (x) { acc += (float)x * Wf[(size_t)k * 64 + lane]; cnt += (float)x; }
    }
    __shared__ float sacc[4][64];
    __shared__ float scnt[4];
    sacc[w][lane] = acc;
    if (lane == 0) scnt[w] = cnt;
    __syncthreads();
    if (w == 0) {
        float a = sacc[0][lane] + sacc[1][lane] + sacc[2][lane] + sacc[3][lane];
        float c = scnt[0] + scnt[1] + scnt[2] + scnt[3];
        X[(size_t)b * 640 + outcol + lane] = a / c;
    }
}

// ---------------- fused MLP: relu(relu(X@W1+b1)@W2+b2)@Wo+bo --------------
__global__ void __launch_bounds__(256) k_mlp(const float* __restrict__ X,
                                             const float* __restrict__ W1, const float* __restrict__ b1,
                                             const float* __restrict__ W2, const float* __restrict__ b2,
                                             const float* __restrict__ Wo, const float* __restrict__ bo,
                                             void* __restrict__ out, const int* flag) {
    int lane = threadIdx.x & 63, w = threadIdx.x >> 6;
    int b = blockIdx.x * 4 + w;
    const float* xr = X + (size_t)b * 640;
    float acc = b1[lane];
    #pragma unroll 8
    for (int k = 0; k < 640; ++k) acc += xr[k] * W1[(size_t)k * 64 + lane];
    float h1 = fmaxf(acc, 0.f);
    __shared__ float sh[4][64];
    sh[w][lane] = h1;
    __syncthreads();
    float acc2 = b2[lane];
    #pragma unroll 8
    for (int j = 0; j < 64; ++j) acc2 += sh[w][j] * W2[(size_t)j * 64 + lane];
    float h2 = fmaxf(acc2, 0.f);
    float p = h2 * Wo[lane];
    #pragma unroll
    for (int off = 32; off; off >>= 1) p += __shfl_down(p, off);
    if (lane == 0) {
        float r = p + bo[0];
        if (*flag) ((float*)out)[b] = r;
        else       ((__hip_bfloat16*)out)[b] = __float2bfloat16(r);
    }
}

extern "C" void kernel_launch(void* const* d_in, const int* in_sizes, int n_in,
                              void* d_out, int out_size, void* d_ws, size_t ws_size,
                              hipStream_t stream) {
    const int* aux  = (const int*)d_in[0];
    const int* uids = (const int*)d_in[1];
    const int* iids = (const int*)d_in[2];
    const int* grow = (const int*)d_in[3];
    const int* gcol = (const int*)d_in[4];
    const void* gval = d_in[5];

    // workspace carve-out (256B aligned)
    char* p = (char*)d_ws;
    auto alloc = [&](size_t bytes) -> char* {
        char* r = p;
        p += (bytes + 255) / 256 * 256;
        return r;
    };
    int*   flag   = (int*)alloc(4);
    int*   cnt    = (int*)alloc((size_t)180224 * 4);
    int*   offs   = (int*)alloc((size_t)180224 * 4);
    int*   cursor = (int*)alloc((size_t)180224 * 4);
    int*   part   = (int*)alloc(256 * 4);
    int2*  pairs  = (int2*)alloc((size_t)E2 * 8);
    float* embA   = (float*)alloc((size_t)N_NODES * 64 * 4);
    float* embB   = (float*)alloc((size_t)N_NODES * 64 * 4);
    float* tacc   = (float*)alloc((size_t)2048 * 64 * 4);
    float* X      = (float*)alloc((size_t)BATCH * 640 * 4);
    float* ratef   = (float*)alloc(384 * 4);
    float* genref  = (float*)alloc(1600 * 4);
    float* dirf    = (float*)alloc((size_t)139904 * 4);
    float* actf    = (float*)alloc((size_t)513920 * 4);
    float* genderf = (float*)alloc(128 * 4);
    float* agef    = (float*)alloc(448 * 4);
    float* occf    = (float*)alloc(1344 * 4);
    float* areaf   = (float*)alloc((size_t)217728 * 4);
    float* fc1W    = (float*)alloc((size_t)40960 * 4);
    float* fc1b    = (float*)alloc(64 * 4);
    float* fc2W    = (float*)alloc(4096 * 4);
    float* fc2b    = (float*)alloc(64 * 4);
    float* outW    = (float*)alloc(64 * 4);
    float* outb    = (float*)alloc(4);

    // 1. dtype detect (probe user_rel)
    hipLaunchKernelGGL(k_detect, dim3(1), dim3(64), 0, stream, d_in[14], flag);

    // 2. convert all float inputs to f32 (user_rel/item_rel straight into embA)
    CvtBatch cb;
    int blk = 0, si = 0;
    auto addseg = [&](const void* s, float* d, int n) {
        cb.seg[si].src = s; cb.seg[si].dst = d; cb.seg[si].n = n; cb.seg[si].blk0 = blk;
        blk += (n + 255) / 256; ++si;
    };
    addseg(d_in[6],  ratef,   384);
    addseg(d_in[7],  genref,  1600);
    addseg(d_in[8],  dirf,    139904);
    addseg(d_in[9],  actf,    513920);
    addseg(d_in[10], genderf, 128);
    addseg(d_in[11], agef,    448);
    addseg(d_in[12], occf,    1344);
    addseg(d_in[13], areaf,   217728);
    addseg(d_in[14], embA,                 N_USER * 64);
    addseg(d_in[15], embA + (size_t)N_USER * 64, M_ITEM * 64);
    addseg(d_in[16], fc1W,   40960);
    addseg(d_in[17], fc1b,   64);
    addseg(d_in[18], fc2W,   4096);
    addseg(d_in[19], fc2b,   64);
    addseg(d_in[20], outW,   64);
    addseg(d_in[21], outb,   1);
    hipLaunchKernelGGL(k_cvt_batch, dim3(blk), dim3(256), 0, stream, cb, flag);

    // 3. CSR build
    hipLaunchKernelGGL(k_zero, dim3((180224 + 255) / 256), dim3(256), 0, stream, cnt, 180224);
    hipLaunchKernelGGL(k_hist, dim3((E2 + 255) / 256), dim3(256), 0, stream, grow, cnt);
    hipLaunchKernelGGL(k_scan_partial, dim3(SCAN_NBLK), dim3(SCAN_BS), 0, stream, cnt, part, 180001);
    hipLaunchKernelGGL(k_scan_part_ex, dim3(1), dim3(64), 0, stream, part);
    hipLaunchKernelGGL(k_scan_final, dim3(SCAN_NBLK), dim3(SCAN_BS), 0, stream, cnt, part, offs, cursor, 180001);
    hipLaunchKernelGGL(k_scatter, dim3((E2 + 255) / 256), dim3(256), 0, stream, grow, gcol, gval, cursor, pairs, flag);

    // 4. LightGCN: tacc = emb0[targets]; 3 layers of SpMV, accumulating targets
    dim3 spmvGrid((N_NODES + 3) / 4), wg(256);
    dim3 taccGrid(2048 / 4);
    hipLaunchKernelGGL(k_tacc, taccGrid, wg, 0, stream, embA, tacc, uids, iids, 1);
    hipLaunchKernelGGL(k_spmv, spmvGrid, wg, 0, stream, embA, embB, offs, pairs);
    hipLaunchKernelGGL(k_tacc, taccGrid, wg, 0, stream, embB, tacc, uids, iids, 0);
    hipLaunchKernelGGL(k_spmv, spmvGrid, wg, 0, stream, embB, embA, offs, pairs);
    hipLaunchKernelGGL(k_tacc, taccGrid, wg, 0, stream, embA, tacc, uids, iids, 0);
    hipLaunchKernelGGL(k_spmv, spmvGrid, wg, 0, stream, embA, embB, offs, pairs);
    hipLaunchKernelGGL(k_tacc, taccGrid, wg, 0, stream, embB, tacc, uids, iids, 0);

    // 5. assemble X (1024 x 640)
    hipLaunchKernelGGL(k_xsmall, dim3(BATCH / 4), wg, 0, stream, aux, ratef, genderf, agef, occf, areaf, tacc, X);
    hipLaunchKernelGGL(k_multihot, dim3(BATCH), wg, 0, stream, aux, genref, X, 25,   1,    64);
    hipLaunchKernelGGL(k_multihot, dim3(BATCH), wg, 0, stream, aux, dirf,   X, 2186, 26,   128);
    hipLaunchKernelGGL(k_multihot, dim3(BATCH), wg, 0, stream, aux, actf,   X, 8030, 2212, 192);

    // 6. fused MLP -> out
    hipLaunchKernelGGL(k_mlp, dim3(BATCH / 4), wg, 0, stream, X, fc1W, fc1b, fc2W, fc2b, outW, outb, d_out, flag);
}

// Round 2
// 942.981 us; speedup vs baseline: 1.3000x; 1.3000x over previous
//
#include <hip/hip_runtime.h>
#include <hip/hip_bf16.h>

#define N_USER 150000
#define M_ITEM 30000
#define N_NODES 180000
#define D_FEAT 64
#define E2 1200000
#define BATCH 1024
#define AUX_W 10246
#define SCAN_BS 256
#define SCAN_EPB 2048
#define SCAN_NBLK 88   // ceil(180001/2048)
#define MH_R 8         // batch rows per block in k_mh
#define MH_WIN 2048    // k-window per block (4 waves x 512)

// ---------------- dtype detector: bf16 vs f32 float inputs ----------------
__global__ void k_detect(const void* probe, int* flag) {
    int lane = threadIdx.x;
    float v = __bfloat162float(((const __hip_bfloat16*)probe)[lane]);
    bool big = !(fabsf(v) < 1000.0f);   // also catches NaN
    unsigned long long m = __ballot(big);
    if (lane == 0) *flag = (__popcll(m) > 8) ? 1 : 0;
}

// ---------------- batched float-input conversion to f32 ----------------
struct CvtSeg { const void* src; float* dst; int n; int blk0; };
struct CvtBatch { CvtSeg seg[16]; };

__global__ void __launch_bounds__(256) k_cvt_batch(CvtBatch cb, const int* flag) {
    int blk = blockIdx.x;
    int si = 0;
    #pragma unroll
    for (int i = 0; i < 16; ++i) if (blk >= cb.seg[i].blk0) si = i;
    const CvtSeg sg = cb.seg[si];
    int i = (blk - sg.blk0) * 256 + threadIdx.x;
    if (i >= sg.n) return;
    if (*flag) sg.dst[i] = ((const float*)sg.src)[i];
    else       sg.dst[i] = __bfloat162float(((const __hip_bfloat16*)sg.src)[i]);
}

// ---------------- CSR build ----------------
__global__ void __launch_bounds__(256) k_zero(int* p, int n) {
    int i = blockIdx.x * 256 + threadIdx.x;
    if (i < n) p[i] = 0;
}

__global__ void __launch_bounds__(256) k_hist(const int* __restrict__ row, int* __restrict__ cnt) {
    int i = blockIdx.x * 256 + threadIdx.x;
    if (i < E2) atomicAdd(&cnt[row[i]], 1);
}

__global__ void __launch_bounds__(SCAN_BS) k_scan_partial(const int* __restrict__ cnt, int* __restrict__ part, int n) {
    __shared__ int sd[SCAN_BS];
    int base = blockIdx.x * SCAN_EPB;
    int s = 0;
    #pragma unroll
    for (int j = 0; j < 8; ++j) {
        int idx = base + j * SCAN_BS + threadIdx.x;
        if (idx < n) s += cnt[idx];
    }
    sd[threadIdx.x] = s; __syncthreads();
    for (int off = SCAN_BS / 2; off; off >>= 1) {
        if (threadIdx.x < off) sd[threadIdx.x] += sd[threadIdx.x + off];
        __syncthreads();
    }
    if (threadIdx.x == 0) part[blockIdx.x] = sd[0];
}

__global__ void k_scan_part_ex(int* part) {
    if (threadIdx.x == 0) {
        int s = 0;
        for (int i = 0; i < SCAN_NBLK; ++i) { int v = part[i]; part[i] = s; s += v; }
    }
}

__global__ void __launch_bounds__(SCAN_BS) k_scan_final(const int* __restrict__ cnt, const int* __restrict__ part,
                                                        int* __restrict__ offs, int* __restrict__ cursor, int n) {
    __shared__ int sw[SCAN_BS];
    int base = blockIdx.x * SCAN_EPB + threadIdx.x * 8;
    int v[8];
    int s = 0;
    #pragma unroll
    for (int j = 0; j < 8; ++j) { int idx = base + j; v[j] = (idx < n) ? cnt[idx] : 0; }
    #pragma unroll
    for (int j = 0; j < 8; ++j) { int t = v[j]; v[j] = s; s += t; }  // exclusive within thread
    sw[threadIdx.x] = s; __syncthreads();
    for (int off = 1; off < SCAN_BS; off <<= 1) {
        int t = (threadIdx.x >= off) ? sw[threadIdx.x - off] : 0;
        __syncthreads();
        sw[threadIdx.x] += t;
        __syncthreads();
    }
    int toff = (threadIdx.x > 0 ? sw[threadIdx.x - 1] : 0) + part[blockIdx.x];
    #pragma unroll
    for (int j = 0; j < 8; ++j) {
        int idx = base + j;
        if (idx < n) {
            int val = v[j] + toff;
            offs[idx] = val;
            if (idx < N_NODES) cursor[idx] = val;
        }
    }
}

__global__ void __launch_bounds__(256) k_scatter(const int* __restrict__ row, const int* __restrict__ col,
                                                 const void* __restrict__ gval, int* __restrict__ cursor,
                                                 int2* __restrict__ pairs, const int* flag) {
    int i = blockIdx.x * 256 + threadIdx.x;
    if (i >= E2) return;
    float v;
    if (*flag) v = ((const float*)gval)[i];
    else       v = __bfloat162float(((const __hip_bfloat16*)gval)[i]);
    int r = row[i];
    int p = atomicAdd(&cursor[r], 1);
    pairs[p] = make_int2(col[i], __float_as_int(v));
}

// ---------------- SpMV: one wave per row, lane = feature ----------------
__global__ void __launch_bounds__(256) k_spmv(const float* __restrict__ src, float* __restrict__ dst,
                                              const int* __restrict__ offs, const int2* __restrict__ pairs) {
    int lane = threadIdx.x & 63;
    int wid = blockIdx.x * 4 + (threadIdx.x >> 6);
    if (wid >= N_NODES) return;
    int s = offs[wid], e = offs[wid + 1];
    float acc = 0.f;
    for (int j = s; j < e; ++j) {
        int2 p = pairs[j];
        acc += __int_as_float(p.y) * src[(size_t)p.x * 64 + lane];
    }
    dst[(size_t)wid * 64 + lane] = acc;
}

// ---------------- target-row accumulation (only 2048 rows of acc needed) ----
__global__ void __launch_bounds__(256) k_tacc(const float* __restrict__ emb, float* __restrict__ tacc,
                                              const int* __restrict__ uids, const int* __restrict__ iids,
                                              int zero_init) {
    int lane = threadIdx.x & 63;
    int t = blockIdx.x * 4 + (threadIdx.x >> 6);
    if (t >= 2048) return;
    int r = (t < BATCH) ? uids[t] : (N_USER + iids[t - BATCH]);
    float v = emb[(size_t)r * 64 + lane];
    if (zero_init) tacc[(size_t)t * 64 + lane] = v;
    else           tacc[(size_t)t * 64 + lane] += v;
}

// ---------------- X assembly: trivial gathers + light/4 ----------------
__global__ void __launch_bounds__(256) k_xsmall(const int* __restrict__ aux,
                                                const float* __restrict__ ratef, const float* __restrict__ genderf,
                                                const float* __restrict__ agef, const float* __restrict__ occf,
                                                const float* __restrict__ areaf, const float* __restrict__ tacc,
                                                float* __restrict__ X) {
    int lane = threadIdx.x & 63;
    int b = blockIdx.x * 4 + (threadIdx.x >> 6);
    if (b >= BATCH) return;
    const int* arow = aux + (size_t)b * AUX_W;
    float* xr = X + (size_t)b * 640;
    xr[0   + lane] = ratef[arow[0] * 64 + lane];
    xr[256 + lane] = genderf[arow[10242] * 64 + lane];
    xr[320 + lane] = agef[arow[10243] * 64 + lane];
    xr[384 + lane] = occf[arow[10244] * 64 + lane];
    xr[448 + lane] = areaf[arow[10245] * 64 + lane];
    xr[512 + lane] = tacc[(size_t)b * 64 + lane] * 0.25f;
    xr[576 + lane] = tacc[(size_t)(BATCH + b) * 64 + lane] * 0.25f;
}

// ---------------- fused multi-hot: genre + director + actor in one launch ---
// x is binary (randint(0,2)). Per block: MH_R batch rows x one 2048-wide
// k-window; wave w handles a 512-wide k-slice for all MH_R rows.
// 64-k chunk: coalesced aux load per row -> __ballot mask (wave-uniform),
// iterate set bits of OR-mask, ONE W-row load shared by all rows.
// Partials atomically accumulated into contiguous Xmh[seg][1024][64] + counts.
__global__ void __launch_bounds__(256) k_mh(const int* __restrict__ aux,
                                            const float* __restrict__ Wg, const float* __restrict__ Wd,
                                            const float* __restrict__ Wa,
                                            float* __restrict__ Xmh, float* __restrict__ cntf) {
    int blk = blockIdx.x;
    int seg, grp, win, K, auxoff;
    const float* W;
    if (blk < 128)      { seg = 0; grp = blk;            win = 0;       K = 25;   auxoff = 1;    W = Wg; }
    else if (blk < 384) { seg = 1; int t = blk - 128; grp = t >> 1; win = t & 1; K = 2186; auxoff = 26;   W = Wd; }
    else                { seg = 2; int t = blk - 384; grp = t >> 2; win = t & 3; K = 8030; auxoff = 2212; W = Wa; }
    int lane = threadIdx.x & 63, w = threadIdx.x >> 6;
    int b0 = grp * MH_R;
    int k0 = win * MH_WIN + w * 512;
    int k1 = min(K, k0 + 512);
    if (k0 >= k1) return;

    float acc[MH_R];
    int csum[MH_R];
    #pragma unroll
    for (int r = 0; r < MH_R; ++r) { acc[r] = 0.f; csum[r] = 0; }

    for (int kb = k0; kb < k1; kb += 64) {
        unsigned long long m[MH_R], anym = 0ull;
        int kk = kb + lane;
        bool inb = (kk < k1);
        #pragma unroll
        for (int r = 0; r < MH_R; ++r) {
            int xv = inb ? aux[(size_t)(b0 + r) * AUX_W + auxoff + kk] : 0;
            m[r] = __ballot(xv != 0);
            anym |= m[r];
            csum[r] += __popcll(m[r]);
        }
        const float* Wk = W + (size_t)kb * 64;
        while (anym) {
            int j = __builtin_ctzll(anym);
            anym &= anym - 1ull;
            float wrow = Wk[(size_t)j * 64 + lane];
            #pragma unroll
            for (int r = 0; r < MH_R; ++r)
                if ((m[r] >> j) & 1ull) acc[r] += wrow;   // wave-uniform condition
        }
    }
    #pragma unroll
    for (int r = 0; r < MH_R; ++r) {
        atomicAdd(&Xmh[((size_t)seg * BATCH + b0 + r) * 64 + lane], acc[r]);
        if (lane == 0) atomicAdd(&cntf[seg * BATCH + b0 + r], (float)csum[r]);
    }
}

// normalize multihot sums -> X columns 64..255
__global__ void __launch_bounds__(256) k_norm(const float* __restrict__ Xmh, const float* __restrict__ cntf,
                                              float* __restrict__ X) {
    int lane = threadIdx.x & 63;
    int t = blockIdx.x * 4 + (threadIdx.x >> 6);   // t in [0, 3072)
    if (t >= 3 * BATCH) return;
    int seg = t >> 10, b = t & 1023;
    X[(size_t)b * 640 + 64 + seg * 64 + lane] = Xmh[(size_t)t * 64 + lane] / cntf[t];
}

// ---------------- fused MLP: relu(relu(X@W1+b1)@W2+b2)@Wo+bo --------------
__global__ void __launch_bounds__(256) k_mlp(const float* __restrict__ X,
                                             const float* __restrict__ W1, const float* __restrict__ b1,
                                             const float* __restrict__ W2, const float* __restrict__ b2,
                                             const float* __restrict__ Wo, const float* __restrict__ bo,
                                             void* __restrict__ out, const int* flag) {
    int lane = threadIdx.x & 63, w = threadIdx.x >> 6;
    int b = blockIdx.x * 4 + w;
    const float* xr = X + (size_t)b * 640;
    float acc = b1[lane];
    #pragma unroll 8
    for (int k = 0; k < 640; ++k) acc += xr[k] * W1[(size_t)k * 64 + lane];
    float h1 = fmaxf(acc, 0.f);
    __shared__ float sh[4][64];
    sh[w][lane] = h1;
    __syncthreads();
    float acc2 = b2[lane];
    #pragma unroll 8
    for (int j = 0; j < 64; ++j) acc2 += sh[w][j] * W2[(size_t)j * 64 + lane];
    float h2 = fmaxf(acc2, 0.f);
    float p = h2 * Wo[lane];
    #pragma unroll
    for (int off = 32; off; off >>= 1) p += __shfl_down(p, off);
    if (lane == 0) {
        float r = p + bo[0];
        if (*flag) ((float*)out)[b] = r;
        else       ((__hip_bfloat16*)out)[b] = __float2bfloat16(r);
    }
}

extern "C" void kernel_launch(void* const* d_in, const int* in_sizes, int n_in,
                              void* d_out, int out_size, void* d_ws, size_t ws_size,
                              hipStream_t stream) {
    const int* aux  = (const int*)d_in[0];
    const int* uids = (const int*)d_in[1];
    const int* iids = (const int*)d_in[2];
    const int* grow = (const int*)d_in[3];
    const int* gcol = (const int*)d_in[4];
    const void* gval = d_in[5];

    // workspace carve-out (256B aligned)
    char* p = (char*)d_ws;
    auto alloc = [&](size_t bytes) -> char* {
        char* r = p;
        p += (bytes + 255) / 256 * 256;
        return r;
    };
    int*   flag   = (int*)alloc(4);
    int*   cnt    = (int*)alloc((size_t)180224 * 4);
    int*   offs   = (int*)alloc((size_t)180224 * 4);
    int*   cursor = (int*)alloc((size_t)180224 * 4);
    int*   part   = (int*)alloc(256 * 4);
    int2*  pairs  = (int2*)alloc((size_t)E2 * 8);
    float* embA   = (float*)alloc((size_t)N_NODES * 64 * 4);
    float* embB   = (float*)alloc((size_t)N_NODES * 64 * 4);
    float* tacc   = (float*)alloc((size_t)2048 * 64 * 4);
    float* X      = (float*)alloc((size_t)BATCH * 640 * 4);
    float* Xmh    = (float*)alloc((size_t)3 * BATCH * 64 * 4);  // contiguous with cntf
    float* cntf   = (float*)alloc((size_t)3 * BATCH * 4);
    float* ratef   = (float*)alloc(384 * 4);
    float* genref  = (float*)alloc(1600 * 4);
    float* dirf    = (float*)alloc((size_t)139904 * 4);
    float* actf    = (float*)alloc((size_t)513920 * 4);
    float* genderf = (float*)alloc(128 * 4);
    float* agef    = (float*)alloc(448 * 4);
    float* occf    = (float*)alloc(1344 * 4);
    float* areaf   = (float*)alloc((size_t)217728 * 4);
    float* fc1W    = (float*)alloc((size_t)40960 * 4);
    float* fc1b    = (float*)alloc(64 * 4);
    float* fc2W    = (float*)alloc(4096 * 4);
    float* fc2b    = (float*)alloc(64 * 4);
    float* outW    = (float*)alloc(64 * 4);
    float* outb    = (float*)alloc(4);

    // 1. dtype detect (probe user_rel)
    hipLaunchKernelGGL(k_detect, dim3(1), dim3(64), 0, stream, d_in[14], flag);

    // 2. convert all float inputs to f32 (user_rel/item_rel straight into embA)
    CvtBatch cb;
    int blk = 0, si = 0;
    auto addseg = [&](const void* s, float* d, int n) {
        cb.seg[si].src = s; cb.seg[si].dst = d; cb.seg[si].n = n; cb.seg[si].blk0 = blk;
        blk += (n + 255) / 256; ++si;
    };
    addseg(d_in[6],  ratef,   384);
    addseg(d_in[7],  genref,  1600);
    addseg(d_in[8],  dirf,    139904);
    addseg(d_in[9],  actf,    513920);
    addseg(d_in[10], genderf, 128);
    addseg(d_in[11], agef,    448);
    addseg(d_in[12], occf,    1344);
    addseg(d_in[13], areaf,   217728);
    addseg(d_in[14], embA,                 N_USER * 64);
    addseg(d_in[15], embA + (size_t)N_USER * 64, M_ITEM * 64);
    addseg(d_in[16], fc1W,   40960);
    addseg(d_in[17], fc1b,   64);
    addseg(d_in[18], fc2W,   4096);
    addseg(d_in[19], fc2b,   64);
    addseg(d_in[20], outW,   64);
    addseg(d_in[21], outb,   1);
    hipLaunchKernelGGL(k_cvt_batch, dim3(blk), dim3(256), 0, stream, cb, flag);

    // 3. CSR build (+ zero multihot accumulators: Xmh and cntf are contiguous)
    hipLaunchKernelGGL(k_zero, dim3((180224 + 255) / 256), dim3(256), 0, stream, cnt, 180224);
    hipLaunchKernelGGL(k_zero, dim3((3 * BATCH * 64 + 3 * BATCH + 255) / 256), dim3(256), 0, stream,
                       (int*)Xmh, 3 * BATCH * 64 + 3 * BATCH);
    hipLaunchKernelGGL(k_hist, dim3((E2 + 255) / 256), dim3(256), 0, stream, grow, cnt);
    hipLaunchKernelGGL(k_scan_partial, dim3(SCAN_NBLK), dim3(SCAN_BS), 0, stream, cnt, part, 180001);
    hipLaunchKernelGGL(k_scan_part_ex, dim3(1), dim3(64), 0, stream, part);
    hipLaunchKernelGGL(k_scan_final, dim3(SCAN_NBLK), dim3(SCAN_BS), 0, stream, cnt, part, offs, cursor, 180001);
    hipLaunchKernelGGL(k_scatter, dim3((E2 + 255) / 256), dim3(256), 0, stream, grow, gcol, gval, cursor, pairs, flag);

    // 4. LightGCN: tacc = emb0[targets]; 3 layers of SpMV, accumulating targets
    dim3 spmvGrid((N_NODES + 3) / 4), wg(256);
    dim3 taccGrid(2048 / 4);
    hipLaunchKernelGGL(k_tacc, taccGrid, wg, 0, stream, embA, tacc, uids, iids, 1);
    hipLaunchKernelGGL(k_spmv, spmvGrid, wg, 0, stream, embA, embB, offs, pairs);
    hipLaunchKernelGGL(k_tacc, taccGrid, wg, 0, stream, embB, tacc, uids, iids, 0);
    hipLaunchKernelGGL(k_spmv, spmvGrid, wg, 0, stream, embB, embA, offs, pairs);
    hipLaunchKernelGGL(k_tacc, taccGrid, wg, 0, stream, embA, tacc, uids, iids, 0);
    hipLaunchKernelGGL(k_spmv, spmvGrid, wg, 0, stream, embA, embB, offs, pairs);
    hipLaunchKernelGGL(k_tacc, taccGrid, wg, 0, stream, embB, tacc, uids, iids, 0);

    // 5. assemble X (1024 x 640)
    hipLaunchKernelGGL(k_xsmall, dim3(BATCH / 4), wg, 0, stream, aux, ratef, genderf, agef, occf, areaf, tacc, X);
    hipLaunchKernelGGL(k_mh, dim3(896), wg, 0, stream, aux, genref, dirf, actf, Xmh, cntf);
    hipLaunchKernelGGL(k_norm, dim3((3 * BATCH + 3) / 4), wg, 0, stream, Xmh, cntf, X);

    // 6. fused MLP -> out
    hipLaunchKernelGGL(k_mlp, dim3(BATCH / 4), wg, 0, stream, X, fc1W, fc1b, fc2W, fc2b, outW, outb, d_out, flag);
}

// Round 3
// 771.873 us; speedup vs baseline: 1.5881x; 1.2217x over previous
//
#include <hip/hip_runtime.h>
#include <hip/hip_bf16.h>

#define N_USER 150000
#define M_ITEM 30000
#define N_NODES 180000
#define D_FEAT 64
#define E2 1200000
#define BATCH 1024
#define AUX_W 10246
#define SCAN_BS 256
#define SCAN_EPB 2048
#define SCAN_NBLK 88   // ceil(180001/2048)
#define KP_G 32        // genre K=25 padded to 32
#define KP_D 2208      // director K=2186 padded
#define KP_A 8064      // actor K=8030 padded

typedef __attribute__((ext_vector_type(8))) short short8;
typedef __attribute__((ext_vector_type(4))) float f32x4;

// ---------------- dtype detector: bf16 vs f32 float inputs ----------------
__global__ void k_detect(const void* probe, int* flag) {
    int lane = threadIdx.x;
    float v = __bfloat162float(((const __hip_bfloat16*)probe)[lane]);
    bool big = !(fabsf(v) < 1000.0f);   // also catches NaN
    unsigned long long m = __ballot(big);
    if (lane == 0) *flag = (__popcll(m) > 8) ? 1 : 0;
}

// ---------------- batched float-input conversion to f32 ----------------
struct CvtSeg { const void* src; float* dst; int n; int blk0; };
struct CvtBatch { CvtSeg seg[16]; };

__global__ void __launch_bounds__(256) k_cvt_batch(CvtBatch cb, const int* flag) {
    int blk = blockIdx.x;
    int si = 0;
    #pragma unroll
    for (int i = 0; i < 16; ++i) if (blk >= cb.seg[i].blk0) si = i;
    const CvtSeg sg = cb.seg[si];
    int i = (blk - sg.blk0) * 256 + threadIdx.x;
    if (i >= sg.n) return;
    if (*flag) sg.dst[i] = ((const float*)sg.src)[i];
    else       sg.dst[i] = __bfloat162float(((const __hip_bfloat16*)sg.src)[i]);
}

// ---------------- pack multihot W tables into B-fragment order ----------
// Element (k,n) -> Wt[((k>>5)*64 + n)*32 + ((k>>3)&3)*8 + (k&7)], zero pad k>=K.
__global__ void __launch_bounds__(256) k_wt(const void* Wg, const void* Wd, const void* Wa,
                                            unsigned short* WtG, unsigned short* WtD, unsigned short* WtA,
                                            const int* flag) {
    int t = blockIdx.x * 256 + threadIdx.x;
    if (t >= (KP_G + KP_D + KP_A) * 64) return;
    int kp = t >> 6, n = t & 63;
    int k, K; const void* src; unsigned short* dst;
    if (kp < KP_G)              { k = kp;                K = 25;   src = Wg; dst = WtG; }
    else if (kp < KP_G + KP_D)  { k = kp - KP_G;         K = 2186; src = Wd; dst = WtD; }
    else                        { k = kp - KP_G - KP_D;  K = 8030; src = Wa; dst = WtA; }
    unsigned short v = 0;
    if (k < K) {
        if (*flag) {
            __hip_bfloat16 h = __float2bfloat16(((const float*)src)[(size_t)k * 64 + n]);
            v = *(unsigned short*)&h;
        } else {
            v = ((const unsigned short*)src)[(size_t)k * 64 + n];
        }
    }
    dst[(((size_t)(k >> 5) * 64 + n) * 4 + ((k >> 3) & 3)) * 8 + (k & 7)] = v;
}

// ---------------- CSR build ----------------
__global__ void __launch_bounds__(256) k_zero(int* p, int n) {
    int i = blockIdx.x * 256 + threadIdx.x;
    if (i < n) p[i] = 0;
}

__global__ void __launch_bounds__(256) k_hist(const int* __restrict__ row, int* __restrict__ cnt) {
    int i = blockIdx.x * 256 + threadIdx.x;
    if (i < E2) atomicAdd(&cnt[row[i]], 1);
}

__global__ void __launch_bounds__(SCAN_BS) k_scan_partial(const int* __restrict__ cnt, int* __restrict__ part, int n) {
    __shared__ int sd[SCAN_BS];
    int base = blockIdx.x * SCAN_EPB;
    int s = 0;
    #pragma unroll
    for (int j = 0; j < 8; ++j) {
        int idx = base + j * SCAN_BS + threadIdx.x;
        if (idx < n) s += cnt[idx];
    }
    sd[threadIdx.x] = s; __syncthreads();
    for (int off = SCAN_BS / 2; off; off >>= 1) {
        if (threadIdx.x < off) sd[threadIdx.x] += sd[threadIdx.x + off];
        __syncthreads();
    }
    if (threadIdx.x == 0) part[blockIdx.x] = sd[0];
}

__global__ void k_scan_part_ex(int* part) {
    if (threadIdx.x == 0) {
        int s = 0;
        for (int i = 0; i < SCAN_NBLK; ++i) { int v = part[i]; part[i] = s; s += v; }
    }
}

__global__ void __launch_bounds__(SCAN_BS) k_scan_final(const int* __restrict__ cnt, const int* __restrict__ part,
                                                        int* __restrict__ offs, int* __restrict__ cursor, int n) {
    __shared__ int sw[SCAN_BS];
    int base = blockIdx.x * SCAN_EPB + threadIdx.x * 8;
    int v[8];
    int s = 0;
    #pragma unroll
    for (int j = 0; j < 8; ++j) { int idx = base + j; v[j] = (idx < n) ? cnt[idx] : 0; }
    #pragma unroll
    for (int j = 0; j < 8; ++j) { int t = v[j]; v[j] = s; s += t; }  // exclusive within thread
    sw[threadIdx.x] = s; __syncthreads();
    for (int off = 1; off < SCAN_BS; off <<= 1) {
        int t = (threadIdx.x >= off) ? sw[threadIdx.x - off] : 0;
        __syncthreads();
        sw[threadIdx.x] += t;
        __syncthreads();
    }
    int toff = (threadIdx.x > 0 ? sw[threadIdx.x - 1] : 0) + part[blockIdx.x];
    #pragma unroll
    for (int j = 0; j < 8; ++j) {
        int idx = base + j;
        if (idx < n) {
            int val = v[j] + toff;
            offs[idx] = val;
            if (idx < N_NODES) cursor[idx] = val;
        }
    }
}

__global__ void __launch_bounds__(256) k_scatter(const int* __restrict__ row, const int* __restrict__ col,
                                                 const void* __restrict__ gval, int* __restrict__ cursor,
                                                 int2* __restrict__ pairs, const int* flag) {
    int i = blockIdx.x * 256 + threadIdx.x;
    if (i >= E2) return;
    float v;
    if (*flag) v = ((const float*)gval)[i];
    else       v = __bfloat162float(((const __hip_bfloat16*)gval)[i]);
    int r = row[i];
    int p = atomicAdd(&cursor[r], 1);
    pairs[p] = make_int2(col[i], __float_as_int(v));
}

// ---------------- SpMV: one wave per row, lane = feature ----------------
__global__ void __launch_bounds__(256) k_spmv(const float* __restrict__ src, float* __restrict__ dst,
                                              const int* __restrict__ offs, const int2* __restrict__ pairs) {
    int lane = threadIdx.x & 63;
    int wid = blockIdx.x * 4 + (threadIdx.x >> 6);
    if (wid >= N_NODES) return;
    int s = offs[wid], e = offs[wid + 1];
    float acc = 0.f;
    for (int j = s; j < e; ++j) {
        int2 p = pairs[j];
        acc += __int_as_float(p.y) * src[(size_t)p.x * 64 + lane];
    }
    dst[(size_t)wid * 64 + lane] = acc;
}

// ---------------- target-row accumulation (only 2048 rows of acc needed) ----
__global__ void __launch_bounds__(256) k_tacc(const float* __restrict__ emb, float* __restrict__ tacc,
                                              const int* __restrict__ uids, const int* __restrict__ iids,
                                              int zero_init) {
    int lane = threadIdx.x & 63;
    int t = blockIdx.x * 4 + (threadIdx.x >> 6);
    if (t >= 2048) return;
    int r = (t < BATCH) ? uids[t] : (N_USER + iids[t - BATCH]);
    float v = emb[(size_t)r * 64 + lane];
    if (zero_init) tacc[(size_t)t * 64 + lane] = v;
    else           tacc[(size_t)t * 64 + lane] += v;
}

// ---------------- X assembly: trivial gathers + light/4 ----------------
__global__ void __launch_bounds__(256) k_xsmall(const int* __restrict__ aux,
                                                const float* __restrict__ ratef, const float* __restrict__ genderf,
                                                const float* __restrict__ agef, const float* __restrict__ occf,
                                                const float* __restrict__ areaf, const float* __restrict__ tacc,
                                                float* __restrict__ X) {
    int lane = threadIdx.x & 63;
    int b = blockIdx.x * 4 + (threadIdx.x >> 6);
    if (b >= BATCH) return;
    const int* arow = aux + (size_t)b * AUX_W;
    float* xr = X + (size_t)b * 640;
    xr[0   + lane] = ratef[arow[0] * 64 + lane];
    xr[256 + lane] = genderf[arow[10242] * 64 + lane];
    xr[320 + lane] = agef[arow[10243] * 64 + lane];
    xr[384 + lane] = occf[arow[10244] * 64 + lane];
    xr[448 + lane] = areaf[arow[10245] * 64 + lane];
    xr[512 + lane] = tacc[(size_t)b * 64 + lane] * 0.25f;
    xr[576 + lane] = tacc[(size_t)(BATCH + b) * 64 + lane] * 0.25f;
}

// ---------------- multihot as dense MFMA GEMM ----------------------------
// A = aux slice (binary ints) 1024 x K, B = Wt (bf16, frag-packed), C += A@B.
// Block: 64 rows x 64 cols, 4 waves (16 rows each), K-chunks of 512.
// Layouts (learn_hip m89/m120): A[m=lane&15][k=quad*8+j]; B[k=quad*8+j][n=lane&15];
// C: col=lane&15, row=quad*4+reg.
__global__ void __launch_bounds__(256) k_mhgemm(const int* __restrict__ aux,
                                                const unsigned short* __restrict__ WtG,
                                                const unsigned short* __restrict__ WtD,
                                                const unsigned short* __restrict__ WtA,
                                                float* __restrict__ Xmh, float* __restrict__ cntf) {
    int blk = blockIdx.x;
    int seg, rb, k0, klen, Kseg, auxoff;
    const unsigned short* Wt;
    if (blk < 16)      { seg = 0; rb = blk;                      k0 = 0;              klen = 25;                    Kseg = 25;   auxoff = 1;    Wt = WtG; }
    else if (blk < 96) { int t = blk - 16; seg = 1; rb = t & 15; k0 = (t >> 4) * 512; klen = min(512, 2186 - k0);   Kseg = 2186; auxoff = 26;   Wt = WtD; }
    else               { int t = blk - 96; seg = 2; rb = t & 15; k0 = (t >> 4) * 512; klen = min(512, 8030 - k0);   Kseg = 8030; auxoff = 2212; Wt = WtA; }
    int lane = threadIdx.x & 63, wave = threadIdx.x >> 6;
    int m = lane & 15, quad = lane >> 4;
    int row = rb * 64 + wave * 16 + m;
    const int* arow = aux + (size_t)row * AUX_W + auxoff;

    f32x4 acc0 = {0.f,0.f,0.f,0.f}, acc1 = acc0, acc2 = acc0, acc3 = acc0;
    float asum = 0.f;
    int nchunk = (klen + 31) >> 5;
    for (int kci = 0; kci < nchunk; ++kci) {
        int kb = k0 + kci * 32 + quad * 8;
        short8 af;
        if (kb + 8 <= Kseg) {
            #pragma unroll
            for (int j = 0; j < 8; ++j) {
                int x = arow[kb + j];
                af[j] = x ? (short)0x3F80 : (short)0;
                asum += (float)x;
            }
        } else {
            #pragma unroll
            for (int j = 0; j < 8; ++j) {
                int x = (kb + j < Kseg) ? arow[kb + j] : 0;
                af[j] = x ? (short)0x3F80 : (short)0;
                asum += (float)x;
            }
        }
        size_t kcg = (size_t)(k0 >> 5) + kci;
        const unsigned short* bp = Wt + ((kcg * 64 + m) * 4 + quad) * 8;
        short8 b0 = *(const short8*)(bp);
        short8 b1 = *(const short8*)(bp + 512);    // +16 cols * 4 quads * 8
        short8 b2 = *(const short8*)(bp + 1024);
        short8 b3 = *(const short8*)(bp + 1536);
        acc0 = __builtin_amdgcn_mfma_f32_16x16x32_bf16(af, b0, acc0, 0, 0, 0);
        acc1 = __builtin_amdgcn_mfma_f32_16x16x32_bf16(af, b1, acc1, 0, 0, 0);
        acc2 = __builtin_amdgcn_mfma_f32_16x16x32_bf16(af, b2, acc2, 0, 0, 0);
        acc3 = __builtin_amdgcn_mfma_f32_16x16x32_bf16(af, b3, acc3, 0, 0, 0);
    }
    // row counts: lane holds partial for row (m); reduce across quads
    asum += __shfl_xor(asum, 16);
    asum += __shfl_xor(asum, 32);
    if (quad == 0) atomicAdd(&cntf[seg * BATCH + row], asum);
    // C write: out_row = rb*64 + wave*16 + quad*4 + reg, col = nt*16 + m
    float* xbase = Xmh + ((size_t)seg * BATCH + rb * 64 + wave * 16 + quad * 4) * 64;
    #pragma unroll
    for (int reg = 0; reg < 4; ++reg) {
        float* xr = xbase + (size_t)reg * 64;
        atomicAdd(&xr[ 0 + m], acc0[reg]);
        atomicAdd(&xr[16 + m], acc1[reg]);
        atomicAdd(&xr[32 + m], acc2[reg]);
        atomicAdd(&xr[48 + m], acc3[reg]);
    }
}

// normalize multihot sums -> X columns 64..255
__global__ void __launch_bounds__(256) k_norm(const float* __restrict__ Xmh, const float* __restrict__ cntf,
                                              float* __restrict__ X) {
    int lane = threadIdx.x & 63;
    int t = blockIdx.x * 4 + (threadIdx.x >> 6);   // t in [0, 3072)
    if (t >= 3 * BATCH) return;
    int seg = t >> 10, b = t & 1023;
    X[(size_t)b * 640 + 64 + seg * 64 + lane] = Xmh[(size_t)t * 64 + lane] / cntf[t];
}

// ---------------- fused MLP: relu(relu(X@W1+b1)@W2+b2)@Wo+bo --------------
__global__ void __launch_bounds__(256) k_mlp(const float* __restrict__ X,
                                             const float* __restrict__ W1, const float* __restrict__ b1,
                                             const float* __restrict__ W2, const float* __restrict__ b2,
                                             const float* __restrict__ Wo, const float* __restrict__ bo,
                                             void* __restrict__ out, const int* flag) {
    int lane = threadIdx.x & 63, w = threadIdx.x >> 6;
    int b = blockIdx.x * 4 + w;
    const float* xr = X + (size_t)b * 640;
    float acc = b1[lane];
    #pragma unroll 8
    for (int k = 0; k < 640; ++k) acc += xr[k] * W1[(size_t)k * 64 + lane];
    float h1 = fmaxf(acc, 0.f);
    __shared__ float sh[4][64];
    sh[w][lane] = h1;
    __syncthreads();
    float acc2 = b2[lane];
    #pragma unroll 8
    for (int j = 0; j < 64; ++j) acc2 += sh[w][j] * W2[(size_t)j * 64 + lane];
    float h2 = fmaxf(acc2, 0.f);
    float p = h2 * Wo[lane];
    #pragma unroll
    for (int off = 32; off; off >>= 1) p += __shfl_down(p, off);
    if (lane == 0) {
        float r = p + bo[0];
        if (*flag) ((float*)out)[b] = r;
        else       ((__hip_bfloat16*)out)[b] = __float2bfloat16(r);
    }
}

extern "C" void kernel_launch(void* const* d_in, const int* in_sizes, int n_in,
                              void* d_out, int out_size, void* d_ws, size_t ws_size,
                              hipStream_t stream) {
    const int* aux  = (const int*)d_in[0];
    const int* uids = (const int*)d_in[1];
    const int* iids = (const int*)d_in[2];
    const int* grow = (const int*)d_in[3];
    const int* gcol = (const int*)d_in[4];
    const void* gval = d_in[5];

    // workspace carve-out (256B aligned)
    char* p = (char*)d_ws;
    auto alloc = [&](size_t bytes) -> char* {
        char* r = p;
        p += (bytes + 255) / 256 * 256;
        return r;
    };
    int*   flag   = (int*)alloc(4);
    int*   cnt    = (int*)alloc((size_t)180224 * 4);
    int*   offs   = (int*)alloc((size_t)180224 * 4);
    int*   cursor = (int*)alloc((size_t)180224 * 4);
    int*   part   = (int*)alloc(256 * 4);
    int2*  pairs  = (int2*)alloc((size_t)E2 * 8);
    float* embA   = (float*)alloc((size_t)N_NODES * 64 * 4);
    float* embB   = (float*)alloc((size_t)N_NODES * 64 * 4);
    float* tacc   = (float*)alloc((size_t)2048 * 64 * 4);
    float* X      = (float*)alloc((size_t)BATCH * 640 * 4);
    float* Xmh    = (float*)alloc((size_t)3 * BATCH * 64 * 4);  // contiguous with cntf
    float* cntf   = (float*)alloc((size_t)3 * BATCH * 4);
    unsigned short* WtG = (unsigned short*)alloc((size_t)KP_G * 64 * 2);
    unsigned short* WtD = (unsigned short*)alloc((size_t)KP_D * 64 * 2);
    unsigned short* WtA = (unsigned short*)alloc((size_t)KP_A * 64 * 2);
    float* ratef   = (float*)alloc(384 * 4);
    float* genderf = (float*)alloc(128 * 4);
    float* agef    = (float*)alloc(448 * 4);
    float* occf    = (float*)alloc(1344 * 4);
    float* areaf   = (float*)alloc((size_t)217728 * 4);
    float* fc1W    = (float*)alloc((size_t)40960 * 4);
    float* fc1b    = (float*)alloc(64 * 4);
    float* fc2W    = (float*)alloc(4096 * 4);
    float* fc2b    = (float*)alloc(64 * 4);
    float* outW    = (float*)alloc(64 * 4);
    float* outb    = (float*)alloc(4);

    // 1. dtype detect (probe user_rel)
    hipLaunchKernelGGL(k_detect, dim3(1), dim3(64), 0, stream, d_in[14], flag);

    // 2. convert float inputs to f32 (user_rel/item_rel straight into embA)
    CvtBatch cb;
    int blk = 0, si = 0;
    auto addseg = [&](const void* s, float* d, int n) {
        cb.seg[si].src = s; cb.seg[si].dst = d; cb.seg[si].n = n; cb.seg[si].blk0 = blk;
        blk += (n + 255) / 256; ++si;
    };
    addseg(d_in[6],  ratef,   384);
    addseg(d_in[10], genderf, 128);
    addseg(d_in[11], agef,    448);
    addseg(d_in[12], occf,    1344);
    addseg(d_in[13], areaf,   217728);
    addseg(d_in[14], embA,                 N_USER * 64);
    addseg(d_in[15], embA + (size_t)N_USER * 64, M_ITEM * 64);
    addseg(d_in[16], fc1W,   40960);
    addseg(d_in[17], fc1b,   64);
    addseg(d_in[18], fc2W,   4096);
    addseg(d_in[19], fc2b,   64);
    addseg(d_in[20], outW,   64);
    addseg(d_in[21], outb,   1);
    for (int i = si; i < 16; ++i) { cb.seg[i].src = nullptr; cb.seg[i].dst = nullptr; cb.seg[i].n = 0; cb.seg[i].blk0 = 0x7fffffff; }
    hipLaunchKernelGGL(k_cvt_batch, dim3(blk), dim3(256), 0, stream, cb, flag);

    // 2b. pack multihot W tables into B-fragment order (bf16)
    hipLaunchKernelGGL(k_wt, dim3(((KP_G + KP_D + KP_A) * 64 + 255) / 256), dim3(256), 0, stream,
                       d_in[7], d_in[8], d_in[9], WtG, WtD, WtA, flag);

    // 3. CSR build (+ zero multihot accumulators: Xmh and cntf are contiguous)
    hipLaunchKernelGGL(k_zero, dim3((180224 + 255) / 256), dim3(256), 0, stream, cnt, 180224);
    hipLaunchKernelGGL(k_zero, dim3((3 * BATCH * 64 + 3 * BATCH + 255) / 256), dim3(256), 0, stream,
                       (int*)Xmh, 3 * BATCH * 64 + 3 * BATCH);
    hipLaunchKernelGGL(k_hist, dim3((E2 + 255) / 256), dim3(256), 0, stream, grow, cnt);
    hipLaunchKernelGGL(k_scan_partial, dim3(SCAN_NBLK), dim3(SCAN_BS), 0, stream, cnt, part, 180001);
    hipLaunchKernelGGL(k_scan_part_ex, dim3(1), dim3(64), 0, stream, part);
    hipLaunchKernelGGL(k_scan_final, dim3(SCAN_NBLK), dim3(SCAN_BS), 0, stream, cnt, part, offs, cursor, 180001);
    hipLaunchKernelGGL(k_scatter, dim3((E2 + 255) / 256), dim3(256), 0, stream, grow, gcol, gval, cursor, pairs, flag);

    // 4. LightGCN: tacc = emb0[targets]; 3 layers of SpMV, accumulating targets
    dim3 spmvGrid((N_NODES + 3) / 4), wg(256);
    dim3 taccGrid(2048 / 4);
    hipLaunchKernelGGL(k_tacc, taccGrid, wg, 0, stream, embA, tacc, uids, iids, 1);
    hipLaunchKernelGGL(k_spmv, spmvGrid, wg, 0, stream, embA, embB, offs, pairs);
    hipLaunchKernelGGL(k_tacc, taccGrid, wg, 0, stream, embB, tacc, uids, iids, 0);
    hipLaunchKernelGGL(k_spmv, spmvGrid, wg, 0, stream, embB, embA, offs, pairs);
    hipLaunchKernelGGL(k_tacc, taccGrid, wg, 0, stream, embA, tacc, uids, iids, 0);
    hipLaunchKernelGGL(k_spmv, spmvGrid, wg, 0, stream, embA, embB, offs, pairs);
    hipLaunchKernelGGL(k_tacc, taccGrid, wg, 0, stream, embB, tacc, uids, iids, 0);

    // 5. assemble X (1024 x 640)
    hipLaunchKernelGGL(k_xsmall, dim3(BATCH / 4), wg, 0, stream, aux, ratef, genderf, agef, occf, areaf, tacc, X);
    hipLaunchKernelGGL(k_mhgemm, dim3(352), wg, 0, stream, aux, WtG, WtD, WtA, Xmh, cntf);
    hipLaunchKernelGGL(k_norm, dim3((3 * BATCH + 3) / 4), wg, 0, stream, Xmh, cntf, X);

    // 6. fused MLP -> out
    hipLaunchKernelGGL(k_mlp, dim3(BATCH / 4), wg, 0, stream, X, fc1W, fc1b, fc2W, fc2b, outW, outb, d_out, flag);
}

// Round 4
// 630.867 us; speedup vs baseline: 1.9431x; 1.2235x over previous
//
#include <hip/hip_runtime.h>
#include <hip/hip_bf16.h>

#define N_USER 150000
#define M_ITEM 30000
#define N_NODES 180000
#define D_FEAT 64
#define E2 1200000
#define BATCH 1024
#define AUX_W 10246
#define SCAN_BS 256
#define SCAN_EPB 2048
#define SCAN_NBLK 88   // ceil(180001/2048)
#define KP_G 32        // genre K=25 padded to 32
#define KP_D 2208      // director K=2186 padded
#define KP_A 8064      // actor K=8030 padded

typedef __attribute__((ext_vector_type(8))) short short8;
typedef __attribute__((ext_vector_type(4))) float f32x4;

// ---------------- dtype detector: bf16 vs f32 float inputs ----------------
__global__ void k_detect(const void* probe, int* flag) {
    int lane = threadIdx.x;
    float v = __bfloat162float(((const __hip_bfloat16*)probe)[lane]);
    bool big = !(fabsf(v) < 1000.0f);   // also catches NaN
    unsigned long long m = __ballot(big);
    if (lane == 0) *flag = (__popcll(m) > 8) ? 1 : 0;
}

// ---------------- batched float-input conversion to f32 ----------------
struct CvtSeg { const void* src; float* dst; int n; int blk0; };
struct CvtBatch { CvtSeg seg[16]; };

__global__ void __launch_bounds__(256) k_cvt_batch(CvtBatch cb, const int* flag) {
    int blk = blockIdx.x;
    int si = 0;
    #pragma unroll
    for (int i = 0; i < 16; ++i) if (blk >= cb.seg[i].blk0) si = i;
    const CvtSeg sg = cb.seg[si];
    int i = (blk - sg.blk0) * 256 + threadIdx.x;
    if (i >= sg.n) return;
    if (*flag) sg.dst[i] = ((const float*)sg.src)[i];
    else       sg.dst[i] = __bfloat162float(((const __hip_bfloat16*)sg.src)[i]);
}

// ---------------- pack multihot W tables into B-fragment order ----------
// Element (k,n) -> Wt[((k>>5)*64 + n)*32 + ((k>>3)&3)*8 + (k&7)], zero pad k>=K.
__global__ void __launch_bounds__(256) k_wt(const void* Wg, const void* Wd, const void* Wa,
                                            unsigned short* WtG, unsigned short* WtD, unsigned short* WtA,
                                            const int* flag) {
    int t = blockIdx.x * 256 + threadIdx.x;
    if (t >= (KP_G + KP_D + KP_A) * 64) return;
    int kp = t >> 6, n = t & 63;
    int k, K; const void* src; unsigned short* dst;
    if (kp < KP_G)              { k = kp;                K = 25;   src = Wg; dst = WtG; }
    else if (kp < KP_G + KP_D)  { k = kp - KP_G;         K = 2186; src = Wd; dst = WtD; }
    else                        { k = kp - KP_G - KP_D;  K = 8030; src = Wa; dst = WtA; }
    unsigned short v = 0;
    if (k < K) {
        if (*flag) {
            __hip_bfloat16 h = __float2bfloat16(((const float*)src)[(size_t)k * 64 + n]);
            v = *(unsigned short*)&h;
        } else {
            v = ((const unsigned short*)src)[(size_t)k * 64 + n];
        }
    }
    dst[(((size_t)(k >> 5) * 64 + n) * 4 + ((k >> 3) & 3)) * 8 + (k & 7)] = v;
}

// ---------------- CSR build ----------------
__global__ void __launch_bounds__(256) k_zero(int* p, int n) {
    int i = blockIdx.x * 256 + threadIdx.x;
    if (i < n) p[i] = 0;
}

__global__ void __launch_bounds__(256) k_hist(const int* __restrict__ row, int* __restrict__ cnt) {
    int i = blockIdx.x * 256 + threadIdx.x;
    if (i < E2) atomicAdd(&cnt[row[i]], 1);
}

__global__ void __launch_bounds__(SCAN_BS) k_scan_partial(const int* __restrict__ cnt, int* __restrict__ part, int n) {
    __shared__ int sd[SCAN_BS];
    int base = blockIdx.x * SCAN_EPB;
    int s = 0;
    #pragma unroll
    for (int j = 0; j < 8; ++j) {
        int idx = base + j * SCAN_BS + threadIdx.x;
        if (idx < n) s += cnt[idx];
    }
    sd[threadIdx.x] = s; __syncthreads();
    for (int off = SCAN_BS / 2; off; off >>= 1) {
        if (threadIdx.x < off) sd[threadIdx.x] += sd[threadIdx.x + off];
        __syncthreads();
    }
    if (threadIdx.x == 0) part[blockIdx.x] = sd[0];
}

__global__ void k_scan_part_ex(int* part) {
    if (threadIdx.x == 0) {
        int s = 0;
        for (int i = 0; i < SCAN_NBLK; ++i) { int v = part[i]; part[i] = s; s += v; }
    }
}

__global__ void __launch_bounds__(SCAN_BS) k_scan_final(const int* __restrict__ cnt, const int* __restrict__ part,
                                                        int* __restrict__ offs, int* __restrict__ cursor, int n) {
    __shared__ int sw[SCAN_BS];
    int base = blockIdx.x * SCAN_EPB + threadIdx.x * 8;
    int v[8];
    int s = 0;
    #pragma unroll
    for (int j = 0; j < 8; ++j) { int idx = base + j; v[j] = (idx < n) ? cnt[idx] : 0; }
    #pragma unroll
    for (int j = 0; j < 8; ++j) { int t = v[j]; v[j] = s; s += t; }  // exclusive within thread
    sw[threadIdx.x] = s; __syncthreads();
    for (int off = 1; off < SCAN_BS; off <<= 1) {
        int t = (threadIdx.x >= off) ? sw[threadIdx.x - off] : 0;
        __syncthreads();
        sw[threadIdx.x] += t;
        __syncthreads();
    }
    int toff = (threadIdx.x > 0 ? sw[threadIdx.x - 1] : 0) + part[blockIdx.x];
    #pragma unroll
    for (int j = 0; j < 8; ++j) {
        int idx = base + j;
        if (idx < n) {
            int val = v[j] + toff;
            offs[idx] = val;
            if (idx < N_NODES) cursor[idx] = val;
        }
    }
}

__global__ void __launch_bounds__(256) k_scatter(const int* __restrict__ row, const int* __restrict__ col,
                                                 const void* __restrict__ gval, int* __restrict__ cursor,
                                                 int2* __restrict__ pairs, const int* flag) {
    int i = blockIdx.x * 256 + threadIdx.x;
    if (i >= E2) return;
    float v;
    if (*flag) v = ((const float*)gval)[i];
    else       v = __bfloat162float(((const __hip_bfloat16*)gval)[i]);
    int r = row[i];
    int p = atomicAdd(&cursor[r], 1);
    pairs[p] = make_int2(col[i], __float_as_int(v));
}

// ---------------- SpMV: one wave per row, lane = feature -------------------
// Edges processed in chunks of 8 with clamped index / zeroed weight so the 8
// pair loads and 8 row gathers issue as independent vmem batches (MLP=8).
__global__ void __launch_bounds__(256) k_spmv(const float* __restrict__ src, float* __restrict__ dst,
                                              const int* __restrict__ offs, const int2* __restrict__ pairs) {
    int lane = threadIdx.x & 63;
    int wid = blockIdx.x * 4 + (threadIdx.x >> 6);
    if (wid >= N_NODES) return;
    int s = offs[wid], e = offs[wid + 1];
    float acc = 0.f;
    for (int j0 = s; j0 < e; j0 += 8) {
        int2 p[8];
        #pragma unroll
        for (int u = 0; u < 8; ++u) {
            int j = j0 + u;
            p[u] = pairs[min(j, e - 1)];
            if (j >= e) p[u].y = 0;          // zero weight for tail
        }
        float v[8];
        #pragma unroll
        for (int u = 0; u < 8; ++u)
            v[u] = src[(size_t)p[u].x * 64 + lane];
        #pragma unroll
        for (int u = 0; u < 8; ++u)
            acc += __int_as_float(p[u].y) * v[u];
    }
    dst[(size_t)wid * 64 + lane] = acc;
}

// ---------------- target-row accumulation (only 2048 rows of acc needed) ----
__global__ void __launch_bounds__(256) k_tacc(const float* __restrict__ emb, float* __restrict__ tacc,
                                              const int* __restrict__ uids, const int* __restrict__ iids,
                                              int zero_init) {
    int lane = threadIdx.x & 63;
    int t = blockIdx.x * 4 + (threadIdx.x >> 6);
    if (t >= 2048) return;
    int r = (t < BATCH) ? uids[t] : (N_USER + iids[t - BATCH]);
    float v = emb[(size_t)r * 64 + lane];
    if (zero_init) tacc[(size_t)t * 64 + lane] = v;
    else           tacc[(size_t)t * 64 + lane] += v;
}

// ---------------- X assembly: trivial gathers + light/4 ----------------
__global__ void __launch_bounds__(256) k_xsmall(const int* __restrict__ aux,
                                                const float* __restrict__ ratef, const float* __restrict__ genderf,
                                                const float* __restrict__ agef, const float* __restrict__ occf,
                                                const float* __restrict__ areaf, const float* __restrict__ tacc,
                                                float* __restrict__ X) {
    int lane = threadIdx.x & 63;
    int b = blockIdx.x * 4 + (threadIdx.x >> 6);
    if (b >= BATCH) return;
    const int* arow = aux + (size_t)b * AUX_W;
    float* xr = X + (size_t)b * 640;
    xr[0   + lane] = ratef[arow[0] * 64 + lane];
    xr[256 + lane] = genderf[arow[10242] * 64 + lane];
    xr[320 + lane] = agef[arow[10243] * 64 + lane];
    xr[384 + lane] = occf[arow[10244] * 64 + lane];
    xr[448 + lane] = areaf[arow[10245] * 64 + lane];
    xr[512 + lane] = tacc[(size_t)b * 64 + lane] * 0.25f;
    xr[576 + lane] = tacc[(size_t)(BATCH + b) * 64 + lane] * 0.25f;
}

// ---------------- multihot as dense MFMA GEMM ----------------------------
// A = aux slice (binary ints) 1024 x K, B = Wt (bf16, frag-packed), C += A@B.
// Block: 64 rows x 64 cols, 4 waves (16 rows each), K-chunks of 512.
// Layouts (learn_hip m89/m120): A[m=lane&15][k=quad*8+j]; B[k=quad*8+j][n=lane&15];
// C: col=lane&15, row=quad*4+reg.
__global__ void __launch_bounds__(256) k_mhgemm(const int* __restrict__ aux,
                                                const unsigned short* __restrict__ WtG,
                                                const unsigned short* __restrict__ WtD,
                                                const unsigned short* __restrict__ WtA,
                                                float* __restrict__ Xmh, float* __restrict__ cntf) {
    int blk = blockIdx.x;
    int seg, rb, k0, klen, Kseg, auxoff;
    const unsigned short* Wt;
    if (blk < 16)      { seg = 0; rb = blk;                      k0 = 0;              klen = 25;                    Kseg = 25;   auxoff = 1;    Wt = WtG; }
    else if (blk < 96) { int t = blk - 16; seg = 1; rb = t & 15; k0 = (t >> 4) * 512; klen = min(512, 2186 - k0);   Kseg = 2186; auxoff = 26;   Wt = WtD; }
    else               { int t = blk - 96; seg = 2; rb = t & 15; k0 = (t >> 4) * 512; klen = min(512, 8030 - k0);   Kseg = 8030; auxoff = 2212; Wt = WtA; }
    int lane = threadIdx.x & 63, wave = threadIdx.x >> 6;
    int m = lane & 15, quad = lane >> 4;
    int row = rb * 64 + wave * 16 + m;
    const int* arow = aux + (size_t)row * AUX_W + auxoff;

    f32x4 acc0 = {0.f,0.f,0.f,0.f}, acc1 = acc0, acc2 = acc0, acc3 = acc0;
    float asum = 0.f;
    int nchunk = (klen + 31) >> 5;
    for (int kci = 0; kci < nchunk; ++kci) {
        int kb = k0 + kci * 32 + quad * 8;
        short8 af;
        if (kb + 8 <= Kseg) {
            #pragma unroll
            for (int j = 0; j < 8; ++j) {
                int x = arow[kb + j];
                af[j] = x ? (short)0x3F80 : (short)0;
                asum += (float)x;
            }
        } else {
            #pragma unroll
            for (int j = 0; j < 8; ++j) {
                int x = (kb + j < Kseg) ? arow[kb + j] : 0;
                af[j] = x ? (short)0x3F80 : (short)0;
                asum += (float)x;
            }
        }
        size_t kcg = (size_t)(k0 >> 5) + kci;
        const unsigned short* bp = Wt + ((kcg * 64 + m) * 4 + quad) * 8;
        short8 b0 = *(const short8*)(bp);
        short8 b1 = *(const short8*)(bp + 512);    // +16 cols * 4 quads * 8
        short8 b2 = *(const short8*)(bp + 1024);
        short8 b3 = *(const short8*)(bp + 1536);
        acc0 = __builtin_amdgcn_mfma_f32_16x16x32_bf16(af, b0, acc0, 0, 0, 0);
        acc1 = __builtin_amdgcn_mfma_f32_16x16x32_bf16(af, b1, acc1, 0, 0, 0);
        acc2 = __builtin_amdgcn_mfma_f32_16x16x32_bf16(af, b2, acc2, 0, 0, 0);
        acc3 = __builtin_amdgcn_mfma_f32_16x16x32_bf16(af, b3, acc3, 0, 0, 0);
    }
    // row counts: lane holds partial for row (m); reduce across quads
    asum += __shfl_xor(asum, 16);
    asum += __shfl_xor(asum, 32);
    if (quad == 0) atomicAdd(&cntf[seg * BATCH + row], asum);
    // C write: out_row = rb*64 + wave*16 + quad*4 + reg, col = nt*16 + m
    float* xbase = Xmh + ((size_t)seg * BATCH + rb * 64 + wave * 16 + quad * 4) * 64;
    #pragma unroll
    for (int reg = 0; reg < 4; ++reg) {
        float* xr = xbase + (size_t)reg * 64;
        atomicAdd(&xr[ 0 + m], acc0[reg]);
        atomicAdd(&xr[16 + m], acc1[reg]);
        atomicAdd(&xr[32 + m], acc2[reg]);
        atomicAdd(&xr[48 + m], acc3[reg]);
    }
}

// normalize multihot sums -> X columns 64..255
__global__ void __launch_bounds__(256) k_norm(const float* __restrict__ Xmh, const float* __restrict__ cntf,
                                              float* __restrict__ X) {
    int lane = threadIdx.x & 63;
    int t = blockIdx.x * 4 + (threadIdx.x >> 6);   // t in [0, 3072)
    if (t >= 3 * BATCH) return;
    int seg = t >> 10, b = t & 1023;
    X[(size_t)b * 640 + 64 + seg * 64 + lane] = Xmh[(size_t)t * 64 + lane] / cntf[t];
}

// ---------------- fused MLP: relu(relu(X@W1+b1)@W2+b2)@Wo+bo --------------
__global__ void __launch_bounds__(256) k_mlp(const float* __restrict__ X,
                                             const float* __restrict__ W1, const float* __restrict__ b1,
                                             const float* __restrict__ W2, const float* __restrict__ b2,
                                             const float* __restrict__ Wo, const float* __restrict__ bo,
                                             void* __restrict__ out, const int* flag) {
    int lane = threadIdx.x & 63, w = threadIdx.x >> 6;
    int b = blockIdx.x * 4 + w;
    const float* xr = X + (size_t)b * 640;
    float acc = b1[lane];
    #pragma unroll 8
    for (int k = 0; k < 640; ++k) acc += xr[k] * W1[(size_t)k * 64 + lane];
    float h1 = fmaxf(acc, 0.f);
    __shared__ float sh[4][64];
    sh[w][lane] = h1;
    __syncthreads();
    float acc2 = b2[lane];
    #pragma unroll 8
    for (int j = 0; j < 64; ++j) acc2 += sh[w][j] * W2[(size_t)j * 64 + lane];
    float h2 = fmaxf(acc2, 0.f);
    float p = h2 * Wo[lane];
    #pragma unroll
    for (int off = 32; off; off >>= 1) p += __shfl_down(p, off);
    if (lane == 0) {
        float r = p + bo[0];
        if (*flag) ((float*)out)[b] = r;
        else       ((__hip_bfloat16*)out)[b] = __float2bfloat16(r);
    }
}

extern "C" void kernel_launch(void* const* d_in, const int* in_sizes, int n_in,
                              void* d_out, int out_size, void* d_ws, size_t ws_size,
                              hipStream_t stream) {
    const int* aux  = (const int*)d_in[0];
    const int* uids = (const int*)d_in[1];
    const int* iids = (const int*)d_in[2];
    const int* grow = (const int*)d_in[3];
    const int* gcol = (const int*)d_in[4];
    const void* gval = d_in[5];

    // workspace carve-out (256B aligned)
    char* p = (char*)d_ws;
    auto alloc = [&](size_t bytes) -> char* {
        char* r = p;
        p += (bytes + 255) / 256 * 256;
        return r;
    };
    int*   flag   = (int*)alloc(4);
    int*   cnt    = (int*)alloc((size_t)180224 * 4);
    int*   offs   = (int*)alloc((size_t)180224 * 4);
    int*   cursor = (int*)alloc((size_t)180224 * 4);
    int*   part   = (int*)alloc(256 * 4);
    int2*  pairs  = (int2*)alloc((size_t)E2 * 8);
    float* embA   = (float*)alloc((size_t)N_NODES * 64 * 4);
    float* embB   = (float*)alloc((size_t)N_NODES * 64 * 4);
    float* tacc   = (float*)alloc((size_t)2048 * 64 * 4);
    float* X      = (float*)alloc((size_t)BATCH * 640 * 4);
    float* Xmh    = (float*)alloc((size_t)3 * BATCH * 64 * 4);  // contiguous with cntf
    float* cntf   = (float*)alloc((size_t)3 * BATCH * 4);
    unsigned short* WtG = (unsigned short*)alloc((size_t)KP_G * 64 * 2);
    unsigned short* WtD = (unsigned short*)alloc((size_t)KP_D * 64 * 2);
    unsigned short* WtA = (unsigned short*)alloc((size_t)KP_A * 64 * 2);
    float* ratef   = (float*)alloc(384 * 4);
    float* genderf = (float*)alloc(128 * 4);
    float* agef    = (float*)alloc(448 * 4);
    float* occf    = (float*)alloc(1344 * 4);
    float* areaf   = (float*)alloc((size_t)217728 * 4);
    float* fc1W    = (float*)alloc((size_t)40960 * 4);
    float* fc1b    = (float*)alloc(64 * 4);
    float* fc2W    = (float*)alloc(4096 * 4);
    float* fc2b    = (float*)alloc(64 * 4);
    float* outW    = (float*)alloc(64 * 4);
    float* outb    = (float*)alloc(4);

    // 1. dtype detect (probe user_rel)
    hipLaunchKernelGGL(k_detect, dim3(1), dim3(64), 0, stream, d_in[14], flag);

    // 2. convert float inputs to f32 (user_rel/item_rel straight into embA)
    CvtBatch cb;
    int blk = 0, si = 0;
    auto addseg = [&](const void* s, float* d, int n) {
        cb.seg[si].src = s; cb.seg[si].dst = d; cb.seg[si].n = n; cb.seg[si].blk0 = blk;
        blk += (n + 255) / 256; ++si;
    };
    addseg(d_in[6],  ratef,   384);
    addseg(d_in[10], genderf, 128);
    addseg(d_in[11], agef,    448);
    addseg(d_in[12], occf,    1344);
    addseg(d_in[13], areaf,   217728);
    addseg(d_in[14], embA,                 N_USER * 64);
    addseg(d_in[15], embA + (size_t)N_USER * 64, M_ITEM * 64);
    addseg(d_in[16], fc1W,   40960);
    addseg(d_in[17], fc1b,   64);
    addseg(d_in[18], fc2W,   4096);
    addseg(d_in[19], fc2b,   64);
    addseg(d_in[20], outW,   64);
    addseg(d_in[21], outb,   1);
    for (int i = si; i < 16; ++i) { cb.seg[i].src = nullptr; cb.seg[i].dst = nullptr; cb.seg[i].n = 0; cb.seg[i].blk0 = 0x7fffffff; }
    hipLaunchKernelGGL(k_cvt_batch, dim3(blk), dim3(256), 0, stream, cb, flag);

    // 2b. pack multihot W tables into B-fragment order (bf16)
    hipLaunchKernelGGL(k_wt, dim3(((KP_G + KP_D + KP_A) * 64 + 255) / 256), dim3(256), 0, stream,
                       d_in[7], d_in[8], d_in[9], WtG, WtD, WtA, flag);

    // 3. CSR build (+ zero multihot accumulators: Xmh and cntf are contiguous)
    hipLaunchKernelGGL(k_zero, dim3((180224 + 255) / 256), dim3(256), 0, stream, cnt, 180224);
    hipLaunchKernelGGL(k_zero, dim3((3 * BATCH * 64 + 3 * BATCH + 255) / 256), dim3(256), 0, stream,
                       (int*)Xmh, 3 * BATCH * 64 + 3 * BATCH);
    hipLaunchKernelGGL(k_hist, dim3((E2 + 255) / 256), dim3(256), 0, stream, grow, cnt);
    hipLaunchKernelGGL(k_scan_partial, dim3(SCAN_NBLK), dim3(SCAN_BS), 0, stream, cnt, part, 180001);
    hipLaunchKernelGGL(k_scan_part_ex, dim3(1), dim3(64), 0, stream, part);
    hipLaunchKernelGGL(k_scan_final, dim3(SCAN_NBLK), dim3(SCAN_BS), 0, stream, cnt, part, offs, cursor, 180001);
    hipLaunchKernelGGL(k_scatter, dim3((E2 + 255) / 256), dim3(256), 0, stream, grow, gcol, gval, cursor, pairs, flag);

    // 4. LightGCN: tacc = emb0[targets]; 3 layers of SpMV, accumulating targets
    dim3 spmvGrid((N_NODES + 3) / 4), wg(256);
    dim3 taccGrid(2048 / 4);
    hipLaunchKernelGGL(k_tacc, taccGrid, wg, 0, stream, embA, tacc, uids, iids, 1);
    hipLaunchKernelGGL(k_spmv, spmvGrid, wg, 0, stream, embA, embB, offs, pairs);
    hipLaunchKernelGGL(k_tacc, taccGrid, wg, 0, stream, embB, tacc, uids, iids, 0);
    hipLaunchKernelGGL(k_spmv, spmvGrid, wg, 0, stream, embB, embA, offs, pairs);
    hipLaunchKernelGGL(k_tacc, taccGrid, wg, 0, stream, embA, tacc, uids, iids, 0);
    hipLaunchKernelGGL(k_spmv, spmvGrid, wg, 0, stream, embA, embB, offs, pairs);
    hipLaunchKernelGGL(k_tacc, taccGrid, wg, 0, stream, embB, tacc, uids, iids, 0);

    // 5. assemble X (1024 x 640)
    hipLaunchKernelGGL(k_xsmall, dim3(BATCH / 4), wg, 0, stream, aux, ratef, genderf, agef, occf, areaf, tacc, X);
    hipLaunchKernelGGL(k_mhgemm, dim3(352), wg, 0, stream, aux, WtG, WtD, WtA, Xmh, cntf);
    hipLaunchKernelGGL(k_norm, dim3((3 * BATCH + 3) / 4), wg, 0, stream, Xmh, cntf, X);

    // 6. fused MLP -> out
    hipLaunchKernelGGL(k_mlp, dim3(BATCH / 4), wg, 0, stream, X, fc1W, fc1b, fc2W, fc2b, outW, outb, d_out, flag);
}

// Round 5
// 503.779 us; speedup vs baseline: 2.4333x; 1.2523x over previous
//
#include <hip/hip_runtime.h>
#include <hip/hip_bf16.h>

#define N_USER 150000
#define M_ITEM 30000
#define N_NODES 180000
#define D_FEAT 64
#define E2 1200000
#define BATCH 1024
#define AUX_W 10246
#define SCAN_BS 256
#define SCAN_EPB 2048
#define SCAN_NBLK 88   // ceil(180001/2048)
#define KP_G 32        // genre K=25 padded to 32
#define KP_D 2208      // director K=2186 padded
#define KP_A 8064      // actor K=8030 padded

typedef __attribute__((ext_vector_type(8))) short short8;
typedef __attribute__((ext_vector_type(4))) float f32x4;

// ---------------- dtype detector: bf16 vs f32 float inputs ----------------
__global__ void k_detect(const void* probe, int* flag) {
    int lane = threadIdx.x;
    float v = __bfloat162float(((const __hip_bfloat16*)probe)[lane]);
    bool big = !(fabsf(v) < 1000.0f);   // also catches NaN
    unsigned long long m = __ballot(big);
    if (lane == 0) *flag = (__popcll(m) > 8) ? 1 : 0;
}

// ---------------- batched float-input conversion to f32 ----------------
struct CvtSeg { const void* src; float* dst; int n; int blk0; };
struct CvtBatch { CvtSeg seg[16]; };

__global__ void __launch_bounds__(256) k_cvt_batch(CvtBatch cb, const int* flag) {
    int blk = blockIdx.x;
    int si = 0;
    #pragma unroll
    for (int i = 0; i < 16; ++i) if (blk >= cb.seg[i].blk0) si = i;
    const CvtSeg sg = cb.seg[si];
    int i = (blk - sg.blk0) * 256 + threadIdx.x;
    if (i >= sg.n) return;
    if (*flag) sg.dst[i] = ((const float*)sg.src)[i];
    else       sg.dst[i] = __bfloat162float(((const __hip_bfloat16*)sg.src)[i]);
}

// ---------------- pack multihot W tables into B-fragment order ----------
// Element (k,n) -> Wt[((k>>5)*64 + n)*32 + ((k>>3)&3)*8 + (k&7)], zero pad k>=K.
__global__ void __launch_bounds__(256) k_wt(const void* Wg, const void* Wd, const void* Wa,
                                            unsigned short* WtG, unsigned short* WtD, unsigned short* WtA,
                                            const int* flag) {
    int t = blockIdx.x * 256 + threadIdx.x;
    if (t >= (KP_G + KP_D + KP_A) * 64) return;
    int kp = t >> 6, n = t & 63;
    int k, K; const void* src; unsigned short* dst;
    if (kp < KP_G)              { k = kp;                K = 25;   src = Wg; dst = WtG; }
    else if (kp < KP_G + KP_D)  { k = kp - KP_G;         K = 2186; src = Wd; dst = WtD; }
    else                        { k = kp - KP_G - KP_D;  K = 8030; src = Wa; dst = WtA; }
    unsigned short v = 0;
    if (k < K) {
        if (*flag) {
            __hip_bfloat16 h = __float2bfloat16(((const float*)src)[(size_t)k * 64 + n]);
            v = *(unsigned short*)&h;
        } else {
            v = ((const unsigned short*)src)[(size_t)k * 64 + n];
        }
    }
    dst[(((size_t)(k >> 5) * 64 + n) * 4 + ((k >> 3) & 3)) * 8 + (k & 7)] = v;
}

// ---------------- CSR build ----------------
__global__ void __launch_bounds__(256) k_zero(int* p, int n) {
    int i = blockIdx.x * 256 + threadIdx.x;
    if (i < n) p[i] = 0;
}

__global__ void __launch_bounds__(256) k_hist(const int* __restrict__ row, int* __restrict__ cnt) {
    int i = blockIdx.x * 256 + threadIdx.x;
    if (i < E2) atomicAdd(&cnt[row[i]], 1);
}

__global__ void __launch_bounds__(SCAN_BS) k_scan_partial(const int* __restrict__ cnt, int* __restrict__ part, int n) {
    __shared__ int sd[SCAN_BS];
    int base = blockIdx.x * SCAN_EPB;
    int s = 0;
    #pragma unroll
    for (int j = 0; j < 8; ++j) {
        int idx = base + j * SCAN_BS + threadIdx.x;
        if (idx < n) s += cnt[idx];
    }
    sd[threadIdx.x] = s; __syncthreads();
    for (int off = SCAN_BS / 2; off; off >>= 1) {
        if (threadIdx.x < off) sd[threadIdx.x] += sd[threadIdx.x + off];
        __syncthreads();
    }
    if (threadIdx.x == 0) part[blockIdx.x] = sd[0];
}

__global__ void k_scan_part_ex(int* part) {
    if (threadIdx.x == 0) {
        int s = 0;
        for (int i = 0; i < SCAN_NBLK; ++i) { int v = part[i]; part[i] = s; s += v; }
    }
}

__global__ void __launch_bounds__(SCAN_BS) k_scan_final(const int* __restrict__ cnt, const int* __restrict__ part,
                                                        int* __restrict__ offs, int* __restrict__ cursor, int n) {
    __shared__ int sw[SCAN_BS];
    int base = blockIdx.x * SCAN_EPB + threadIdx.x * 8;
    int v[8];
    int s = 0;
    #pragma unroll
    for (int j = 0; j < 8; ++j) { int idx = base + j; v[j] = (idx < n) ? cnt[idx] : 0; }
    #pragma unroll
    for (int j = 0; j < 8; ++j) { int t = v[j]; v[j] = s; s += t; }  // exclusive within thread
    sw[threadIdx.x] = s; __syncthreads();
    for (int off = 1; off < SCAN_BS; off <<= 1) {
        int t = (threadIdx.x >= off) ? sw[threadIdx.x - off] : 0;
        __syncthreads();
        sw[threadIdx.x] += t;
        __syncthreads();
    }
    int toff = (threadIdx.x > 0 ? sw[threadIdx.x - 1] : 0) + part[blockIdx.x];
    #pragma unroll
    for (int j = 0; j < 8; ++j) {
        int idx = base + j;
        if (idx < n) {
            int val = v[j] + toff;
            offs[idx] = val;
            if (idx < N_NODES) cursor[idx] = val;
        }
    }
}

// pairs store (col*256, weight): col pre-scaled to a byte offset into a
// 64-float row so the SpMV gather address is base + p.x + lane*4.
__global__ void __launch_bounds__(256) k_scatter(const int* __restrict__ row, const int* __restrict__ col,
                                                 const void* __restrict__ gval, int* __restrict__ cursor,
                                                 int2* __restrict__ pairs, const int* flag) {
    int i = blockIdx.x * 256 + threadIdx.x;
    if (i >= E2) return;
    float v;
    if (*flag) v = ((const float*)gval)[i];
    else       v = __bfloat162float(((const __hip_bfloat16*)gval)[i]);
    int r = row[i];
    int p = atomicAdd(&cursor[r], 1);
    pairs[p] = make_int2(col[i] << 8, __float_as_int(v));
}

// ---------------- mark bitmap: rows needed in layer 2 = T  ∪ N(T) ----------
__global__ void __launch_bounds__(256) k_mark(const int* __restrict__ offs, const int2* __restrict__ pairs,
                                              const int* __restrict__ uids, const int* __restrict__ iids,
                                              int* __restrict__ mark) {
    int lane = threadIdx.x & 63;
    int t = blockIdx.x * 4 + (threadIdx.x >> 6);
    if (t >= 2048) return;
    int r = (t < BATCH) ? uids[t] : (N_USER + iids[t - BATCH]);
    if (lane == 0) mark[r] = 1;                       // racing stores of 1 are fine
    int s = offs[r], e = offs[r + 1];
    for (int j = s + lane; j < e; j += 64) mark[(unsigned)pairs[j].x >> 8] = 1;
}

// ---------------- SpMV: one wave per row, lane = feature -------------------
// launch_bounds(256,4): cap 4 blocks/CU so the VGPR budget (~128) keeps all
// 8 gathers + 8 pairs in flight (R4's VGPR=32 serialized them).
// mark != null: compute only marked rows (early-exit otherwise).
__global__ void __launch_bounds__(256, 4) k_spmv(const float* __restrict__ src, float* __restrict__ dst,
                                                 const int* __restrict__ offs, const int2* __restrict__ pairs,
                                                 const int* __restrict__ mark) {
    int lane = threadIdx.x & 63;
    int wid = blockIdx.x * 4 + (threadIdx.x >> 6);
    if (wid >= N_NODES) return;
    if (mark && mark[wid] == 0) return;
    int s = offs[wid], e = offs[wid + 1];
    const char* sb = (const char*)src + (lane << 2);
    float acc = 0.f;
    int j0 = s;
    for (; j0 + 8 <= e; j0 += 8) {          // main: no clamp, 8 outstanding
        int2 p[8];
        #pragma unroll
        for (int u = 0; u < 8; ++u) p[u] = pairs[j0 + u];
        float v[8];
        #pragma unroll
        for (int u = 0; u < 8; ++u) v[u] = *(const float*)(sb + (size_t)(unsigned)p[u].x);
        #pragma unroll
        for (int u = 0; u < 8; ++u) acc = fmaf(__int_as_float(p[u].y), v[u], acc);
    }
    if (j0 < e) {                           // tail <8 edges, clamped
        int2 p[8];
        float v[8];
        #pragma unroll
        for (int u = 0; u < 8; ++u) {
            int j = j0 + u;
            p[u] = pairs[min(j, e - 1)];
            if (j >= e) p[u].y = 0;
        }
        #pragma unroll
        for (int u = 0; u < 8; ++u) v[u] = *(const float*)(sb + (size_t)(unsigned)p[u].x);
        #pragma unroll
        for (int u = 0; u < 8; ++u) acc = fmaf(__int_as_float(p[u].y), v[u], acc);
    }
    dst[(size_t)wid * 64 + lane] = acc;
}

// ---------------- layer-3 SpMV fused with target accumulation --------------
// Only the 2048 target rows of emb3 are ever read -> compute exactly those,
// accumulating straight into tacc.
__global__ void __launch_bounds__(256, 4) k_spmv3(const float* __restrict__ src, float* __restrict__ tacc,
                                                  const int* __restrict__ offs, const int2* __restrict__ pairs,
                                                  const int* __restrict__ uids, const int* __restrict__ iids) {
    int lane = threadIdx.x & 63;
    int t = blockIdx.x * 4 + (threadIdx.x >> 6);
    if (t >= 2048) return;
    int r = (t < BATCH) ? uids[t] : (N_USER + iids[t - BATCH]);
    int s = offs[r], e = offs[r + 1];
    const char* sb = (const char*)src + (lane << 2);
    float acc = 0.f;
    int j0 = s;
    for (; j0 + 8 <= e; j0 += 8) {
        int2 p[8];
        #pragma unroll
        for (int u = 0; u < 8; ++u) p[u] = pairs[j0 + u];
        float v[8];
        #pragma unroll
        for (int u = 0; u < 8; ++u) v[u] = *(const float*)(sb + (size_t)(unsigned)p[u].x);
        #pragma unroll
        for (int u = 0; u < 8; ++u) acc = fmaf(__int_as_float(p[u].y), v[u], acc);
    }
    if (j0 < e) {
        int2 p[8];
        float v[8];
        #pragma unroll
        for (int u = 0; u < 8; ++u) {
            int j = j0 + u;
            p[u] = pairs[min(j, e - 1)];
            if (j >= e) p[u].y = 0;
        }
        #pragma unroll
        for (int u = 0; u < 8; ++u) v[u] = *(const float*)(sb + (size_t)(unsigned)p[u].x);
        #pragma unroll
        for (int u = 0; u < 8; ++u) acc = fmaf(__int_as_float(p[u].y), v[u], acc);
    }
    tacc[(size_t)t * 64 + lane] += acc;
}

// ---------------- target-row accumulation (only 2048 rows of acc needed) ----
__global__ void __launch_bounds__(256) k_tacc(const float* __restrict__ emb, float* __restrict__ tacc,
                                              const int* __restrict__ uids, const int* __restrict__ iids,
                                              int zero_init) {
    int lane = threadIdx.x & 63;
    int t = blockIdx.x * 4 + (threadIdx.x >> 6);
    if (t >= 2048) return;
    int r = (t < BATCH) ? uids[t] : (N_USER + iids[t - BATCH]);
    float v = emb[(size_t)r * 64 + lane];
    if (zero_init) tacc[(size_t)t * 64 + lane] = v;
    else           tacc[(size_t)t * 64 + lane] += v;
}

// ---------------- X assembly: trivial gathers + light/4 ----------------
__global__ void __launch_bounds__(256) k_xsmall(const int* __restrict__ aux,
                                                const float* __restrict__ ratef, const float* __restrict__ genderf,
                                                const float* __restrict__ agef, const float* __restrict__ occf,
                                                const float* __restrict__ areaf, const float* __restrict__ tacc,
                                                float* __restrict__ X) {
    int lane = threadIdx.x & 63;
    int b = blockIdx.x * 4 + (threadIdx.x >> 6);
    if (b >= BATCH) return;
    const int* arow = aux + (size_t)b * AUX_W;
    float* xr = X + (size_t)b * 640;
    xr[0   + lane] = ratef[arow[0] * 64 + lane];
    xr[256 + lane] = genderf[arow[10242] * 64 + lane];
    xr[320 + lane] = agef[arow[10243] * 64 + lane];
    xr[384 + lane] = occf[arow[10244] * 64 + lane];
    xr[448 + lane] = areaf[arow[10245] * 64 + lane];
    xr[512 + lane] = tacc[(size_t)b * 64 + lane] * 0.25f;
    xr[576 + lane] = tacc[(size_t)(BATCH + b) * 64 + lane] * 0.25f;
}

// ---------------- multihot as dense MFMA GEMM ----------------------------
// A = aux slice (binary ints) 1024 x K, B = Wt (bf16, frag-packed), C += A@B.
// Block: 64 rows x 64 cols, 4 waves (16 rows each), K-chunks of 512.
// Layouts (learn_hip m89/m120): A[m=lane&15][k=quad*8+j]; B[k=quad*8+j][n=lane&15];
// C: col=lane&15, row=quad*4+reg.
__global__ void __launch_bounds__(256) k_mhgemm(const int* __restrict__ aux,
                                                const unsigned short* __restrict__ WtG,
                                                const unsigned short* __restrict__ WtD,
                                                const unsigned short* __restrict__ WtA,
                                                float* __restrict__ Xmh, float* __restrict__ cntf) {
    int blk = blockIdx.x;
    int seg, rb, k0, klen, Kseg, auxoff;
    const unsigned short* Wt;
    if (blk < 16)      { seg = 0; rb = blk;                      k0 = 0;              klen = 25;                    Kseg = 25;   auxoff = 1;    Wt = WtG; }
    else if (blk < 96) { int t = blk - 16; seg = 1; rb = t & 15; k0 = (t >> 4) * 512; klen = min(512, 2186 - k0);   Kseg = 2186; auxoff = 26;   Wt = WtD; }
    else               { int t = blk - 96; seg = 2; rb = t & 15; k0 = (t >> 4) * 512; klen = min(512, 8030 - k0);   Kseg = 8030; auxoff = 2212; Wt = WtA; }
    int lane = threadIdx.x & 63, wave = threadIdx.x >> 6;
    int m = lane & 15, quad = lane >> 4;
    int row = rb * 64 + wave * 16 + m;
    const int* arow = aux + (size_t)row * AUX_W + auxoff;

    f32x4 acc0 = {0.f,0.f,0.f,0.f}, acc1 = acc0, acc2 = acc0, acc3 = acc0;
    float asum = 0.f;
    int nchunk = (klen + 31) >> 5;
    for (int kci = 0; kci < nchunk; ++kci) {
        int kb = k0 + kci * 32 + quad * 8;
        short8 af;
        if (kb + 8 <= Kseg) {
            #pragma unroll
            for (int j = 0; j < 8; ++j) {
                int x = arow[kb + j];
                af[j] = x ? (short)0x3F80 : (short)0;
                asum += (float)x;
            }
        } else {
            #pragma unroll
            for (int j = 0; j < 8; ++j) {
                int x = (kb + j < Kseg) ? arow[kb + j] : 0;
                af[j] = x ? (short)0x3F80 : (short)0;
                asum += (float)x;
            }
        }
        size_t kcg = (size_t)(k0 >> 5) + kci;
        const unsigned short* bp = Wt + ((kcg * 64 + m) * 4 + quad) * 8;
        short8 b0 = *(const short8*)(bp);
        short8 b1 = *(const short8*)(bp + 512);    // +16 cols * 4 quads * 8
        short8 b2 = *(const short8*)(bp + 1024);
        short8 b3 = *(const short8*)(bp + 1536);
        acc0 = __builtin_amdgcn_mfma_f32_16x16x32_bf16(af, b0, acc0, 0, 0, 0);
        acc1 = __builtin_amdgcn_mfma_f32_16x16x32_bf16(af, b1, acc1, 0, 0, 0);
        acc2 = __builtin_amdgcn_mfma_f32_16x16x32_bf16(af, b2, acc2, 0, 0, 0);
        acc3 = __builtin_amdgcn_mfma_f32_16x16x32_bf16(af, b3, acc3, 0, 0, 0);
    }
    // row counts: lane holds partial for row (m); reduce across quads
    asum += __shfl_xor(asum, 16);
    asum += __shfl_xor(asum, 32);
    if (quad == 0) atomicAdd(&cntf[seg * BATCH + row], asum);
    // C write: out_row = rb*64 + wave*16 + quad*4 + reg, col = nt*16 + m
    float* xbase = Xmh + ((size_t)seg * BATCH + rb * 64 + wave * 16 + quad * 4) * 64;
    #pragma unroll
    for (int reg = 0; reg < 4; ++reg) {
        float* xr = xbase + (size_t)reg * 64;
        atomicAdd(&xr[ 0 + m], acc0[reg]);
        atomicAdd(&xr[16 + m], acc1[reg]);
        atomicAdd(&xr[32 + m], acc2[reg]);
        atomicAdd(&xr[48 + m], acc3[reg]);
    }
}

// normalize multihot sums -> X columns 64..255
__global__ void __launch_bounds__(256) k_norm(const float* __restrict__ Xmh, const float* __restrict__ cntf,
                                              float* __restrict__ X) {
    int lane = threadIdx.x & 63;
    int t = blockIdx.x * 4 + (threadIdx.x >> 6);   // t in [0, 3072)
    if (t >= 3 * BATCH) return;
    int seg = t >> 10, b = t & 1023;
    X[(size_t)b * 640 + 64 + seg * 64 + lane] = Xmh[(size_t)t * 64 + lane] / cntf[t];
}

// ---------------- fused MLP: relu(relu(X@W1+b1)@W2+b2)@Wo+bo --------------
__global__ void __launch_bounds__(256) k_mlp(const float* __restrict__ X,
                                             const float* __restrict__ W1, const float* __restrict__ b1,
                                             const float* __restrict__ W2, const float* __restrict__ b2,
                                             const float* __restrict__ Wo, const float* __restrict__ bo,
                                             void* __restrict__ out, const int* flag) {
    int lane = threadIdx.x & 63, w = threadIdx.x >> 6;
    int b = blockIdx.x * 4 + w;
    const float* xr = X + (size_t)b * 640;
    float acc = b1[lane];
    #pragma unroll 8
    for (int k = 0; k < 640; ++k) acc += xr[k] * W1[(size_t)k * 64 + lane];
    float h1 = fmaxf(acc, 0.f);
    __shared__ float sh[4][64];
    sh[w][lane] = h1;
    __syncthreads();
    float acc2 = b2[lane];
    #pragma unroll 8
    for (int j = 0; j < 64; ++j) acc2 += sh[w][j] * W2[(size_t)j * 64 + lane];
    float h2 = fmaxf(acc2, 0.f);
    float p = h2 * Wo[lane];
    #pragma unroll
    for (int off = 32; off; off >>= 1) p += __shfl_down(p, off);
    if (lane == 0) {
        float r = p + bo[0];
        if (*flag) ((float*)out)[b] = r;
        else       ((__hip_bfloat16*)out)[b] = __float2bfloat16(r);
    }
}

extern "C" void kernel_launch(void* const* d_in, const int* in_sizes, int n_in,
                              void* d_out, int out_size, void* d_ws, size_t ws_size,
                              hipStream_t stream) {
    const int* aux  = (const int*)d_in[0];
    const int* uids = (const int*)d_in[1];
    const int* iids = (const int*)d_in[2];
    const int* grow = (const int*)d_in[3];
    const int* gcol = (const int*)d_in[4];
    const void* gval = d_in[5];

    // workspace carve-out (256B aligned)
    char* p = (char*)d_ws;
    auto alloc = [&](size_t bytes) -> char* {
        char* r = p;
        p += (bytes + 255) / 256 * 256;
        return r;
    };
    int*   flag   = (int*)alloc(4);
    int*   cnt    = (int*)alloc((size_t)180224 * 4);
    int*   mark   = (int*)alloc((size_t)180224 * 4);   // adjacent to cnt: zeroed together
    int*   offs   = (int*)alloc((size_t)180224 * 4);
    int*   cursor = (int*)alloc((size_t)180224 * 4);
    int*   part   = (int*)alloc(256 * 4);
    int2*  pairs  = (int2*)alloc((size_t)E2 * 8);
    float* embA   = (float*)alloc((size_t)N_NODES * 64 * 4);
    float* embB   = (float*)alloc((size_t)N_NODES * 64 * 4);
    float* tacc   = (float*)alloc((size_t)2048 * 64 * 4);
    float* X      = (float*)alloc((size_t)BATCH * 640 * 4);
    float* Xmh    = (float*)alloc((size_t)3 * BATCH * 64 * 4);  // contiguous with cntf
    float* cntf   = (float*)alloc((size_t)3 * BATCH * 4);
    unsigned short* WtG = (unsigned short*)alloc((size_t)KP_G * 64 * 2);
    unsigned short* WtD = (unsigned short*)alloc((size_t)KP_D * 64 * 2);
    unsigned short* WtA = (unsigned short*)alloc((size_t)KP_A * 64 * 2);
    float* ratef   = (float*)alloc(384 * 4);
    float* genderf = (float*)alloc(128 * 4);
    float* agef    = (float*)alloc(448 * 4);
    float* occf    = (float*)alloc(1344 * 4);
    float* areaf   = (float*)alloc((size_t)217728 * 4);
    float* fc1W    = (float*)alloc((size_t)40960 * 4);
    float* fc1b    = (float*)alloc(64 * 4);
    float* fc2W    = (float*)alloc(4096 * 4);
    float* fc2b    = (float*)alloc(64 * 4);
    float* outW    = (float*)alloc(64 * 4);
    float* outb    = (float*)alloc(4);

    // 1. dtype detect (probe user_rel)
    hipLaunchKernelGGL(k_detect, dim3(1), dim3(64), 0, stream, d_in[14], flag);

    // 2. convert float inputs to f32 (user_rel/item_rel straight into embA)
    CvtBatch cb;
    int blk = 0, si = 0;
    auto addseg = [&](const void* s, float* d, int n) {
        cb.seg[si].src = s; cb.seg[si].dst = d; cb.seg[si].n = n; cb.seg[si].blk0 = blk;
        blk += (n + 255) / 256; ++si;
    };
    addseg(d_in[6],  ratef,   384);
    addseg(d_in[10], genderf, 128);
    addseg(d_in[11], agef,    448);
    addseg(d_in[12], occf,    1344);
    addseg(d_in[13], areaf,   217728);
    addseg(d_in[14], embA,                 N_USER * 64);
    addseg(d_in[15], embA + (size_t)N_USER * 64, M_ITEM * 64);
    addseg(d_in[16], fc1W,   40960);
    addseg(d_in[17], fc1b,   64);
    addseg(d_in[18], fc2W,   4096);
    addseg(d_in[19], fc2b,   64);
    addseg(d_in[20], outW,   64);
    addseg(d_in[21], outb,   1);
    for (int i = si; i < 16; ++i) { cb.seg[i].src = nullptr; cb.seg[i].dst = nullptr; cb.seg[i].n = 0; cb.seg[i].blk0 = 0x7fffffff; }
    hipLaunchKernelGGL(k_cvt_batch, dim3(blk), dim3(256), 0, stream, cb, flag);

    // 2b. pack multihot W tables into B-fragment order (bf16)
    hipLaunchKernelGGL(k_wt, dim3(((KP_G + KP_D + KP_A) * 64 + 255) / 256), dim3(256), 0, stream,
                       d_in[7], d_in[8], d_in[9], WtG, WtD, WtA, flag);

    // 3. CSR build (+ zero cnt+mark in one pass; Xmh+cntf in another)
    hipLaunchKernelGGL(k_zero, dim3((2 * 180224 + 255) / 256), dim3(256), 0, stream, cnt, 2 * 180224);
    hipLaunchKernelGGL(k_zero, dim3((3 * BATCH * 64 + 3 * BATCH + 255) / 256), dim3(256), 0, stream,
                       (int*)Xmh, 3 * BATCH * 64 + 3 * BATCH);
    hipLaunchKernelGGL(k_hist, dim3((E2 + 255) / 256), dim3(256), 0, stream, grow, cnt);
    hipLaunchKernelGGL(k_scan_partial, dim3(SCAN_NBLK), dim3(SCAN_BS), 0, stream, cnt, part, 180001);
    hipLaunchKernelGGL(k_scan_part_ex, dim3(1), dim3(64), 0, stream, part);
    hipLaunchKernelGGL(k_scan_final, dim3(SCAN_NBLK), dim3(SCAN_BS), 0, stream, cnt, part, offs, cursor, 180001);
    hipLaunchKernelGGL(k_scatter, dim3((E2 + 255) / 256), dim3(256), 0, stream, grow, gcol, gval, cursor, pairs, flag);
    hipLaunchKernelGGL(k_mark, dim3(2048 / 4), dim3(256), 0, stream, offs, pairs, uids, iids, mark);

    // 4. LightGCN with backward pruning:
    //    layer1 full (emb1 needed at ~N(F2) ~= everywhere),
    //    layer2 masked to T u N(T)  (~29k rows),
    //    layer3 only at T, fused into tacc.
    dim3 spmvGrid((N_NODES + 3) / 4), wg(256);
    dim3 taccGrid(2048 / 4);
    hipLaunchKernelGGL(k_tacc, taccGrid, wg, 0, stream, embA, tacc, uids, iids, 1);
    hipLaunchKernelGGL(k_spmv, spmvGrid, wg, 0, stream, embA, embB, offs, pairs, (const int*)nullptr);
    hipLaunchKernelGGL(k_tacc, taccGrid, wg, 0, stream, embB, tacc, uids, iids, 0);
    hipLaunchKernelGGL(k_spmv, spmvGrid, wg, 0, stream, embB, embA, offs, pairs, mark);
    hipLaunchKernelGGL(k_tacc, taccGrid, wg, 0, stream, embA, tacc, uids, iids, 0);
    hipLaunchKernelGGL(k_spmv3, taccGrid, wg, 0, stream, embA, tacc, offs, pairs, uids, iids);

    // 5. assemble X (1024 x 640)
    hipLaunchKernelGGL(k_xsmall, dim3(BATCH / 4), wg, 0, stream, aux, ratef, genderf, agef, occf, areaf, tacc, X);
    hipLaunchKernelGGL(k_mhgemm, dim3(352), wg, 0, stream, aux, WtG, WtD, WtA, Xmh, cntf);
    hipLaunchKernelGGL(k_norm, dim3((3 * BATCH + 3) / 4), wg, 0, stream, Xmh, cntf, X);

    // 6. fused MLP -> out
    hipLaunchKernelGGL(k_mlp, dim3(BATCH / 4), wg, 0, stream, X, fc1W, fc1b, fc2W, fc2b, outW, outb, d_out, flag);
}

// Round 6
// 427.327 us; speedup vs baseline: 2.8686x; 1.1789x over previous
//
#include <hip/hip_runtime.h>
#include <hip/hip_bf16.h>

#define N_USER 150000
#define M_ITEM 30000
#define N_NODES 180000
#define E2 1200000
#define BATCH 1024
#define AUX_W 10246
#define SCAN_BS 256
#define SCAN_EPB 2048
#define SCAN_NBLK 88   // ceil(180001/2048)
#define KP_G 32
#define KP_D 2208
#define KP_A 8064
#define NBKT 265       // 147 user buckets (1024 rows) + 118 item buckets (256 rows)

typedef __attribute__((ext_vector_type(8))) short short8;
typedef __attribute__((ext_vector_type(4))) float f32x4;

__device__ __forceinline__ int bucket_of(int r) {
    return r < N_USER ? (r >> 10) : 147 + ((r - N_USER) >> 8);
}

// ---------------- dtype detector: bf16 vs f32 float inputs ----------------
__global__ void k_detect(const void* probe, int* flag) {
    int lane = threadIdx.x;
    float v = __bfloat162float(((const __hip_bfloat16*)probe)[lane]);
    bool big = !(fabsf(v) < 1000.0f);
    unsigned long long m = __ballot(big);
    if (lane == 0) *flag = (__popcll(m) > 8) ? 1 : 0;
}

// ---------------- batched float-input conversion to f32 ----------------
struct CvtSeg { const void* src; float* dst; int n; int blk0; };
struct CvtBatch { CvtSeg seg[16]; };

__global__ void __launch_bounds__(256) k_cvt_batch(CvtBatch cb, const int* flag) {
    int blk = blockIdx.x;
    int si = 0;
    #pragma unroll
    for (int i = 0; i < 16; ++i) if (blk >= cb.seg[i].blk0) si = i;
    const CvtSeg sg = cb.seg[si];
    int i = (blk - sg.blk0) * 256 + threadIdx.x;
    if (i >= sg.n) return;
    if (*flag) sg.dst[i] = ((const float*)sg.src)[i];
    else       sg.dst[i] = __bfloat162float(((const __hip_bfloat16*)sg.src)[i]);
}

// ---------------- scaled embedding conversion: embA = dinv[r] * raw --------
// 4 elems/thread: ushort4 (bf16) or float4 path.
__global__ void __launch_bounds__(256) k_cvt_emb(const void* rawU, const void* rawI,
                                                 const float* __restrict__ dinv,
                                                 float* __restrict__ emb, const int* flag) {
    int q = blockIdx.x * 256 + threadIdx.x;          // quad index
    if (q >= N_NODES * 16) return;
    int r = q >> 4;
    const void* src; size_t off;
    if (r < N_USER) { src = rawU; off = (size_t)q * 4; }
    else            { src = rawI; off = (size_t)(q - N_USER * 16) * 4; }
    float d = dinv[r];
    float4 v;
    if (*flag) {
        v = ((const float4*)src)[off >> 2];
    } else {
        ushort4 u = ((const ushort4*)src)[off >> 2];
        v.x = __bfloat162float(*(__hip_bfloat16*)&u.x);
        v.y = __bfloat162float(*(__hip_bfloat16*)&u.y);
        v.z = __bfloat162float(*(__hip_bfloat16*)&u.z);
        v.w = __bfloat162float(*(__hip_bfloat16*)&u.w);
    }
    float4 o = { v.x * d, v.y * d, v.z * d, v.w * d };
    ((float4*)emb)[(size_t)q] = o;
}

// ---------------- pack multihot W tables into B-fragment order ----------
__global__ void __launch_bounds__(256) k_wt(const void* Wg, const void* Wd, const void* Wa,
                                            unsigned short* WtG, unsigned short* WtD, unsigned short* WtA,
                                            const int* flag) {
    int t = blockIdx.x * 256 + threadIdx.x;
    if (t >= (KP_G + KP_D + KP_A) * 64) return;
    int kp = t >> 6, n = t & 63;
    int k, K; const void* src; unsigned short* dst;
    if (kp < KP_G)              { k = kp;                K = 25;   src = Wg; dst = WtG; }
    else if (kp < KP_G + KP_D)  { k = kp - KP_G;         K = 2186; src = Wd; dst = WtD; }
    else                        { k = kp - KP_G - KP_D;  K = 8030; src = Wa; dst = WtA; }
    unsigned short v = 0;
    if (k < K) {
        if (*flag) {
            __hip_bfloat16 h = __float2bfloat16(((const float*)src)[(size_t)k * 64 + n]);
            v = *(unsigned short*)&h;
        } else {
            v = ((const unsigned short*)src)[(size_t)k * 64 + n];
        }
    }
    dst[(((size_t)(k >> 5) * 64 + n) * 4 + ((k >> 3) & 3)) * 8 + (k & 7)] = v;
}

// ---------------- CSR build ----------------
__global__ void __launch_bounds__(256) k_zero(int* p, int n) {
    int i = blockIdx.x * 256 + threadIdx.x;
    if (i < n) p[i] = 0;
}

__global__ void __launch_bounds__(256) k_hist(const int* __restrict__ row, int* __restrict__ cnt) {
    int i = blockIdx.x * 256 + threadIdx.x;
    if (i < E2) atomicAdd(&cnt[row[i]], 1);
}

__global__ void __launch_bounds__(SCAN_BS) k_scan_partial(const int* __restrict__ cnt, int* __restrict__ part, int n) {
    __shared__ int sd[SCAN_BS];
    int base = blockIdx.x * SCAN_EPB;
    int s = 0;
    #pragma unroll
    for (int j = 0; j < 8; ++j) {
        int idx = base + j * SCAN_BS + threadIdx.x;
        if (idx < n) s += cnt[idx];
    }
    sd[threadIdx.x] = s; __syncthreads();
    for (int off = SCAN_BS / 2; off; off >>= 1) {
        if (threadIdx.x < off) sd[threadIdx.x] += sd[threadIdx.x + off];
        __syncthreads();
    }
    if (threadIdx.x == 0) part[blockIdx.x] = sd[0];
}

__global__ void k_scan_part_ex(int* part) {
    if (threadIdx.x == 0) {
        int s = 0;
        for (int i = 0; i < SCAN_NBLK; ++i) { int v = part[i]; part[i] = s; s += v; }
    }
}

__global__ void __launch_bounds__(SCAN_BS) k_scan_final(const int* __restrict__ cnt, const int* __restrict__ part,
                                                        int* __restrict__ offs, int n) {
    __shared__ int sw[SCAN_BS];
    int base = blockIdx.x * SCAN_EPB + threadIdx.x * 8;
    int v[8];
    int s = 0;
    #pragma unroll
    for (int j = 0; j < 8; ++j) { int idx = base + j; v[j] = (idx < n) ? cnt[idx] : 0; }
    #pragma unroll
    for (int j = 0; j < 8; ++j) { int t = v[j]; v[j] = s; s += t; }
    sw[threadIdx.x] = s; __syncthreads();
    for (int off = 1; off < SCAN_BS; off <<= 1) {
        int t = (threadIdx.x >= off) ? sw[threadIdx.x - off] : 0;
        __syncthreads();
        sw[threadIdx.x] += t;
        __syncthreads();
    }
    int toff = (threadIdx.x > 0 ? sw[threadIdx.x - 1] : 0) + part[blockIdx.x];
    #pragma unroll
    for (int j = 0; j < 8; ++j) {
        int idx = base + j;
        if (idx < n) offs[idx] = v[j] + toff;
    }
}

// ---------------- degree-derived scale factors ----------------
// dinv = rsqrt(deg) (0 if deg==0); dsq = dinv^2; g = sqrt(deg) (0 if deg==0)
__global__ void __launch_bounds__(256) k_dinv(const int* __restrict__ cnt, float* __restrict__ dinv,
                                              float* __restrict__ dsq, float* __restrict__ g) {
    int i = blockIdx.x * 256 + threadIdx.x;
    if (i >= 180224) return;
    float deg = (float)cnt[i];
    bool nz = deg > 0.f;
    dinv[i] = nz ? rsqrtf(deg) : 0.f;
    dsq[i]  = nz ? 1.f / deg : 0.f;
    g[i]    = nz ? sqrtf(deg) : 0.f;
}

// bucket base cursors = offs[first row of bucket]
__global__ void k_bases(const int* __restrict__ offs, int* __restrict__ bucketcur) {
    int b = threadIdx.x;
    if (b >= NBKT) return;
    int r0 = (b < 147) ? (b << 10) : N_USER + ((b - 147) << 8);
    bucketcur[b] = offs[r0];
}

// ---------------- P1: bin edges into NBKT row-range buckets ----------------
// Block = 4096 edges. LDS histogram -> one global atomic per (block,bucket),
// writes are ~contiguous runs per bucket (good line locality).
__global__ void __launch_bounds__(256) k_p1(const int* __restrict__ grow, const int* __restrict__ gcol,
                                            int* __restrict__ bucketcur, int2* __restrict__ binned) {
    __shared__ int h1[NBKT], base1[NBKT];
    int tid = threadIdx.x;
    for (int i = tid; i < NBKT; i += 256) h1[i] = 0;
    __syncthreads();
    int idx0 = blockIdx.x * 4096;
    int r[16], c[16];
    #pragma unroll
    for (int k = 0; k < 16; ++k) {
        int i = idx0 + k * 256 + tid;
        if (i < E2) {
            r[k] = grow[i]; c[k] = gcol[i];
            atomicAdd(&h1[bucket_of(r[k])], 1);
        } else r[k] = -1;
    }
    __syncthreads();
    for (int i = tid; i < NBKT; i += 256) {
        base1[i] = h1[i] ? atomicAdd(&bucketcur[i], h1[i]) : 0;
        h1[i] = 0;
    }
    __syncthreads();
    #pragma unroll
    for (int k = 0; k < 16; ++k) {
        if (r[k] >= 0) {
            int b = bucket_of(r[k]);
            int p = base1[b] + atomicAdd(&h1[b], 1);
            binned[p] = make_int2(r[k], c[k]);
        }
    }
}

// ---------------- P2: sort each bucket into final CSR order ----------------
// One block per bucket. LDS hist+scan of <=1024 rows, scatter cols (<<8) into
// the bucket's contiguous output window (writes stay in one L2 region).
__global__ void __launch_bounds__(256) k_p2(const int2* __restrict__ binned, const int* __restrict__ offs,
                                            int* __restrict__ cols) {
    __shared__ int h[1024];
    __shared__ int ws2[256];
    int b = blockIdx.x, tid = threadIdx.x;
    int r0, r1;
    if (b < 147) { r0 = b << 10; r1 = min((b + 1) << 10, N_USER); }
    else         { r0 = N_USER + ((b - 147) << 8); r1 = min(N_USER + ((b - 146) << 8), N_NODES); }
    int s0 = offs[r0], e0 = offs[r1];
    for (int i = tid; i < 1024; i += 256) h[i] = 0;
    __syncthreads();
    for (int j = s0 + tid; j < e0; j += 256) atomicAdd(&h[binned[j].x - r0], 1);
    __syncthreads();
    int t0 = tid * 4;
    int a0 = h[t0], a1 = h[t0 + 1], a2 = h[t0 + 2], a3 = h[t0 + 3];
    ws2[tid] = a0 + a1 + a2 + a3;
    __syncthreads();
    for (int off = 1; off < 256; off <<= 1) {
        int v = (tid >= off) ? ws2[tid - off] : 0;
        __syncthreads();
        ws2[tid] += v;
        __syncthreads();
    }
    int excl = tid ? ws2[tid - 1] : 0;
    h[t0]     = excl;
    h[t0 + 1] = excl + a0;
    h[t0 + 2] = excl + a0 + a1;
    h[t0 + 3] = excl + a0 + a1 + a2;
    __syncthreads();
    for (int j = s0 + tid; j < e0; j += 256) {
        int2 e = binned[j];
        int p = s0 + atomicAdd(&h[e.x - r0], 1);
        cols[p] = e.y << 8;           // pre-scaled byte offset into a 64-float row
    }
}

// ---------------- mark bitmap: rows needed in layer 2 = T ∪ N(T) ----------
__global__ void __launch_bounds__(256) k_mark(const int* __restrict__ offs, const int* __restrict__ cols,
                                              const int* __restrict__ uids, const int* __restrict__ iids,
                                              int* __restrict__ mark) {
    int lane = threadIdx.x & 63;
    int t = blockIdx.x * 4 + (threadIdx.x >> 6);
    if (t >= 2048) return;
    int r = (t < BATCH) ? uids[t] : (N_USER + iids[t - BATCH]);
    if (lane == 0) mark[r] = 1;
    int s = offs[r], e = offs[r + 1];
    for (int j = s + lane; j < e; j += 64) mark[(unsigned)cols[j] >> 8] = 1;
}

// ---------------- f-domain SpMV: f_out[r] = dsq[r] * sum_{c in N(r)} f_in[c]
__global__ void __launch_bounds__(256, 4) k_spmv(const float* __restrict__ src, float* __restrict__ dst,
                                                 const int* __restrict__ offs, const int* __restrict__ cols,
                                                 const float* __restrict__ dsq, const int* __restrict__ mark) {
    int lane = threadIdx.x & 63;
    int wid = blockIdx.x * 4 + (threadIdx.x >> 6);
    if (wid >= N_NODES) return;
    if (mark && mark[wid] == 0) return;
    int s = offs[wid], e = offs[wid + 1];
    const char* sb = (const char*)src + (lane << 2);
    float acc = 0.f;
    int j0 = s;
    for (; j0 + 8 <= e; j0 += 8) {
        int c[8];
        #pragma unroll
        for (int u = 0; u < 8; ++u) c[u] = cols[j0 + u];
        float v[8];
        #pragma unroll
        for (int u = 0; u < 8; ++u) v[u] = *(const float*)(sb + (size_t)(unsigned)c[u]);
        #pragma unroll
        for (int u = 0; u < 8; ++u) acc += v[u];
    }
    if (j0 < e) {
        int c[8]; float w[8];
        #pragma unroll
        for (int u = 0; u < 8; ++u) {
            int j = j0 + u;
            c[u] = cols[min(j, e - 1)];
            w[u] = (j < e) ? 1.f : 0.f;
        }
        float v[8];
        #pragma unroll
        for (int u = 0; u < 8; ++u) v[u] = *(const float*)(sb + (size_t)(unsigned)c[u]);
        #pragma unroll
        for (int u = 0; u < 8; ++u) acc = fmaf(w[u], v[u], acc);
    }
    dst[(size_t)wid * 64 + lane] = dsq[wid] * acc;
}

// ---------------- layer-3 SpMV fused into tacc: += dinv[r] * sum f2[c] -----
__global__ void __launch_bounds__(256, 4) k_spmv3(const float* __restrict__ src, float* __restrict__ tacc,
                                                  const int* __restrict__ offs, const int* __restrict__ cols,
                                                  const float* __restrict__ dinv,
                                                  const int* __restrict__ uids, const int* __restrict__ iids) {
    int lane = threadIdx.x & 63;
    int t = blockIdx.x * 4 + (threadIdx.x >> 6);
    if (t >= 2048) return;
    int r = (t < BATCH) ? uids[t] : (N_USER + iids[t - BATCH]);
    int s = offs[r], e = offs[r + 1];
    const char* sb = (const char*)src + (lane << 2);
    float acc = 0.f;
    int j0 = s;
    for (; j0 + 8 <= e; j0 += 8) {
        int c[8];
        #pragma unroll
        for (int u = 0; u < 8; ++u) c[u] = cols[j0 + u];
        float v[8];
        #pragma unroll
        for (int u = 0; u < 8; ++u) v[u] = *(const float*)(sb + (size_t)(unsigned)c[u]);
        #pragma unroll
        for (int u = 0; u < 8; ++u) acc += v[u];
    }
    if (j0 < e) {
        int c[8]; float w[8];
        #pragma unroll
        for (int u = 0; u < 8; ++u) {
            int j = j0 + u;
            c[u] = cols[min(j, e - 1)];
            w[u] = (j < e) ? 1.f : 0.f;
        }
        float v[8];
        #pragma unroll
        for (int u = 0; u < 8; ++u) v[u] = *(const float*)(sb + (size_t)(unsigned)c[u]);
        #pragma unroll
        for (int u = 0; u < 8; ++u) acc = fmaf(w[u], v[u], acc);
    }
    tacc[(size_t)t * 64 + lane] += dinv[r] * acc;
}

// ---------------- tacc init from RAW tables (deg-0 rows keep emb0) ---------
__global__ void __launch_bounds__(256) k_tacc0(const void* rawU, const void* rawI, float* __restrict__ tacc,
                                               const int* __restrict__ uids, const int* __restrict__ iids,
                                               const int* flag) {
    int lane = threadIdx.x & 63;
    int t = blockIdx.x * 4 + (threadIdx.x >> 6);
    if (t >= 2048) return;
    const void* src; size_t ri;
    if (t < BATCH) { src = rawU; ri = (size_t)uids[t]; }
    else           { src = rawI; ri = (size_t)iids[t - BATCH]; }
    float v;
    if (*flag) v = ((const float*)src)[ri * 64 + lane];
    else       v = __bfloat162float(((const __hip_bfloat16*)src)[ri * 64 + lane]);
    tacc[(size_t)t * 64 + lane] = v;
}

// ---------------- tacc layers: += f_l[r] * g[r] ---------------------------
__global__ void __launch_bounds__(256) k_tacc(const float* __restrict__ emb, float* __restrict__ tacc,
                                              const int* __restrict__ uids, const int* __restrict__ iids,
                                              const float* __restrict__ g) {
    int lane = threadIdx.x & 63;
    int t = blockIdx.x * 4 + (threadIdx.x >> 6);
    if (t >= 2048) return;
    int r = (t < BATCH) ? uids[t] : (N_USER + iids[t - BATCH]);
    tacc[(size_t)t * 64 + lane] += emb[(size_t)r * 64 + lane] * g[r];
}

// ---------------- X assembly: trivial gathers + light/4 ----------------
__global__ void __launch_bounds__(256) k_xsmall(const int* __restrict__ aux,
                                                const float* __restrict__ ratef, const float* __restrict__ genderf,
                                                const float* __restrict__ agef, const float* __restrict__ occf,
                                                const float* __restrict__ areaf, const float* __restrict__ tacc,
                                                float* __restrict__ X) {
    int lane = threadIdx.x & 63;
    int b = blockIdx.x * 4 + (threadIdx.x >> 6);
    if (b >= BATCH) return;
    const int* arow = aux + (size_t)b * AUX_W;
    float* xr = X + (size_t)b * 640;
    xr[0   + lane] = ratef[arow[0] * 64 + lane];
    xr[256 + lane] = genderf[arow[10242] * 64 + lane];
    xr[320 + lane] = agef[arow[10243] * 64 + lane];
    xr[384 + lane] = occf[arow[10244] * 64 + lane];
    xr[448 + lane] = areaf[arow[10245] * 64 + lane];
    xr[512 + lane] = tacc[(size_t)b * 64 + lane] * 0.25f;
    xr[576 + lane] = tacc[(size_t)(BATCH + b) * 64 + lane] * 0.25f;
}

// ---------------- multihot as dense MFMA GEMM ----------------------------
__global__ void __launch_bounds__(256) k_mhgemm(const int* __restrict__ aux,
                                                const unsigned short* __restrict__ WtG,
                                                const unsigned short* __restrict__ WtD,
                                                const unsigned short* __restrict__ WtA,
                                                float* __restrict__ Xmh, float* __restrict__ cntf) {
    int blk = blockIdx.x;
    int seg, rb, k0, klen, Kseg, auxoff;
    const unsigned short* Wt;
    if (blk < 16)      { seg = 0; rb = blk;                      k0 = 0;              klen = 25;                    Kseg = 25;   auxoff = 1;    Wt = WtG; }
    else if (blk < 96) { int t = blk - 16; seg = 1; rb = t & 15; k0 = (t >> 4) * 512; klen = min(512, 2186 - k0);   Kseg = 2186; auxoff = 26;   Wt = WtD; }
    else               { int t = blk - 96; seg = 2; rb = t & 15; k0 = (t >> 4) * 512; klen = min(512, 8030 - k0);   Kseg = 8030; auxoff = 2212; Wt = WtA; }
    int lane = threadIdx.x & 63, wave = threadIdx.x >> 6;
    int m = lane & 15, quad = lane >> 4;
    int row = rb * 64 + wave * 16 + m;
    const int* arow = aux + (size_t)row * AUX_W + auxoff;

    f32x4 acc0 = {0.f,0.f,0.f,0.f}, acc1 = acc0, acc2 = acc0, acc3 = acc0;
    float asum = 0.f;
    int nchunk = (klen + 31) >> 5;
    for (int kci = 0; kci < nchunk; ++kci) {
        int kb = k0 + kci * 32 + quad * 8;
        short8 af;
        if (kb + 8 <= Kseg) {
            #pragma unroll
            for (int j = 0; j < 8; ++j) {
                int x = arow[kb + j];
                af[j] = x ? (short)0x3F80 : (short)0;
                asum += (float)x;
            }
        } else {
            #pragma unroll
            for (int j = 0; j < 8; ++j) {
                int x = (kb + j < Kseg) ? arow[kb + j] : 0;
                af[j] = x ? (short)0x3F80 : (short)0;
                asum += (float)x;
            }
        }
        size_t kcg = (size_t)(k0 >> 5) + kci;
        const unsigned short* bp = Wt + ((kcg * 64 + m) * 4 + quad) * 8;
        short8 b0 = *(const short8*)(bp);
        short8 b1 = *(const short8*)(bp + 512);
        short8 b2 = *(const short8*)(bp + 1024);
        short8 b3 = *(const short8*)(bp + 1536);
        acc0 = __builtin_amdgcn_mfma_f32_16x16x32_bf16(af, b0, acc0, 0, 0, 0);
        acc1 = __builtin_amdgcn_mfma_f32_16x16x32_bf16(af, b1, acc1, 0, 0, 0);
        acc2 = __builtin_amdgcn_mfma_f32_16x16x32_bf16(af, b2, acc2, 0, 0, 0);
        acc3 = __builtin_amdgcn_mfma_f32_16x16x32_bf16(af, b3, acc3, 0, 0, 0);
    }
    asum += __shfl_xor(asum, 16);
    asum += __shfl_xor(asum, 32);
    if (quad == 0) atomicAdd(&cntf[seg * BATCH + row], asum);
    float* xbase = Xmh + ((size_t)seg * BATCH + rb * 64 + wave * 16 + quad * 4) * 64;
    #pragma unroll
    for (int reg = 0; reg < 4; ++reg) {
        float* xr = xbase + (size_t)reg * 64;
        atomicAdd(&xr[ 0 + m], acc0[reg]);
        atomicAdd(&xr[16 + m], acc1[reg]);
        atomicAdd(&xr[32 + m], acc2[reg]);
        atomicAdd(&xr[48 + m], acc3[reg]);
    }
}

__global__ void __launch_bounds__(256) k_norm(const float* __restrict__ Xmh, const float* __restrict__ cntf,
                                              float* __restrict__ X) {
    int lane = threadIdx.x & 63;
    int t = blockIdx.x * 4 + (threadIdx.x >> 6);
    if (t >= 3 * BATCH) return;
    int seg = t >> 10, b = t & 1023;
    X[(size_t)b * 640 + 64 + seg * 64 + lane] = Xmh[(size_t)t * 64 + lane] / cntf[t];
}

// ---------------- fused MLP ----------------
__global__ void __launch_bounds__(256) k_mlp(const float* __restrict__ X,
                                             const float* __restrict__ W1, const float* __restrict__ b1,
                                             const float* __restrict__ W2, const float* __restrict__ b2,
                                             const float* __restrict__ Wo, const float* __restrict__ bo,
                                             void* __restrict__ out, const int* flag) {
    int lane = threadIdx.x & 63, w = threadIdx.x >> 6;
    int b = blockIdx.x * 4 + w;
    const float* xr = X + (size_t)b * 640;
    float acc = b1[lane];
    #pragma unroll 8
    for (int k = 0; k < 640; ++k) acc += xr[k] * W1[(size_t)k * 64 + lane];
    float h1 = fmaxf(acc, 0.f);
    __shared__ float sh[4][64];
    sh[w][lane] = h1;
    __syncthreads();
    float acc2 = b2[lane];
    #pragma unroll 8
    for (int j = 0; j < 64; ++j) acc2 += sh[w][j] * W2[(size_t)j * 64 + lane];
    float h2 = fmaxf(acc2, 0.f);
    float p = h2 * Wo[lane];
    #pragma unroll
    for (int off = 32; off; off >>= 1) p += __shfl_down(p, off);
    if (lane == 0) {
        float r = p + bo[0];
        if (*flag) ((float*)out)[b] = r;
        else       ((__hip_bfloat16*)out)[b] = __float2bfloat16(r);
    }
}

extern "C" void kernel_launch(void* const* d_in, const int* in_sizes, int n_in,
                              void* d_out, int out_size, void* d_ws, size_t ws_size,
                              hipStream_t stream) {
    const int* aux  = (const int*)d_in[0];
    const int* uids = (const int*)d_in[1];
    const int* iids = (const int*)d_in[2];
    const int* grow = (const int*)d_in[3];
    const int* gcol = (const int*)d_in[4];

    char* p = (char*)d_ws;
    auto alloc = [&](size_t bytes) -> char* {
        char* r = p;
        p += (bytes + 255) / 256 * 256;
        return r;
    };
    int*   flag      = (int*)alloc(4);
    int*   cnt       = (int*)alloc((size_t)180224 * 4);
    int*   mark      = (int*)alloc((size_t)180224 * 4);   // adjacent to cnt: zeroed together
    int*   offs      = (int*)alloc((size_t)180224 * 4);
    float* dinv      = (float*)alloc((size_t)180224 * 4);
    float* dsq       = (float*)alloc((size_t)180224 * 4);
    float* gsc       = (float*)alloc((size_t)180224 * 4);
    int*   part      = (int*)alloc(256 * 4);
    int*   bucketcur = (int*)alloc(512 * 4);
    int2*  binned    = (int2*)alloc((size_t)E2 * 8);
    int*   cols      = (int*)alloc((size_t)E2 * 4);
    float* embA      = (float*)alloc((size_t)N_NODES * 64 * 4);
    float* embB      = (float*)alloc((size_t)N_NODES * 64 * 4);
    float* tacc      = (float*)alloc((size_t)2048 * 64 * 4);
    float* X         = (float*)alloc((size_t)BATCH * 640 * 4);
    float* Xmh       = (float*)alloc((size_t)3 * BATCH * 64 * 4);
    float* cntf      = (float*)alloc((size_t)3 * BATCH * 4);
    unsigned short* WtG = (unsigned short*)alloc((size_t)KP_G * 64 * 2);
    unsigned short* WtD = (unsigned short*)alloc((size_t)KP_D * 64 * 2);
    unsigned short* WtA = (unsigned short*)alloc((size_t)KP_A * 64 * 2);
    float* ratef   = (float*)alloc(384 * 4);
    float* genderf = (float*)alloc(128 * 4);
    float* agef    = (float*)alloc(448 * 4);
    float* occf    = (float*)alloc(1344 * 4);
    float* areaf   = (float*)alloc((size_t)217728 * 4);
    float* fc1W    = (float*)alloc((size_t)40960 * 4);
    float* fc1b    = (float*)alloc(64 * 4);
    float* fc2W    = (float*)alloc(4096 * 4);
    float* fc2b    = (float*)alloc(64 * 4);
    float* outW    = (float*)alloc(64 * 4);
    float* outb    = (float*)alloc(4);

    // 1. dtype detect
    hipLaunchKernelGGL(k_detect, dim3(1), dim3(64), 0, stream, d_in[14], flag);

    // 2. convert small float tables (embeddings handled by k_cvt_emb later)
    CvtBatch cb;
    int blk = 0, si = 0;
    auto addseg = [&](const void* s, float* d, int n) {
        cb.seg[si].src = s; cb.seg[si].dst = d; cb.seg[si].n = n; cb.seg[si].blk0 = blk;
        blk += (n + 255) / 256; ++si;
    };
    addseg(d_in[6],  ratef,   384);
    addseg(d_in[10], genderf, 128);
    addseg(d_in[11], agef,    448);
    addseg(d_in[12], occf,    1344);
    addseg(d_in[13], areaf,   217728);
    addseg(d_in[16], fc1W,   40960);
    addseg(d_in[17], fc1b,   64);
    addseg(d_in[18], fc2W,   4096);
    addseg(d_in[19], fc2b,   64);
    addseg(d_in[20], outW,   64);
    addseg(d_in[21], outb,   1);
    for (int i = si; i < 16; ++i) { cb.seg[i].src = nullptr; cb.seg[i].dst = nullptr; cb.seg[i].n = 0; cb.seg[i].blk0 = 0x7fffffff; }
    hipLaunchKernelGGL(k_cvt_batch, dim3(blk), dim3(256), 0, stream, cb, flag);

    // 2b. pack multihot W tables
    hipLaunchKernelGGL(k_wt, dim3(((KP_G + KP_D + KP_A) * 64 + 255) / 256), dim3(256), 0, stream,
                       d_in[7], d_in[8], d_in[9], WtG, WtD, WtA, flag);

    // 3. CSR build: hist -> scan -> dinv -> bases -> P1 bin -> P2 sort
    hipLaunchKernelGGL(k_zero, dim3((2 * 180224 + 255) / 256), dim3(256), 0, stream, cnt, 2 * 180224);
    hipLaunchKernelGGL(k_zero, dim3((3 * BATCH * 64 + 3 * BATCH + 255) / 256), dim3(256), 0, stream,
                       (int*)Xmh, 3 * BATCH * 64 + 3 * BATCH);
    hipLaunchKernelGGL(k_hist, dim3((E2 + 255) / 256), dim3(256), 0, stream, grow, cnt);
    hipLaunchKernelGGL(k_scan_partial, dim3(SCAN_NBLK), dim3(SCAN_BS), 0, stream, cnt, part, 180001);
    hipLaunchKernelGGL(k_scan_part_ex, dim3(1), dim3(64), 0, stream, part);
    hipLaunchKernelGGL(k_scan_final, dim3(SCAN_NBLK), dim3(SCAN_BS), 0, stream, cnt, part, offs, 180001);
    hipLaunchKernelGGL(k_dinv, dim3((180224 + 255) / 256), dim3(256), 0, stream, cnt, dinv, dsq, gsc);
    hipLaunchKernelGGL(k_bases, dim3(1), dim3(512), 0, stream, offs, bucketcur);
    hipLaunchKernelGGL(k_p1, dim3((E2 + 4095) / 4096), dim3(256), 0, stream, grow, gcol, bucketcur, binned);
    hipLaunchKernelGGL(k_p2, dim3(NBKT), dim3(256), 0, stream, binned, offs, cols);
    hipLaunchKernelGGL(k_cvt_emb, dim3((N_NODES * 16 + 255) / 256), dim3(256), 0, stream,
                       d_in[14], d_in[15], dinv, embA, flag);
    hipLaunchKernelGGL(k_mark, dim3(2048 / 4), dim3(256), 0, stream, offs, cols, uids, iids, mark);

    // 4. LightGCN (f-domain, backward-pruned)
    dim3 spmvGrid((N_NODES + 3) / 4), wg(256);
    dim3 taccGrid(2048 / 4);
    hipLaunchKernelGGL(k_tacc0, taccGrid, wg, 0, stream, d_in[14], d_in[15], tacc, uids, iids, flag);
    hipLaunchKernelGGL(k_spmv, spmvGrid, wg, 0, stream, embA, embB, offs, cols, dsq, (const int*)nullptr);
    hipLaunchKernelGGL(k_tacc, taccGrid, wg, 0, stream, embB, tacc, uids, iids, gsc);
    hipLaunchKernelGGL(k_spmv, spmvGrid, wg, 0, stream, embB, embA, offs, cols, dsq, mark);
    hipLaunchKernelGGL(k_tacc, taccGrid, wg, 0, stream, embA, tacc, uids, iids, gsc);
    hipLaunchKernelGGL(k_spmv3, taccGrid, wg, 0, stream, embA, tacc, offs, cols, dinv, uids, iids);

    // 5. assemble X
    hipLaunchKernelGGL(k_xsmall, dim3(BATCH / 4), wg, 0, stream, aux, ratef, genderf, agef, occf, areaf, tacc, X);
    hipLaunchKernelGGL(k_mhgemm, dim3(352), wg, 0, stream, aux, WtG, WtD, WtA, Xmh, cntf);
    hipLaunchKernelGGL(k_norm, dim3((3 * BATCH + 3) / 4), wg, 0, stream, Xmh, cntf, X);

    // 6. fused MLP -> out
    hipLaunchKernelGGL(k_mlp, dim3(BATCH / 4), wg, 0, stream, X, fc1W, fc1b, fc2W, fc2b, outW, outb, d_out, flag);
}

// Round 7
// 425.674 us; speedup vs baseline: 2.8798x; 1.0039x over previous
//
#include <hip/hip_runtime.h>
#include <hip/hip_bf16.h>
#include <hip/hip_fp16.h>

#define N_USER 150000
#define M_ITEM 30000
#define N_NODES 180000
#define E2 1200000
#define BATCH 1024
#define AUX_W 10246
#define SCAN_BS 256
#define SCAN_EPB 2048
#define SCAN_NBLK 88   // ceil(180001/2048)
#define KP_G 32
#define KP_D 2208
#define KP_A 8064
#define NBKT 265       // 147 user buckets (1024 rows) + 118 item buckets (256 rows)

typedef __attribute__((ext_vector_type(8))) short short8;
typedef __attribute__((ext_vector_type(4))) float f32x4;

__device__ __forceinline__ int bucket_of(int r) {
    return r < N_USER ? (r >> 10) : 147 + ((r - N_USER) >> 8);
}

// ---------------- dtype detector: bf16 vs f32 float inputs ----------------
__global__ void k_detect(const void* probe, int* flag) {
    int lane = threadIdx.x;
    float v = __bfloat162float(((const __hip_bfloat16*)probe)[lane]);
    bool big = !(fabsf(v) < 1000.0f);
    unsigned long long m = __ballot(big);
    if (lane == 0) *flag = (__popcll(m) > 8) ? 1 : 0;
}

// ---------------- batched float-input conversion to f32 ----------------
struct CvtSeg { const void* src; float* dst; int n; int blk0; };
struct CvtBatch { CvtSeg seg[16]; };

__global__ void __launch_bounds__(256) k_cvt_batch(CvtBatch cb, const int* flag) {
    int blk = blockIdx.x;
    int si = 0;
    #pragma unroll
    for (int i = 0; i < 16; ++i) if (blk >= cb.seg[i].blk0) si = i;
    const CvtSeg sg = cb.seg[si];
    int i = (blk - sg.blk0) * 256 + threadIdx.x;
    if (i >= sg.n) return;
    if (*flag) sg.dst[i] = ((const float*)sg.src)[i];
    else       sg.dst[i] = __bfloat162float(((const __hip_bfloat16*)sg.src)[i]);
}

// ---------------- scaled embedding conversion: embA = fp16(dinv[r] * raw) ---
__global__ void __launch_bounds__(256) k_cvt_emb(const void* rawU, const void* rawI,
                                                 const float* __restrict__ dinv,
                                                 __half* __restrict__ emb, const int* flag) {
    int q = blockIdx.x * 256 + threadIdx.x;          // quad index (4 elems)
    if (q >= N_NODES * 16) return;
    int r = q >> 4;
    const void* src; size_t qq;
    if (r < N_USER) { src = rawU; qq = (size_t)q; }
    else            { src = rawI; qq = (size_t)q - (size_t)N_USER * 16; }
    float d = dinv[r];
    float4 v;
    if (*flag) {
        v = ((const float4*)src)[qq];
    } else {
        ushort4 u = ((const ushort4*)src)[qq];
        v.x = __bfloat162float(*(__hip_bfloat16*)&u.x);
        v.y = __bfloat162float(*(__hip_bfloat16*)&u.y);
        v.z = __bfloat162float(*(__hip_bfloat16*)&u.z);
        v.w = __bfloat162float(*(__hip_bfloat16*)&u.w);
    }
    __half h0 = __float2half(v.x * d), h1 = __float2half(v.y * d);
    __half h2 = __float2half(v.z * d), h3 = __float2half(v.w * d);
    ushort4 o = { *(unsigned short*)&h0, *(unsigned short*)&h1,
                  *(unsigned short*)&h2, *(unsigned short*)&h3 };
    ((ushort4*)emb)[(size_t)q] = o;
}

// ---------------- pack multihot W tables into B-fragment order ----------
__global__ void __launch_bounds__(256) k_wt(const void* Wg, const void* Wd, const void* Wa,
                                            unsigned short* WtG, unsigned short* WtD, unsigned short* WtA,
                                            const int* flag) {
    int t = blockIdx.x * 256 + threadIdx.x;
    if (t >= (KP_G + KP_D + KP_A) * 64) return;
    int kp = t >> 6, n = t & 63;
    int k, K; const void* src; unsigned short* dst;
    if (kp < KP_G)              { k = kp;                K = 25;   src = Wg; dst = WtG; }
    else if (kp < KP_G + KP_D)  { k = kp - KP_G;         K = 2186; src = Wd; dst = WtD; }
    else                        { k = kp - KP_G - KP_D;  K = 8030; src = Wa; dst = WtA; }
    unsigned short v = 0;
    if (k < K) {
        if (*flag) {
            __hip_bfloat16 h = __float2bfloat16(((const float*)src)[(size_t)k * 64 + n]);
            v = *(unsigned short*)&h;
        } else {
            v = ((const unsigned short*)src)[(size_t)k * 64 + n];
        }
    }
    dst[(((size_t)(k >> 5) * 64 + n) * 4 + ((k >> 3) & 3)) * 8 + (k & 7)] = v;
}

// ---------------- CSR build ----------------
__global__ void __launch_bounds__(256) k_zero(int* p, int n) {
    int i = blockIdx.x * 256 + threadIdx.x;
    if (i < n) p[i] = 0;
}

__global__ void __launch_bounds__(256) k_hist(const int* __restrict__ row, int* __restrict__ cnt) {
    int i = blockIdx.x * 256 + threadIdx.x;
    if (i < E2) atomicAdd(&cnt[row[i]], 1);
}

__global__ void __launch_bounds__(SCAN_BS) k_scan_partial(const int* __restrict__ cnt, int* __restrict__ part, int n) {
    __shared__ int sd[SCAN_BS];
    int base = blockIdx.x * SCAN_EPB;
    int s = 0;
    #pragma unroll
    for (int j = 0; j < 8; ++j) {
        int idx = base + j * SCAN_BS + threadIdx.x;
        if (idx < n) s += cnt[idx];
    }
    sd[threadIdx.x] = s; __syncthreads();
    for (int off = SCAN_BS / 2; off; off >>= 1) {
        if (threadIdx.x < off) sd[threadIdx.x] += sd[threadIdx.x + off];
        __syncthreads();
    }
    if (threadIdx.x == 0) part[blockIdx.x] = sd[0];
}

__global__ void k_scan_part_ex(int* part) {
    if (threadIdx.x == 0) {
        int s = 0;
        for (int i = 0; i < SCAN_NBLK; ++i) { int v = part[i]; part[i] = s; s += v; }
    }
}

__global__ void __launch_bounds__(SCAN_BS) k_scan_final(const int* __restrict__ cnt, const int* __restrict__ part,
                                                        int* __restrict__ offs, int n) {
    __shared__ int sw[SCAN_BS];
    int base = blockIdx.x * SCAN_EPB + threadIdx.x * 8;
    int v[8];
    int s = 0;
    #pragma unroll
    for (int j = 0; j < 8; ++j) { int idx = base + j; v[j] = (idx < n) ? cnt[idx] : 0; }
    #pragma unroll
    for (int j = 0; j < 8; ++j) { int t = v[j]; v[j] = s; s += t; }
    sw[threadIdx.x] = s; __syncthreads();
    for (int off = 1; off < 256; off <<= 1) {
        int t = (threadIdx.x >= off) ? sw[threadIdx.x - off] : 0;
        __syncthreads();
        sw[threadIdx.x] += t;
        __syncthreads();
    }
    int toff = (threadIdx.x > 0 ? sw[threadIdx.x - 1] : 0) + part[blockIdx.x];
    #pragma unroll
    for (int j = 0; j < 8; ++j) {
        int idx = base + j;
        if (idx < n) offs[idx] = v[j] + toff;
    }
}

// dinv = rsqrt(deg); dsq = 1/deg; g = sqrt(deg) (all 0 if deg==0)
__global__ void __launch_bounds__(256) k_dinv(const int* __restrict__ cnt, float* __restrict__ dinv,
                                              float* __restrict__ dsq, float* __restrict__ g) {
    int i = blockIdx.x * 256 + threadIdx.x;
    if (i >= 180224) return;
    float deg = (float)cnt[i];
    bool nz = deg > 0.f;
    dinv[i] = nz ? rsqrtf(deg) : 0.f;
    dsq[i]  = nz ? 1.f / deg : 0.f;
    g[i]    = nz ? sqrtf(deg) : 0.f;
}

__global__ void k_bases(const int* __restrict__ offs, int* __restrict__ bucketcur) {
    int b = threadIdx.x;
    if (b >= NBKT) return;
    int r0 = (b < 147) ? (b << 10) : N_USER + ((b - 147) << 8);
    bucketcur[b] = offs[r0];
}

// ---------------- P1: bin edges into NBKT row-range buckets ----------------
__global__ void __launch_bounds__(256) k_p1(const int* __restrict__ grow, const int* __restrict__ gcol,
                                            int* __restrict__ bucketcur, int2* __restrict__ binned) {
    __shared__ int h1[NBKT], base1[NBKT];
    int tid = threadIdx.x;
    for (int i = tid; i < NBKT; i += 256) h1[i] = 0;
    __syncthreads();
    int idx0 = blockIdx.x * 4096;
    int r[16], c[16];
    #pragma unroll
    for (int k = 0; k < 16; ++k) {
        int i = idx0 + k * 256 + tid;
        if (i < E2) {
            r[k] = grow[i]; c[k] = gcol[i];
            atomicAdd(&h1[bucket_of(r[k])], 1);
        } else r[k] = -1;
    }
    __syncthreads();
    for (int i = tid; i < NBKT; i += 256) {
        base1[i] = h1[i] ? atomicAdd(&bucketcur[i], h1[i]) : 0;
        h1[i] = 0;
    }
    __syncthreads();
    #pragma unroll
    for (int k = 0; k < 16; ++k) {
        if (r[k] >= 0) {
            int b = bucket_of(r[k]);
            int p = base1[b] + atomicAdd(&h1[b], 1);
            binned[p] = make_int2(r[k], c[k]);
        }
    }
}

// ---------------- P2: sort each bucket into final CSR order ----------------
// cols[] stores col<<7 (byte offset into a 64-half row).
__global__ void __launch_bounds__(256) k_p2(const int2* __restrict__ binned, const int* __restrict__ offs,
                                            int* __restrict__ cols) {
    __shared__ int h[1024];
    __shared__ int ws2[256];
    int b = blockIdx.x, tid = threadIdx.x;
    int r0, r1;
    if (b < 147) { r0 = b << 10; r1 = min((b + 1) << 10, N_USER); }
    else         { r0 = N_USER + ((b - 147) << 8); r1 = min(N_USER + ((b - 146) << 8), N_NODES); }
    int s0 = offs[r0], e0 = offs[r1];
    for (int i = tid; i < 1024; i += 256) h[i] = 0;
    __syncthreads();
    for (int j = s0 + tid; j < e0; j += 256) atomicAdd(&h[binned[j].x - r0], 1);
    __syncthreads();
    int t0 = tid * 4;
    int a0 = h[t0], a1 = h[t0 + 1], a2 = h[t0 + 2], a3 = h[t0 + 3];
    ws2[tid] = a0 + a1 + a2 + a3;
    __syncthreads();
    for (int off = 1; off < 256; off <<= 1) {
        int v = (tid >= off) ? ws2[tid - off] : 0;
        __syncthreads();
        ws2[tid] += v;
        __syncthreads();
    }
    int excl = tid ? ws2[tid - 1] : 0;
    h[t0]     = excl;
    h[t0 + 1] = excl + a0;
    h[t0 + 2] = excl + a0 + a1;
    h[t0 + 3] = excl + a0 + a1 + a2;
    __syncthreads();
    for (int j = s0 + tid; j < e0; j += 256) {
        int2 e = binned[j];
        int p = s0 + atomicAdd(&h[e.x - r0], 1);
        cols[p] = e.y << 7;
    }
}

// ---------------- mark: layer-2 rows = T ∪ N(T); also seed mark2 with T ----
__global__ void __launch_bounds__(256) k_mark(const int* __restrict__ offs, const int* __restrict__ cols,
                                              const int* __restrict__ uids, const int* __restrict__ iids,
                                              int* __restrict__ mark, int* __restrict__ mark2) {
    int lane = threadIdx.x & 63;
    int t = blockIdx.x * 4 + (threadIdx.x >> 6);
    if (t >= 2048) return;
    int r = (t < BATCH) ? uids[t] : (N_USER + iids[t - BATCH]);
    if (lane == 0) { mark[r] = 1; mark2[r] = 1; }
    int s = offs[r], e = offs[r + 1];
    for (int j = s + lane; j < e; j += 64) mark[(unsigned)cols[j] >> 7] = 1;
}

// ---------------- mark2: layer-1 rows = T ∪ N(mark) ------------------------
__global__ void __launch_bounds__(256) k_mark2(const int* __restrict__ offs, const int* __restrict__ cols,
                                               const int* __restrict__ mark, int* __restrict__ mark2) {
    int lane = threadIdx.x & 63;
    int wid = blockIdx.x * 4 + (threadIdx.x >> 6);
    if (wid >= N_NODES) return;
    if (mark[wid] == 0) return;
    int s = offs[wid], e = offs[wid + 1];
    for (int j = s + lane; j < e; j += 64) mark2[(unsigned)cols[j] >> 7] = 1;
}

// ---------------- f-domain SpMV (fp16 storage, f32 accumulate) -------------
__global__ void __launch_bounds__(256, 4) k_spmv(const __half* __restrict__ src, __half* __restrict__ dst,
                                                 const int* __restrict__ offs, const int* __restrict__ cols,
                                                 const float* __restrict__ dsq, const int* __restrict__ mark) {
    int lane = threadIdx.x & 63;
    int wid = blockIdx.x * 4 + (threadIdx.x >> 6);
    if (wid >= N_NODES) return;
    if (mark && mark[wid] == 0) return;
    int s = offs[wid], e = offs[wid + 1];
    const char* sb = (const char*)src + (lane << 1);
    float acc = 0.f;
    int j0 = s;
    for (; j0 + 8 <= e; j0 += 8) {
        int c[8];
        #pragma unroll
        for (int u = 0; u < 8; ++u) c[u] = cols[j0 + u];
        float v[8];
        #pragma unroll
        for (int u = 0; u < 8; ++u) v[u] = __half2float(*(const __half*)(sb + (size_t)(unsigned)c[u]));
        #pragma unroll
        for (int u = 0; u < 8; ++u) acc += v[u];
    }
    if (j0 < e) {
        int c[8]; float w[8];
        #pragma unroll
        for (int u = 0; u < 8; ++u) {
            int j = j0 + u;
            c[u] = cols[min(j, e - 1)];
            w[u] = (j < e) ? 1.f : 0.f;
        }
        float v[8];
        #pragma unroll
        for (int u = 0; u < 8; ++u) v[u] = __half2float(*(const __half*)(sb + (size_t)(unsigned)c[u]));
        #pragma unroll
        for (int u = 0; u < 8; ++u) acc = fmaf(w[u], v[u], acc);
    }
    dst[(size_t)wid * 64 + lane] = __float2half(dsq[wid] * acc);
}

// ---------------- layer-3 SpMV fused into tacc: += dinv[r] * sum f2[c] -----
__global__ void __launch_bounds__(256, 4) k_spmv3(const __half* __restrict__ src, float* __restrict__ tacc,
                                                  const int* __restrict__ offs, const int* __restrict__ cols,
                                                  const float* __restrict__ dinv,
                                                  const int* __restrict__ uids, const int* __restrict__ iids) {
    int lane = threadIdx.x & 63;
    int t = blockIdx.x * 4 + (threadIdx.x >> 6);
    if (t >= 2048) return;
    int r = (t < BATCH) ? uids[t] : (N_USER + iids[t - BATCH]);
    int s = offs[r], e = offs[r + 1];
    const char* sb = (const char*)src + (lane << 1);
    float acc = 0.f;
    int j0 = s;
    for (; j0 + 8 <= e; j0 += 8) {
        int c[8];
        #pragma unroll
        for (int u = 0; u < 8; ++u) c[u] = cols[j0 + u];
        float v[8];
        #pragma unroll
        for (int u = 0; u < 8; ++u) v[u] = __half2float(*(const __half*)(sb + (size_t)(unsigned)c[u]));
        #pragma unroll
        for (int u = 0; u < 8; ++u) acc += v[u];
    }
    if (j0 < e) {
        int c[8]; float w[8];
        #pragma unroll
        for (int u = 0; u < 8; ++u) {
            int j = j0 + u;
            c[u] = cols[min(j, e - 1)];
            w[u] = (j < e) ? 1.f : 0.f;
        }
        float v[8];
        #pragma unroll
        for (int u = 0; u < 8; ++u) v[u] = __half2float(*(const __half*)(sb + (size_t)(unsigned)c[u]));
        #pragma unroll
        for (int u = 0; u < 8; ++u) acc = fmaf(w[u], v[u], acc);
    }
    tacc[(size_t)t * 64 + lane] += dinv[r] * acc;
}

// ---------------- tacc init from RAW tables (deg-0 rows keep emb0) ---------
__global__ void __launch_bounds__(256) k_tacc0(const void* rawU, const void* rawI, float* __restrict__ tacc,
                                               const int* __restrict__ uids, const int* __restrict__ iids,
                                               const int* flag) {
    int lane = threadIdx.x & 63;
    int t = blockIdx.x * 4 + (threadIdx.x >> 6);
    if (t >= 2048) return;
    const void* src; size_t ri;
    if (t < BATCH) { src = rawU; ri = (size_t)uids[t]; }
    else           { src = rawI; ri = (size_t)iids[t - BATCH]; }
    float v;
    if (*flag) v = ((const float*)src)[ri * 64 + lane];
    else       v = __bfloat162float(((const __hip_bfloat16*)src)[ri * 64 + lane]);
    tacc[(size_t)t * 64 + lane] = v;
}

// ---------------- tacc layers: += f_l[r] * g[r] ---------------------------
__global__ void __launch_bounds__(256) k_tacc(const __half* __restrict__ emb, float* __restrict__ tacc,
                                              const int* __restrict__ uids, const int* __restrict__ iids,
                                              const float* __restrict__ g) {
    int lane = threadIdx.x & 63;
    int t = blockIdx.x * 4 + (threadIdx.x >> 6);
    if (t >= 2048) return;
    int r = (t < BATCH) ? uids[t] : (N_USER + iids[t - BATCH]);
    tacc[(size_t)t * 64 + lane] += __half2float(emb[(size_t)r * 64 + lane]) * g[r];
}

// ---------------- X assembly ----------------
__global__ void __launch_bounds__(256) k_xsmall(const int* __restrict__ aux,
                                                const float* __restrict__ ratef, const float* __restrict__ genderf,
                                                const float* __restrict__ agef, const float* __restrict__ occf,
                                                const float* __restrict__ areaf, const float* __restrict__ tacc,
                                                float* __restrict__ X) {
    int lane = threadIdx.x & 63;
    int b = blockIdx.x * 4 + (threadIdx.x >> 6);
    if (b >= BATCH) return;
    const int* arow = aux + (size_t)b * AUX_W;
    float* xr = X + (size_t)b * 640;
    xr[0   + lane] = ratef[arow[0] * 64 + lane];
    xr[256 + lane] = genderf[arow[10242] * 64 + lane];
    xr[320 + lane] = agef[arow[10243] * 64 + lane];
    xr[384 + lane] = occf[arow[10244] * 64 + lane];
    xr[448 + lane] = areaf[arow[10245] * 64 + lane];
    xr[512 + lane] = tacc[(size_t)b * 64 + lane] * 0.25f;
    xr[576 + lane] = tacc[(size_t)(BATCH + b) * 64 + lane] * 0.25f;
}

// ---------------- multihot as dense MFMA GEMM ----------------------------
__global__ void __launch_bounds__(256) k_mhgemm(const int* __restrict__ aux,
                                                const unsigned short* __restrict__ WtG,
                                                const unsigned short* __restrict__ WtD,
                                                const unsigned short* __restrict__ WtA,
                                                float* __restrict__ Xmh, float* __restrict__ cntf) {
    int blk = blockIdx.x;
    int seg, rb, k0, klen, Kseg, auxoff;
    const unsigned short* Wt;
    if (blk < 16)      { seg = 0; rb = blk;                      k0 = 0;              klen = 25;                    Kseg = 25;   auxoff = 1;    Wt = WtG; }
    else if (blk < 96) { int t = blk - 16; seg = 1; rb = t & 15; k0 = (t >> 4) * 512; klen = min(512, 2186 - k0);   Kseg = 2186; auxoff = 26;   Wt = WtD; }
    else               { int t = blk - 96; seg = 2; rb = t & 15; k0 = (t >> 4) * 512; klen = min(512, 8030 - k0);   Kseg = 8030; auxoff = 2212; Wt = WtA; }
    int lane = threadIdx.x & 63, wave = threadIdx.x >> 6;
    int m = lane & 15, quad = lane >> 4;
    int row = rb * 64 + wave * 16 + m;
    const int* arow = aux + (size_t)row * AUX_W + auxoff;

    f32x4 acc0 = {0.f,0.f,0.f,0.f}, acc1 = acc0, acc2 = acc0, acc3 = acc0;
    float asum = 0.f;
    int nchunk = (klen + 31) >> 5;
    for (int kci = 0; kci < nchunk; ++kci) {
        int kb = k0 + kci * 32 + quad * 8;
        short8 af;
        if (kb + 8 <= Kseg) {
            #pragma unroll
            for (int j = 0; j < 8; ++j) {
                int x = arow[kb + j];
                af[j] = x ? (short)0x3F80 : (short)0;
                asum += (float)x;
            }
        } else {
            #pragma unroll
            for (int j = 0; j < 8; ++j) {
                int x = (kb + j < Kseg) ? arow[kb + j] : 0;
                af[j] = x ? (short)0x3F80 : (short)0;
                asum += (float)x;
            }
        }
        size_t kcg = (size_t)(k0 >> 5) + kci;
        const unsigned short* bp = Wt + ((kcg * 64 + m) * 4 + quad) * 8;
        short8 b0 = *(const short8*)(bp);
        short8 b1 = *(const short8*)(bp + 512);
        short8 b2 = *(const short8*)(bp + 1024);
        short8 b3 = *(const short8*)(bp + 1536);
        acc0 = __builtin_amdgcn_mfma_f32_16x16x32_bf16(af, b0, acc0, 0, 0, 0);
        acc1 = __builtin_amdgcn_mfma_f32_16x16x32_bf16(af, b1, acc1, 0, 0, 0);
        acc2 = __builtin_amdgcn_mfma_f32_16x16x32_bf16(af, b2, acc2, 0, 0, 0);
        acc3 = __builtin_amdgcn_mfma_f32_16x16x32_bf16(af, b3, acc3, 0, 0, 0);
    }
    asum += __shfl_xor(asum, 16);
    asum += __shfl_xor(asum, 32);
    if (quad == 0) atomicAdd(&cntf[seg * BATCH + row], asum);
    float* xbase = Xmh + ((size_t)seg * BATCH + rb * 64 + wave * 16 + quad * 4) * 64;
    #pragma unroll
    for (int reg = 0; reg < 4; ++reg) {
        float* xr = xbase + (size_t)reg * 64;
        atomicAdd(&xr[ 0 + m], acc0[reg]);
        atomicAdd(&xr[16 + m], acc1[reg]);
        atomicAdd(&xr[32 + m], acc2[reg]);
        atomicAdd(&xr[48 + m], acc3[reg]);
    }
}

__global__ void __launch_bounds__(256) k_norm(const float* __restrict__ Xmh, const float* __restrict__ cntf,
                                              float* __restrict__ X) {
    int lane = threadIdx.x & 63;
    int t = blockIdx.x * 4 + (threadIdx.x >> 6);
    if (t >= 3 * BATCH) return;
    int seg = t >> 10, b = t & 1023;
    X[(size_t)b * 640 + 64 + seg * 64 + lane] = Xmh[(size_t)t * 64 + lane] / cntf[t];
}

// ---------------- fused MLP ----------------
__global__ void __launch_bounds__(256) k_mlp(const float* __restrict__ X,
                                             const float* __restrict__ W1, const float* __restrict__ b1,
                                             const float* __restrict__ W2, const float* __restrict__ b2,
                                             const float* __restrict__ Wo, const float* __restrict__ bo,
                                             void* __restrict__ out, const int* flag) {
    int lane = threadIdx.x & 63, w = threadIdx.x >> 6;
    int b = blockIdx.x * 4 + w;
    const float* xr = X + (size_t)b * 640;
    float acc = b1[lane];
    #pragma unroll 8
    for (int k = 0; k < 640; ++k) acc += xr[k] * W1[(size_t)k * 64 + lane];
    float h1 = fmaxf(acc, 0.f);
    __shared__ float sh[4][64];
    sh[w][lane] = h1;
    __syncthreads();
    float acc2 = b2[lane];
    #pragma unroll 8
    for (int j = 0; j < 64; ++j) acc2 += sh[w][j] * W2[(size_t)j * 64 + lane];
    float h2 = fmaxf(acc2, 0.f);
    float p = h2 * Wo[lane];
    #pragma unroll
    for (int off = 32; off; off >>= 1) p += __shfl_down(p, off);
    if (lane == 0) {
        float r = p + bo[0];
        if (*flag) ((float*)out)[b] = r;
        else       ((__hip_bfloat16*)out)[b] = __float2bfloat16(r);
    }
}

extern "C" void kernel_launch(void* const* d_in, const int* in_sizes, int n_in,
                              void* d_out, int out_size, void* d_ws, size_t ws_size,
                              hipStream_t stream) {
    const int* aux  = (const int*)d_in[0];
    const int* uids = (const int*)d_in[1];
    const int* iids = (const int*)d_in[2];
    const int* grow = (const int*)d_in[3];
    const int* gcol = (const int*)d_in[4];

    char* p = (char*)d_ws;
    auto alloc = [&](size_t bytes) -> char* {
        char* r = p;
        p += (bytes + 255) / 256 * 256;
        return r;
    };
    int*   flag      = (int*)alloc(4);
    int*   cnt       = (int*)alloc((size_t)180224 * 4);
    int*   mark      = (int*)alloc((size_t)180224 * 4);   // cnt/mark/mark2 contiguous: one zero pass
    int*   mark2     = (int*)alloc((size_t)180224 * 4);
    int*   offs      = (int*)alloc((size_t)180224 * 4);
    float* dinv      = (float*)alloc((size_t)180224 * 4);
    float* dsq       = (float*)alloc((size_t)180224 * 4);
    float* gsc       = (float*)alloc((size_t)180224 * 4);
    int*   part      = (int*)alloc(256 * 4);
    int*   bucketcur = (int*)alloc(512 * 4);
    int2*  binned    = (int2*)alloc((size_t)E2 * 8);
    int*   cols      = (int*)alloc((size_t)E2 * 4);
    __half* embA     = (__half*)alloc((size_t)N_NODES * 64 * 2);
    __half* embB     = (__half*)alloc((size_t)N_NODES * 64 * 2);
    float* tacc      = (float*)alloc((size_t)2048 * 64 * 4);
    float* X         = (float*)alloc((size_t)BATCH * 640 * 4);
    float* Xmh       = (float*)alloc((size_t)3 * BATCH * 64 * 4);
    float* cntf      = (float*)alloc((size_t)3 * BATCH * 4);
    unsigned short* WtG = (unsigned short*)alloc((size_t)KP_G * 64 * 2);
    unsigned short* WtD = (unsigned short*)alloc((size_t)KP_D * 64 * 2);
    unsigned short* WtA = (unsigned short*)alloc((size_t)KP_A * 64 * 2);
    float* ratef   = (float*)alloc(384 * 4);
    float* genderf = (float*)alloc(128 * 4);
    float* agef    = (float*)alloc(448 * 4);
    float* occf    = (float*)alloc(1344 * 4);
    float* areaf   = (float*)alloc((size_t)217728 * 4);
    float* fc1W    = (float*)alloc((size_t)40960 * 4);
    float* fc1b    = (float*)alloc(64 * 4);
    float* fc2W    = (float*)alloc(4096 * 4);
    float* fc2b    = (float*)alloc(64 * 4);
    float* outW    = (float*)alloc(64 * 4);
    float* outb    = (float*)alloc(4);

    // 1. dtype detect
    hipLaunchKernelGGL(k_detect, dim3(1), dim3(64), 0, stream, d_in[14], flag);

    // 2. convert small float tables
    CvtBatch cb;
    int blk = 0, si = 0;
    auto addseg = [&](const void* s, float* d, int n) {
        cb.seg[si].src = s; cb.seg[si].dst = d; cb.seg[si].n = n; cb.seg[si].blk0 = blk;
        blk += (n + 255) / 256; ++si;
    };
    addseg(d_in[6],  ratef,   384);
    addseg(d_in[10], genderf, 128);
    addseg(d_in[11], agef,    448);
    addseg(d_in[12], occf,    1344);
    addseg(d_in[13], areaf,   217728);
    addseg(d_in[16], fc1W,   40960);
    addseg(d_in[17], fc1b,   64);
    addseg(d_in[18], fc2W,   4096);
    addseg(d_in[19], fc2b,   64);
    addseg(d_in[20], outW,   64);
    addseg(d_in[21], outb,   1);
    for (int i = si; i < 16; ++i) { cb.seg[i].src = nullptr; cb.seg[i].dst = nullptr; cb.seg[i].n = 0; cb.seg[i].blk0 = 0x7fffffff; }
    hipLaunchKernelGGL(k_cvt_batch, dim3(blk), dim3(256), 0, stream, cb, flag);

    // 2b. pack multihot W tables
    hipLaunchKernelGGL(k_wt, dim3(((KP_G + KP_D + KP_A) * 64 + 255) / 256), dim3(256), 0, stream,
                       d_in[7], d_in[8], d_in[9], WtG, WtD, WtA, flag);

    // 3. CSR build
    hipLaunchKernelGGL(k_zero, dim3((3 * 180224 + 255) / 256), dim3(256), 0, stream, cnt, 3 * 180224);
    hipLaunchKernelGGL(k_zero, dim3((3 * BATCH * 64 + 3 * BATCH + 255) / 256), dim3(256), 0, stream,
                       (int*)Xmh, 3 * BATCH * 64 + 3 * BATCH);
    hipLaunchKernelGGL(k_hist, dim3((E2 + 255) / 256), dim3(256), 0, stream, grow, cnt);
    hipLaunchKernelGGL(k_scan_partial, dim3(SCAN_NBLK), dim3(SCAN_BS), 0, stream, cnt, part, 180001);
    hipLaunchKernelGGL(k_scan_part_ex, dim3(1), dim3(64), 0, stream, part);
    hipLaunchKernelGGL(k_scan_final, dim3(SCAN_NBLK), dim3(SCAN_BS), 0, stream, cnt, part, offs, 180001);
    hipLaunchKernelGGL(k_dinv, dim3((180224 + 255) / 256), dim3(256), 0, stream, cnt, dinv, dsq, gsc);
    hipLaunchKernelGGL(k_bases, dim3(1), dim3(512), 0, stream, offs, bucketcur);
    hipLaunchKernelGGL(k_p1, dim3((E2 + 4095) / 4096), dim3(256), 0, stream, grow, gcol, bucketcur, binned);
    hipLaunchKernelGGL(k_p2, dim3(NBKT), dim3(256), 0, stream, binned, offs, cols);
    hipLaunchKernelGGL(k_cvt_emb, dim3((N_NODES * 16 + 255) / 256), dim3(256), 0, stream,
                       d_in[14], d_in[15], dinv, embA, flag);
    hipLaunchKernelGGL(k_mark, dim3(2048 / 4), dim3(256), 0, stream, offs, cols, uids, iids, mark, mark2);
    hipLaunchKernelGGL(k_mark2, dim3((N_NODES + 3) / 4), dim3(256), 0, stream, offs, cols, mark, mark2);

    // 4. LightGCN (f-domain fp16, backward-pruned: L1 over mark2, L2 over mark, L3 at T)
    dim3 spmvGrid((N_NODES + 3) / 4), wg(256);
    dim3 taccGrid(2048 / 4);
    hipLaunchKernelGGL(k_tacc0, taccGrid, wg, 0, stream, d_in[14], d_in[15], tacc, uids, iids, flag);
    hipLaunchKernelGGL(k_spmv, spmvGrid, wg, 0, stream, embA, embB, offs, cols, dsq, mark2);
    hipLaunchKernelGGL(k_tacc, taccGrid, wg, 0, stream, embB, tacc, uids, iids, gsc);
    hipLaunchKernelGGL(k_spmv, spmvGrid, wg, 0, stream, embB, embA, offs, cols, dsq, mark);
    hipLaunchKernelGGL(k_tacc, taccGrid, wg, 0, stream, embA, tacc, uids, iids, gsc);
    hipLaunchKernelGGL(k_spmv3, taccGrid, wg, 0, stream, embA, tacc, offs, cols, dinv, uids, iids);

    // 5. assemble X
    hipLaunchKernelGGL(k_xsmall, dim3(BATCH / 4), wg, 0, stream, aux, ratef, genderf, agef, occf, areaf, tacc, X);
    hipLaunchKernelGGL(k_mhgemm, dim3(352), wg, 0, stream, aux, WtG, WtD, WtA, Xmh, cntf);
    hipLaunchKernelGGL(k_norm, dim3((3 * BATCH + 3) / 4), wg, 0, stream, Xmh, cntf, X);

    // 6. fused MLP -> out
    hipLaunchKernelGGL(k_mlp, dim3(BATCH / 4), wg, 0, stream, X, fc1W, fc1b, fc2W, fc2b, outW, outb, d_out, flag);
}

// Round 8
// 381.086 us; speedup vs baseline: 3.2167x; 1.1170x over previous
//
#include <hip/hip_runtime.h>
#include <hip/hip_bf16.h>
#include <hip/hip_fp16.h>

#define N_USER 150000
#define M_ITEM 30000
#define N_NODES 180000
#define E2 1200000
#define BATCH 1024
#define AUX_W 10246
#define KP_G 32
#define KP_D 2208
#define KP_A 8064
#define NBKT 265       // 147 user buckets (1024 rows) + 118 item buckets (256 rows)

typedef __attribute__((ext_vector_type(8))) short short8;
typedef __attribute__((ext_vector_type(4))) float f32x4;

__device__ __forceinline__ int bucket_of(int r) {
    return r < N_USER ? (r >> 10) : 147 + ((r - N_USER) >> 8);
}

// ---------------- dtype detector: bf16 vs f32 float inputs ----------------
__global__ void k_detect(const void* probe, int* flag) {
    int lane = threadIdx.x;
    float v = __bfloat162float(((const __hip_bfloat16*)probe)[lane]);
    bool big = !(fabsf(v) < 1000.0f);
    unsigned long long m = __ballot(big);
    if (lane == 0) *flag = (__popcll(m) > 8) ? 1 : 0;
}

// ---------------- batched float-input conversion to f32 ----------------
struct CvtSeg { const void* src; float* dst; int n; int blk0; };
struct CvtBatch { CvtSeg seg[16]; };

__global__ void __launch_bounds__(256) k_cvt_batch(CvtBatch cb, const int* flag) {
    int blk = blockIdx.x;
    int si = 0;
    #pragma unroll
    for (int i = 0; i < 16; ++i) if (blk >= cb.seg[i].blk0) si = i;
    const CvtSeg sg = cb.seg[si];
    int i = (blk - sg.blk0) * 256 + threadIdx.x;
    if (i >= sg.n) return;
    if (*flag) sg.dst[i] = ((const float*)sg.src)[i];
    else       sg.dst[i] = __bfloat162float(((const __hip_bfloat16*)sg.src)[i]);
}

// ---------------- scaled embedding conversion: embA = fp16(dinv[r] * raw) ---
__global__ void __launch_bounds__(256) k_cvt_emb(const void* rawU, const void* rawI,
                                                 const float* __restrict__ dinv,
                                                 __half* __restrict__ emb, const int* flag) {
    int q = blockIdx.x * 256 + threadIdx.x;          // quad index (4 elems)
    if (q >= N_NODES * 16) return;
    int r = q >> 4;
    const void* src; size_t qq;
    if (r < N_USER) { src = rawU; qq = (size_t)q; }
    else            { src = rawI; qq = (size_t)q - (size_t)N_USER * 16; }
    float d = dinv[r];
    float4 v;
    if (*flag) {
        v = ((const float4*)src)[qq];
    } else {
        ushort4 u = ((const ushort4*)src)[qq];
        v.x = __bfloat162float(*(__hip_bfloat16*)&u.x);
        v.y = __bfloat162float(*(__hip_bfloat16*)&u.y);
        v.z = __bfloat162float(*(__hip_bfloat16*)&u.z);
        v.w = __bfloat162float(*(__hip_bfloat16*)&u.w);
    }
    __half h0 = __float2half(v.x * d), h1 = __float2half(v.y * d);
    __half h2 = __float2half(v.z * d), h3 = __float2half(v.w * d);
    ushort4 o = { *(unsigned short*)&h0, *(unsigned short*)&h1,
                  *(unsigned short*)&h2, *(unsigned short*)&h3 };
    ((ushort4*)emb)[(size_t)q] = o;
}

// ---------------- pack multihot W tables into B-fragment order ----------
__global__ void __launch_bounds__(256) k_wt(const void* Wg, const void* Wd, const void* Wa,
                                            unsigned short* WtG, unsigned short* WtD, unsigned short* WtA,
                                            const int* flag) {
    int t = blockIdx.x * 256 + threadIdx.x;
    if (t >= (KP_G + KP_D + KP_A) * 64) return;
    int kp = t >> 6, n = t & 63;
    int k, K; const void* src; unsigned short* dst;
    if (kp < KP_G)              { k = kp;                K = 25;   src = Wg; dst = WtG; }
    else if (kp < KP_G + KP_D)  { k = kp - KP_G;         K = 2186; src = Wd; dst = WtD; }
    else                        { k = kp - KP_G - KP_D;  K = 8030; src = Wa; dst = WtA; }
    unsigned short v = 0;
    if (k < K) {
        if (*flag) {
            __hip_bfloat16 h = __float2bfloat16(((const float*)src)[(size_t)k * 64 + n]);
            v = *(unsigned short*)&h;
        } else {
            v = ((const unsigned short*)src)[(size_t)k * 64 + n];
        }
    }
    dst[(((size_t)(k >> 5) * 64 + n) * 4 + ((k >> 3) & 3)) * 8 + (k & 7)] = v;
}

// ---------------- misc ----------------
__global__ void __launch_bounds__(256) k_zero(int* p, int n) {
    int i = blockIdx.x * 256 + threadIdx.x;
    if (i < n) p[i] = 0;
}

// ---------------- bucket counts: LDS hist -> 265 global atomics/block ------
__global__ void __launch_bounds__(256) k_bcnt(const int* __restrict__ grow, int* __restrict__ bucket_tot) {
    __shared__ int h[NBKT];
    int tid = threadIdx.x;
    for (int i = tid; i < NBKT; i += 256) h[i] = 0;
    __syncthreads();
    int idx0 = blockIdx.x * 4096;
    #pragma unroll
    for (int k = 0; k < 16; ++k) {
        int i = idx0 + k * 256 + tid;
        if (i < E2) atomicAdd(&h[bucket_of(grow[i])], 1);
    }
    __syncthreads();
    for (int i = tid; i < NBKT; i += 256) if (h[i]) atomicAdd(&bucket_tot[i], h[i]);
}

// ---------------- bucket scan: bucket_base = excl scan; offs[N]=E2 ---------
__global__ void __launch_bounds__(512) k_bscan(const int* __restrict__ bucket_tot,
                                               int* __restrict__ bucket_base,
                                               int* __restrict__ bucketcur,
                                               int* __restrict__ offs) {
    __shared__ int s[512];
    int tid = threadIdx.x;
    s[tid] = (tid < NBKT) ? bucket_tot[tid] : 0;
    __syncthreads();
    for (int off = 1; off < 512; off <<= 1) {
        int v = (tid >= off) ? s[tid - off] : 0;
        __syncthreads();
        s[tid] += v;
        __syncthreads();
    }
    int excl = tid ? s[tid - 1] : 0;
    bucket_base[tid] = excl;                 // bucket_base[NBKT] = E2
    if (tid < NBKT) bucketcur[tid] = excl;
    if (tid == 0) offs[N_NODES] = E2;
}

// ---------------- P1: bin edges into NBKT row-range buckets ----------------
__global__ void __launch_bounds__(256) k_p1(const int* __restrict__ grow, const int* __restrict__ gcol,
                                            int* __restrict__ bucketcur, int2* __restrict__ binned) {
    __shared__ int h1[NBKT], base1[NBKT];
    int tid = threadIdx.x;
    for (int i = tid; i < NBKT; i += 256) h1[i] = 0;
    __syncthreads();
    int idx0 = blockIdx.x * 4096;
    int r[16], c[16];
    #pragma unroll
    for (int k = 0; k < 16; ++k) {
        int i = idx0 + k * 256 + tid;
        if (i < E2) {
            r[k] = grow[i]; c[k] = gcol[i];
            atomicAdd(&h1[bucket_of(r[k])], 1);
        } else r[k] = -1;
    }
    __syncthreads();
    for (int i = tid; i < NBKT; i += 256) {
        base1[i] = h1[i] ? atomicAdd(&bucketcur[i], h1[i]) : 0;
        h1[i] = 0;
    }
    __syncthreads();
    #pragma unroll
    for (int k = 0; k < 16; ++k) {
        if (r[k] >= 0) {
            int b = bucket_of(r[k]);
            int p = base1[b] + atomicAdd(&h1[b], 1);
            binned[p] = make_int2(r[k], c[k]);
        }
    }
}

// ---------------- P2: per-bucket sort + offs + degree factors --------------
// LDS hist of the bucket's <=1024 rows gives degree; LDS scan gives local
// prefix; offs[row] = bucket_base[b] + local_excl. Then scatter cols (<<7).
__global__ void __launch_bounds__(256) k_p2(const int2* __restrict__ binned, const int* __restrict__ bb,
                                            int* __restrict__ cols, int* __restrict__ offs,
                                            float* __restrict__ dinv, float* __restrict__ dsq,
                                            float* __restrict__ gsc) {
    __shared__ int h[1024];
    __shared__ int ws2[256];
    int b = blockIdx.x, tid = threadIdx.x;
    int r0, r1;
    if (b < 147) { r0 = b << 10; r1 = min((b + 1) << 10, N_USER); }
    else         { r0 = N_USER + ((b - 147) << 8); r1 = min(N_USER + ((b - 146) << 8), N_NODES); }
    int s0 = bb[b], e0 = bb[b + 1];
    for (int i = tid; i < 1024; i += 256) h[i] = 0;
    __syncthreads();
    for (int j = s0 + tid; j < e0; j += 256) atomicAdd(&h[binned[j].x - r0], 1);
    __syncthreads();
    int t0 = tid * 4;
    int a0 = h[t0], a1 = h[t0 + 1], a2 = h[t0 + 2], a3 = h[t0 + 3];
    ws2[tid] = a0 + a1 + a2 + a3;
    __syncthreads();
    for (int off = 1; off < 256; off <<= 1) {
        int v = (tid >= off) ? ws2[tid - off] : 0;
        __syncthreads();
        ws2[tid] += v;
        __syncthreads();
    }
    int excl = tid ? ws2[tid - 1] : 0;
    int ex[4] = { excl, excl + a0, excl + a0 + a1, excl + a0 + a1 + a2 };
    int ac[4] = { a0, a1, a2, a3 };
    #pragma unroll
    for (int i = 0; i < 4; ++i) {
        int row = r0 + t0 + i;
        if (row < r1) {
            offs[row] = s0 + ex[i];
            float deg = (float)ac[i];
            bool nz = deg > 0.f;
            dinv[row] = nz ? rsqrtf(deg) : 0.f;
            dsq[row]  = nz ? 1.f / deg  : 0.f;
            gsc[row]  = nz ? sqrtf(deg) : 0.f;
        }
        h[t0 + i] = ex[i];
    }
    __syncthreads();
    for (int j = s0 + tid; j < e0; j += 256) {
        int2 e = binned[j];
        int p = s0 + atomicAdd(&h[e.x - r0], 1);
        cols[p] = e.y << 7;           // byte offset into a 64-half row
    }
}

// ---------------- mark: layer-2 rows = T ∪ N(T); also seed mark2 with T ----
__global__ void __launch_bounds__(256) k_mark(const int* __restrict__ offs, const int* __restrict__ cols,
                                              const int* __restrict__ uids, const int* __restrict__ iids,
                                              int* __restrict__ mark, int* __restrict__ mark2) {
    int lane = threadIdx.x & 63;
    int t = blockIdx.x * 4 + (threadIdx.x >> 6);
    if (t >= 2048) return;
    int r = (t < BATCH) ? uids[t] : (N_USER + iids[t - BATCH]);
    if (lane == 0) { mark[r] = 1; mark2[r] = 1; }
    int s = offs[r], e = offs[r + 1];
    for (int j = s + lane; j < e; j += 64) mark[(unsigned)cols[j] >> 7] = 1;
}

// ---------------- mark2: layer-1 rows = T ∪ N(mark) ------------------------
__global__ void __launch_bounds__(256) k_mark2(const int* __restrict__ offs, const int* __restrict__ cols,
                                               const int* __restrict__ mark, int* __restrict__ mark2) {
    int lane = threadIdx.x & 63;
    int wid = blockIdx.x * 4 + (threadIdx.x >> 6);
    if (wid >= N_NODES) return;
    if (mark[wid] == 0) return;
    int s = offs[wid], e = offs[wid + 1];
    for (int j = s + lane; j < e; j += 64) mark2[(unsigned)cols[j] >> 7] = 1;
}

// ---------------- f-domain SpMV (fp16 storage, f32 accumulate) -------------
__global__ void __launch_bounds__(256, 4) k_spmv(const __half* __restrict__ src, __half* __restrict__ dst,
                                                 const int* __restrict__ offs, const int* __restrict__ cols,
                                                 const float* __restrict__ dsq, const int* __restrict__ mark) {
    int lane = threadIdx.x & 63;
    int wid = blockIdx.x * 4 + (threadIdx.x >> 6);
    if (wid >= N_NODES) return;
    if (mark && mark[wid] == 0) return;
    int s = offs[wid], e = offs[wid + 1];
    const char* sb = (const char*)src + (lane << 1);
    float acc = 0.f;
    int j0 = s;
    for (; j0 + 8 <= e; j0 += 8) {
        int c[8];
        #pragma unroll
        for (int u = 0; u < 8; ++u) c[u] = cols[j0 + u];
        float v[8];
        #pragma unroll
        for (int u = 0; u < 8; ++u) v[u] = __half2float(*(const __half*)(sb + (size_t)(unsigned)c[u]));
        #pragma unroll
        for (int u = 0; u < 8; ++u) acc += v[u];
    }
    if (j0 < e) {
        int c[8]; float w[8];
        #pragma unroll
        for (int u = 0; u < 8; ++u) {
            int j = j0 + u;
            c[u] = cols[min(j, e - 1)];
            w[u] = (j < e) ? 1.f : 0.f;
        }
        float v[8];
        #pragma unroll
        for (int u = 0; u < 8; ++u) v[u] = __half2float(*(const __half*)(sb + (size_t)(unsigned)c[u]));
        #pragma unroll
        for (int u = 0; u < 8; ++u) acc = fmaf(w[u], v[u], acc);
    }
    dst[(size_t)wid * 64 + lane] = __float2half(dsq[wid] * acc);
}

// ---------------- layer-3 SpMV fused into tacc: += dinv[r] * sum f2[c] -----
__global__ void __launch_bounds__(256, 4) k_spmv3(const __half* __restrict__ src, float* __restrict__ tacc,
                                                  const int* __restrict__ offs, const int* __restrict__ cols,
                                                  const float* __restrict__ dinv,
                                                  const int* __restrict__ uids, const int* __restrict__ iids) {
    int lane = threadIdx.x & 63;
    int t = blockIdx.x * 4 + (threadIdx.x >> 6);
    if (t >= 2048) return;
    int r = (t < BATCH) ? uids[t] : (N_USER + iids[t - BATCH]);
    int s = offs[r], e = offs[r + 1];
    const char* sb = (const char*)src + (lane << 1);
    float acc = 0.f;
    int j0 = s;
    for (; j0 + 8 <= e; j0 += 8) {
        int c[8];
        #pragma unroll
        for (int u = 0; u < 8; ++u) c[u] = cols[j0 + u];
        float v[8];
        #pragma unroll
        for (int u = 0; u < 8; ++u) v[u] = __half2float(*(const __half*)(sb + (size_t)(unsigned)c[u]));
        #pragma unroll
        for (int u = 0; u < 8; ++u) acc += v[u];
    }
    if (j0 < e) {
        int c[8]; float w[8];
        #pragma unroll
        for (int u = 0; u < 8; ++u) {
            int j = j0 + u;
            c[u] = cols[min(j, e - 1)];
            w[u] = (j < e) ? 1.f : 0.f;
        }
        float v[8];
        #pragma unroll
        for (int u = 0; u < 8; ++u) v[u] = __half2float(*(const __half*)(sb + (size_t)(unsigned)c[u]));
        #pragma unroll
        for (int u = 0; u < 8; ++u) acc = fmaf(w[u], v[u], acc);
    }
    tacc[(size_t)t * 64 + lane] += dinv[r] * acc;
}

// ---------------- tacc init from RAW tables (deg-0 rows keep emb0) ---------
__global__ void __launch_bounds__(256) k_tacc0(const void* rawU, const void* rawI, float* __restrict__ tacc,
                                               const int* __restrict__ uids, const int* __restrict__ iids,
                                               const int* flag) {
    int lane = threadIdx.x & 63;
    int t = blockIdx.x * 4 + (threadIdx.x >> 6);
    if (t >= 2048) return;
    const void* src; size_t ri;
    if (t < BATCH) { src = rawU; ri = (size_t)uids[t]; }
    else           { src = rawI; ri = (size_t)iids[t - BATCH]; }
    float v;
    if (*flag) v = ((const float*)src)[ri * 64 + lane];
    else       v = __bfloat162float(((const __hip_bfloat16*)src)[ri * 64 + lane]);
    tacc[(size_t)t * 64 + lane] = v;
}

// ---------------- tacc layers: += f_l[r] * g[r] ---------------------------
__global__ void __launch_bounds__(256) k_tacc(const __half* __restrict__ emb, float* __restrict__ tacc,
                                              const int* __restrict__ uids, const int* __restrict__ iids,
                                              const float* __restrict__ g) {
    int lane = threadIdx.x & 63;
    int t = blockIdx.x * 4 + (threadIdx.x >> 6);
    if (t >= 2048) return;
    int r = (t < BATCH) ? uids[t] : (N_USER + iids[t - BATCH]);
    tacc[(size_t)t * 64 + lane] += __half2float(emb[(size_t)r * 64 + lane]) * g[r];
}

// ---------------- X assembly ----------------
__global__ void __launch_bounds__(256) k_xsmall(const int* __restrict__ aux,
                                                const float* __restrict__ ratef, const float* __restrict__ genderf,
                                                const float* __restrict__ agef, const float* __restrict__ occf,
                                                const float* __restrict__ areaf, const float* __restrict__ tacc,
                                                float* __restrict__ X) {
    int lane = threadIdx.x & 63;
    int b = blockIdx.x * 4 + (threadIdx.x >> 6);
    if (b >= BATCH) return;
    const int* arow = aux + (size_t)b * AUX_W;
    float* xr = X + (size_t)b * 640;
    xr[0   + lane] = ratef[arow[0] * 64 + lane];
    xr[256 + lane] = genderf[arow[10242] * 64 + lane];
    xr[320 + lane] = agef[arow[10243] * 64 + lane];
    xr[384 + lane] = occf[arow[10244] * 64 + lane];
    xr[448 + lane] = areaf[arow[10245] * 64 + lane];
    xr[512 + lane] = tacc[(size_t)b * 64 + lane] * 0.25f;
    xr[576 + lane] = tacc[(size_t)(BATCH + b) * 64 + lane] * 0.25f;
}

// ---------------- multihot as dense MFMA GEMM ----------------------------
__global__ void __launch_bounds__(256) k_mhgemm(const int* __restrict__ aux,
                                                const unsigned short* __restrict__ WtG,
                                                const unsigned short* __restrict__ WtD,
                                                const unsigned short* __restrict__ WtA,
                                                float* __restrict__ Xmh, float* __restrict__ cntf) {
    int blk = blockIdx.x;
    int seg, rb, k0, klen, Kseg, auxoff;
    const unsigned short* Wt;
    if (blk < 16)      { seg = 0; rb = blk;                      k0 = 0;              klen = 25;                    Kseg = 25;   auxoff = 1;    Wt = WtG; }
    else if (blk < 96) { int t = blk - 16; seg = 1; rb = t & 15; k0 = (t >> 4) * 512; klen = min(512, 2186 - k0);   Kseg = 2186; auxoff = 26;   Wt = WtD; }
    else               { int t = blk - 96; seg = 2; rb = t & 15; k0 = (t >> 4) * 512; klen = min(512, 8030 - k0);   Kseg = 8030; auxoff = 2212; Wt = WtA; }
    int lane = threadIdx.x & 63, wave = threadIdx.x >> 6;
    int m = lane & 15, quad = lane >> 4;
    int row = rb * 64 + wave * 16 + m;
    const int* arow = aux + (size_t)row * AUX_W + auxoff;

    f32x4 acc0 = {0.f,0.f,0.f,0.f}, acc1 = acc0, acc2 = acc0, acc3 = acc0;
    float asum = 0.f;
    int nchunk = (klen + 31) >> 5;
    for (int kci = 0; kci < nchunk; ++kci) {
        int kb = k0 + kci * 32 + quad * 8;
        short8 af;
        if (kb + 8 <= Kseg) {
            #pragma unroll
            for (int j = 0; j < 8; ++j) {
                int x = arow[kb + j];
                af[j] = x ? (short)0x3F80 : (short)0;
                asum += (float)x;
            }
        } else {
            #pragma unroll
            for (int j = 0; j < 8; ++j) {
                int x = (kb + j < Kseg) ? arow[kb + j] : 0;
                af[j] = x ? (short)0x3F80 : (short)0;
                asum += (float)x;
            }
        }
        size_t kcg = (size_t)(k0 >> 5) + kci;
        const unsigned short* bp = Wt + ((kcg * 64 + m) * 4 + quad) * 8;
        short8 b0 = *(const short8*)(bp);
        short8 b1 = *(const short8*)(bp + 512);
        short8 b2 = *(const short8*)(bp + 1024);
        short8 b3 = *(const short8*)(bp + 1536);
        acc0 = __builtin_amdgcn_mfma_f32_16x16x32_bf16(af, b0, acc0, 0, 0, 0);
        acc1 = __builtin_amdgcn_mfma_f32_16x16x32_bf16(af, b1, acc1, 0, 0, 0);
        acc2 = __builtin_amdgcn_mfma_f32_16x16x32_bf16(af, b2, acc2, 0, 0, 0);
        acc3 = __builtin_amdgcn_mfma_f32_16x16x32_bf16(af, b3, acc3, 0, 0, 0);
    }
    asum += __shfl_xor(asum, 16);
    asum += __shfl_xor(asum, 32);
    if (quad == 0) atomicAdd(&cntf[seg * BATCH + row], asum);
    float* xbase = Xmh + ((size_t)seg * BATCH + rb * 64 + wave * 16 + quad * 4) * 64;
    #pragma unroll
    for (int reg = 0; reg < 4; ++reg) {
        float* xr = xbase + (size_t)reg * 64;
        atomicAdd(&xr[ 0 + m], acc0[reg]);
        atomicAdd(&xr[16 + m], acc1[reg]);
        atomicAdd(&xr[32 + m], acc2[reg]);
        atomicAdd(&xr[48 + m], acc3[reg]);
    }
}

__global__ void __launch_bounds__(256) k_norm(const float* __restrict__ Xmh, const float* __restrict__ cntf,
                                              float* __restrict__ X) {
    int lane = threadIdx.x & 63;
    int t = blockIdx.x * 4 + (threadIdx.x >> 6);
    if (t >= 3 * BATCH) return;
    int seg = t >> 10, b = t & 1023;
    X[(size_t)b * 640 + 64 + seg * 64 + lane] = Xmh[(size_t)t * 64 + lane] / cntf[t];
}

// ---------------- fused MLP ----------------
__global__ void __launch_bounds__(256) k_mlp(const float* __restrict__ X,
                                             const float* __restrict__ W1, const float* __restrict__ b1,
                                             const float* __restrict__ W2, const float* __restrict__ b2,
                                             const float* __restrict__ Wo, const float* __restrict__ bo,
                                             void* __restrict__ out, const int* flag) {
    int lane = threadIdx.x & 63, w = threadIdx.x >> 6;
    int b = blockIdx.x * 4 + w;
    const float* xr = X + (size_t)b * 640;
    float acc = b1[lane];
    #pragma unroll 8
    for (int k = 0; k < 640; ++k) acc += xr[k] * W1[(size_t)k * 64 + lane];
    float h1 = fmaxf(acc, 0.f);
    __shared__ float sh[4][64];
    sh[w][lane] = h1;
    __syncthreads();
    float acc2 = b2[lane];
    #pragma unroll 8
    for (int j = 0; j < 64; ++j) acc2 += sh[w][j] * W2[(size_t)j * 64 + lane];
    float h2 = fmaxf(acc2, 0.f);
    float p = h2 * Wo[lane];
    #pragma unroll
    for (int off = 32; off; off >>= 1) p += __shfl_down(p, off);
    if (lane == 0) {
        float r = p + bo[0];
        if (*flag) ((float*)out)[b] = r;
        else       ((__hip_bfloat16*)out)[b] = __float2bfloat16(r);
    }
}

extern "C" void kernel_launch(void* const* d_in, const int* in_sizes, int n_in,
                              void* d_out, int out_size, void* d_ws, size_t ws_size,
                              hipStream_t stream) {
    const int* aux  = (const int*)d_in[0];
    const int* uids = (const int*)d_in[1];
    const int* iids = (const int*)d_in[2];
    const int* grow = (const int*)d_in[3];
    const int* gcol = (const int*)d_in[4];

    char* p = (char*)d_ws;
    auto alloc = [&](size_t bytes) -> char* {
        char* r = p;
        p += (bytes + 255) / 256 * 256;
        return r;
    };
    int*   flag        = (int*)alloc(4);
    int*   mark        = (int*)alloc((size_t)180224 * 4);   // mark/mark2/bucket_tot contiguous: one zero pass
    int*   mark2       = (int*)alloc((size_t)180224 * 4);
    int*   bucket_tot  = (int*)alloc(512 * 4);
    int*   bucket_base = (int*)alloc(512 * 4);
    int*   bucketcur   = (int*)alloc(512 * 4);
    int*   offs        = (int*)alloc((size_t)180224 * 4);
    float* dinv        = (float*)alloc((size_t)180224 * 4);
    float* dsq         = (float*)alloc((size_t)180224 * 4);
    float* gsc         = (float*)alloc((size_t)180224 * 4);
    int2*  binned      = (int2*)alloc((size_t)E2 * 8);
    int*   cols        = (int*)alloc((size_t)E2 * 4);
    __half* embA       = (__half*)alloc((size_t)N_NODES * 64 * 2);
    __half* embB       = (__half*)alloc((size_t)N_NODES * 64 * 2);
    float* tacc        = (float*)alloc((size_t)2048 * 64 * 4);
    float* X           = (float*)alloc((size_t)BATCH * 640 * 4);
    float* Xmh         = (float*)alloc((size_t)3 * BATCH * 64 * 4);
    float* cntf        = (float*)alloc((size_t)3 * BATCH * 4);
    unsigned short* WtG = (unsigned short*)alloc((size_t)KP_G * 64 * 2);
    unsigned short* WtD = (unsigned short*)alloc((size_t)KP_D * 64 * 2);
    unsigned short* WtA = (unsigned short*)alloc((size_t)KP_A * 64 * 2);
    float* ratef   = (float*)alloc(384 * 4);
    float* genderf = (float*)alloc(128 * 4);
    float* agef    = (float*)alloc(448 * 4);
    float* occf    = (float*)alloc(1344 * 4);
    float* areaf   = (float*)alloc((size_t)217728 * 4);
    float* fc1W    = (float*)alloc((size_t)40960 * 4);
    float* fc1b    = (float*)alloc(64 * 4);
    float* fc2W    = (float*)alloc(4096 * 4);
    float* fc2b    = (float*)alloc(64 * 4);
    float* outW    = (float*)alloc(64 * 4);
    float* outb    = (float*)alloc(4);

    // 1. dtype detect
    hipLaunchKernelGGL(k_detect, dim3(1), dim3(64), 0, stream, d_in[14], flag);

    // 2. convert small float tables
    CvtBatch cb;
    int blk = 0, si = 0;
    auto addseg = [&](const void* s, float* d, int n) {
        cb.seg[si].src = s; cb.seg[si].dst = d; cb.seg[si].n = n; cb.seg[si].blk0 = blk;
        blk += (n + 255) / 256; ++si;
    };
    addseg(d_in[6],  ratef,   384);
    addseg(d_in[10], genderf, 128);
    addseg(d_in[11], agef,    448);
    addseg(d_in[12], occf,    1344);
    addseg(d_in[13], areaf,   217728);
    addseg(d_in[16], fc1W,   40960);
    addseg(d_in[17], fc1b,   64);
    addseg(d_in[18], fc2W,   4096);
    addseg(d_in[19], fc2b,   64);
    addseg(d_in[20], outW,   64);
    addseg(d_in[21], outb,   1);
    for (int i = si; i < 16; ++i) { cb.seg[i].src = nullptr; cb.seg[i].dst = nullptr; cb.seg[i].n = 0; cb.seg[i].blk0 = 0x7fffffff; }
    hipLaunchKernelGGL(k_cvt_batch, dim3(blk), dim3(256), 0, stream, cb, flag);

    // 2b. pack multihot W tables
    hipLaunchKernelGGL(k_wt, dim3(((KP_G + KP_D + KP_A) * 64 + 255) / 256), dim3(256), 0, stream,
                       d_in[7], d_in[8], d_in[9], WtG, WtD, WtA, flag);

    // 3. CSR build: bucket counts -> bucket scan -> P1 bin -> P2 sort(+offs+dinv)
    hipLaunchKernelGGL(k_zero, dim3((2 * 180224 + 512 + 255) / 256), dim3(256), 0, stream, mark, 2 * 180224 + 512);
    hipLaunchKernelGGL(k_zero, dim3((3 * BATCH * 64 + 3 * BATCH + 255) / 256), dim3(256), 0, stream,
                       (int*)Xmh, 3 * BATCH * 64 + 3 * BATCH);
    hipLaunchKernelGGL(k_bcnt, dim3((E2 + 4095) / 4096), dim3(256), 0, stream, grow, bucket_tot);
    hipLaunchKernelGGL(k_bscan, dim3(1), dim3(512), 0, stream, bucket_tot, bucket_base, bucketcur, offs);
    hipLaunchKernelGGL(k_p1, dim3((E2 + 4095) / 4096), dim3(256), 0, stream, grow, gcol, bucketcur, binned);
    hipLaunchKernelGGL(k_p2, dim3(NBKT), dim3(256), 0, stream, binned, bucket_base, cols, offs, dinv, dsq, gsc);
    hipLaunchKernelGGL(k_cvt_emb, dim3((N_NODES * 16 + 255) / 256), dim3(256), 0, stream,
                       d_in[14], d_in[15], dinv, embA, flag);
    hipLaunchKernelGGL(k_mark, dim3(2048 / 4), dim3(256), 0, stream, offs, cols, uids, iids, mark, mark2);
    hipLaunchKernelGGL(k_mark2, dim3((N_NODES + 3) / 4), dim3(256), 0, stream, offs, cols, mark, mark2);

    // 4. LightGCN (f-domain fp16, backward-pruned: L1 over mark2, L2 over mark, L3 at T)
    dim3 spmvGrid((N_NODES + 3) / 4), wg(256);
    dim3 taccGrid(2048 / 4);
    hipLaunchKernelGGL(k_tacc0, taccGrid, wg, 0, stream, d_in[14], d_in[15], tacc, uids, iids, flag);
    hipLaunchKernelGGL(k_spmv, spmvGrid, wg, 0, stream, embA, embB, offs, cols, dsq, mark2);
    hipLaunchKernelGGL(k_tacc, taccGrid, wg, 0, stream, embB, tacc, uids, iids, gsc);
    hipLaunchKernelGGL(k_spmv, spmvGrid, wg, 0, stream, embB, embA, offs, cols, dsq, mark);
    hipLaunchKernelGGL(k_tacc, taccGrid, wg, 0, stream, embA, tacc, uids, iids, gsc);
    hipLaunchKernelGGL(k_spmv3, taccGrid, wg, 0, stream, embA, tacc, offs, cols, dinv, uids, iids);

    // 5. assemble X
    hipLaunchKernelGGL(k_xsmall, dim3(BATCH / 4), wg, 0, stream, aux, ratef, genderf, agef, occf, areaf, tacc, X);
    hipLaunchKernelGGL(k_mhgemm, dim3(352), wg, 0, stream, aux, WtG, WtD, WtA, Xmh, cntf);
    hipLaunchKernelGGL(k_norm, dim3((3 * BATCH + 3) / 4), wg, 0, stream, Xmh, cntf, X);

    // 6. fused MLP -> out
    hipLaunchKernelGGL(k_mlp, dim3(BATCH / 4), wg, 0, stream, X, fc1W, fc1b, fc2W, fc2b, outW, outb, d_out, flag);
}

// Round 9
// 356.074 us; speedup vs baseline: 3.4427x; 1.0702x over previous
//
#include <hip/hip_runtime.h>
#include <hip/hip_bf16.h>
#include <hip/hip_fp16.h>

#define N_USER 150000
#define M_ITEM 30000
#define N_NODES 180000
#define E2 1200000
#define BATCH 1024
#define AUX_W 10246
#define KP_G 32
#define KP_D 2208
#define KP_A 8064
#define NBKT 265       // 147 user buckets (1024 rows) + 118 item buckets (256 rows)

typedef __attribute__((ext_vector_type(8))) short short8;
typedef __attribute__((ext_vector_type(4))) float f32x4;

__device__ __forceinline__ int bucket_of(int r) {
    return r < N_USER ? (r >> 10) : 147 + ((r - N_USER) >> 8);
}

// inline dtype detect (wave-uniform): bf16 data reads small; f32-as-bf16 huge.
__device__ __forceinline__ int detect_f32(const void* probe) {
    float v = __bfloat162float(((const __hip_bfloat16*)probe)[threadIdx.x & 63]);
    unsigned long long m = __ballot(!(fabsf(v) < 1000.0f));
    return __popcll(m) > 8;
}

// ---------------- batched float-input conversion to f32 ----------------
struct CvtSeg { const void* src; float* dst; int n; int blk0; };
struct CvtBatch { CvtSeg seg[16]; };

__global__ void __launch_bounds__(256) k_cvt_batch(CvtBatch cb, const void* probe) {
    int isf32 = detect_f32(probe);
    int blk = blockIdx.x;
    int si = 0;
    #pragma unroll
    for (int i = 0; i < 16; ++i) if (blk >= cb.seg[i].blk0) si = i;
    const CvtSeg sg = cb.seg[si];
    int i = (blk - sg.blk0) * 256 + threadIdx.x;
    if (i >= sg.n) return;
    if (isf32) sg.dst[i] = ((const float*)sg.src)[i];
    else       sg.dst[i] = __bfloat162float(((const __hip_bfloat16*)sg.src)[i]);
}

// ---------------- scaled emb conversion + fused tacc0 ----------------------
// Blocks [0,cvtN): embA = fp16(dinv[r]*raw). Blocks [cvtN, cvtN+512): tacc0.
__global__ void __launch_bounds__(256) k_cvt_emb(const void* rawU, const void* rawI,
                                                 const float* __restrict__ dinv,
                                                 __half* __restrict__ emb,
                                                 float* __restrict__ tacc,
                                                 const int* __restrict__ uids,
                                                 const int* __restrict__ iids, int cvtN) {
    int isf32 = detect_f32(rawU);
    if ((int)blockIdx.x >= cvtN) {            // tacc0: init from RAW rows
        int lane = threadIdx.x & 63;
        int t = (blockIdx.x - cvtN) * 4 + (threadIdx.x >> 6);
        const void* src; size_t ri;
        if (t < BATCH) { src = rawU; ri = (size_t)uids[t]; }
        else           { src = rawI; ri = (size_t)iids[t - BATCH]; }
        float v;
        if (isf32) v = ((const float*)src)[ri * 64 + lane];
        else       v = __bfloat162float(((const __hip_bfloat16*)src)[ri * 64 + lane]);
        tacc[(size_t)t * 64 + lane] = v;
        return;
    }
    int q = blockIdx.x * 256 + threadIdx.x;          // quad index (4 elems)
    if (q >= N_NODES * 16) return;
    int r = q >> 4;
    const void* src; size_t qq;
    if (r < N_USER) { src = rawU; qq = (size_t)q; }
    else            { src = rawI; qq = (size_t)q - (size_t)N_USER * 16; }
    float d = dinv[r];
    float4 v;
    if (isf32) {
        v = ((const float4*)src)[qq];
    } else {
        ushort4 u = ((const ushort4*)src)[qq];
        v.x = __bfloat162float(*(__hip_bfloat16*)&u.x);
        v.y = __bfloat162float(*(__hip_bfloat16*)&u.y);
        v.z = __bfloat162float(*(__hip_bfloat16*)&u.z);
        v.w = __bfloat162float(*(__hip_bfloat16*)&u.w);
    }
    __half h0 = __float2half(v.x * d), h1 = __float2half(v.y * d);
    __half h2 = __float2half(v.z * d), h3 = __float2half(v.w * d);
    ushort4 o = { *(unsigned short*)&h0, *(unsigned short*)&h1,
                  *(unsigned short*)&h2, *(unsigned short*)&h3 };
    ((ushort4*)emb)[(size_t)q] = o;
}

// ---------------- pack multihot W tables into B-fragment order ----------
__global__ void __launch_bounds__(256) k_wt(const void* Wg, const void* Wd, const void* Wa,
                                            unsigned short* WtG, unsigned short* WtD, unsigned short* WtA,
                                            const void* probe) {
    int isf32 = detect_f32(probe);
    int t = blockIdx.x * 256 + threadIdx.x;
    if (t >= (KP_G + KP_D + KP_A) * 64) return;
    int kp = t >> 6, n = t & 63;
    int k, K; const void* src; unsigned short* dst;
    if (kp < KP_G)              { k = kp;                K = 25;   src = Wg; dst = WtG; }
    else if (kp < KP_G + KP_D)  { k = kp - KP_G;         K = 2186; src = Wd; dst = WtD; }
    else                        { k = kp - KP_G - KP_D;  K = 8030; src = Wa; dst = WtA; }
    unsigned short v = 0;
    if (k < K) {
        if (isf32) {
            __hip_bfloat16 h = __float2bfloat16(((const float*)src)[(size_t)k * 64 + n]);
            v = *(unsigned short*)&h;
        } else {
            v = ((const unsigned short*)src)[(size_t)k * 64 + n];
        }
    }
    dst[(((size_t)(k >> 5) * 64 + n) * 4 + ((k >> 3) & 3)) * 8 + (k & 7)] = v;
}

// ---------------- misc ----------------
__global__ void __launch_bounds__(256) k_zero(int* p, int n) {
    int i = blockIdx.x * 256 + threadIdx.x;
    if (i < n) p[i] = 0;
}

// ---------------- bucket counts: LDS hist -> 265 global atomics/block ------
__global__ void __launch_bounds__(256) k_bcnt(const int* __restrict__ grow, int* __restrict__ bucket_tot) {
    __shared__ int h[NBKT];
    int tid = threadIdx.x;
    for (int i = tid; i < NBKT; i += 256) h[i] = 0;
    __syncthreads();
    int idx0 = blockIdx.x * 4096;
    #pragma unroll
    for (int k = 0; k < 16; ++k) {
        int i = idx0 + k * 256 + tid;
        if (i < E2) atomicAdd(&h[bucket_of(grow[i])], 1);
    }
    __syncthreads();
    for (int i = tid; i < NBKT; i += 256) if (h[i]) atomicAdd(&bucket_tot[i], h[i]);
}

// ---------------- bucket scan ----------------
__global__ void __launch_bounds__(512) k_bscan(const int* __restrict__ bucket_tot,
                                               int* __restrict__ bucket_base,
                                               int* __restrict__ bucketcur,
                                               int* __restrict__ offs) {
    __shared__ int s[512];
    int tid = threadIdx.x;
    s[tid] = (tid < NBKT) ? bucket_tot[tid] : 0;
    __syncthreads();
    for (int off = 1; off < 512; off <<= 1) {
        int v = (tid >= off) ? s[tid - off] : 0;
        __syncthreads();
        s[tid] += v;
        __syncthreads();
    }
    int excl = tid ? s[tid - 1] : 0;
    bucket_base[tid] = excl;                 // bucket_base[NBKT] = E2
    if (tid < NBKT) bucketcur[tid] = excl;
    if (tid == 0) offs[N_NODES] = E2;
}

// ---------------- P1: bin edges into NBKT row-range buckets ----------------
__global__ void __launch_bounds__(256) k_p1(const int* __restrict__ grow, const int* __restrict__ gcol,
                                            int* __restrict__ bucketcur, int2* __restrict__ binned) {
    __shared__ int h1[NBKT], base1[NBKT];
    int tid = threadIdx.x;
    for (int i = tid; i < NBKT; i += 256) h1[i] = 0;
    __syncthreads();
    int idx0 = blockIdx.x * 4096;
    int r[16], c[16];
    #pragma unroll
    for (int k = 0; k < 16; ++k) {
        int i = idx0 + k * 256 + tid;
        if (i < E2) {
            r[k] = grow[i]; c[k] = gcol[i];
            atomicAdd(&h1[bucket_of(r[k])], 1);
        } else r[k] = -1;
    }
    __syncthreads();
    for (int i = tid; i < NBKT; i += 256) {
        base1[i] = h1[i] ? atomicAdd(&bucketcur[i], h1[i]) : 0;
        h1[i] = 0;
    }
    __syncthreads();
    #pragma unroll
    for (int k = 0; k < 16; ++k) {
        if (r[k] >= 0) {
            int b = bucket_of(r[k]);
            int p = base1[b] + atomicAdd(&h1[b], 1);
            binned[p] = make_int2(r[k], c[k]);
        }
    }
}

// ---------------- P2: per-bucket sort + offs + degree factors --------------
__global__ void __launch_bounds__(256) k_p2(const int2* __restrict__ binned, const int* __restrict__ bb,
                                            int* __restrict__ cols, int* __restrict__ offs,
                                            float* __restrict__ dinv, float* __restrict__ dsq,
                                            float* __restrict__ gsc) {
    __shared__ int h[1024];
    __shared__ int ws2[256];
    int b = blockIdx.x, tid = threadIdx.x;
    int r0, r1;
    if (b < 147) { r0 = b << 10; r1 = min((b + 1) << 10, N_USER); }
    else         { r0 = N_USER + ((b - 147) << 8); r1 = min(N_USER + ((b - 146) << 8), N_NODES); }
    int s0 = bb[b], e0 = bb[b + 1];
    for (int i = tid; i < 1024; i += 256) h[i] = 0;
    __syncthreads();
    for (int j = s0 + tid; j < e0; j += 256) atomicAdd(&h[binned[j].x - r0], 1);
    __syncthreads();
    int t0 = tid * 4;
    int a0 = h[t0], a1 = h[t0 + 1], a2 = h[t0 + 2], a3 = h[t0 + 3];
    ws2[tid] = a0 + a1 + a2 + a3;
    __syncthreads();
    for (int off = 1; off < 256; off <<= 1) {
        int v = (tid >= off) ? ws2[tid - off] : 0;
        __syncthreads();
        ws2[tid] += v;
        __syncthreads();
    }
    int excl = tid ? ws2[tid - 1] : 0;
    int ex[4] = { excl, excl + a0, excl + a0 + a1, excl + a0 + a1 + a2 };
    int ac[4] = { a0, a1, a2, a3 };
    #pragma unroll
    for (int i = 0; i < 4; ++i) {
        int row = r0 + t0 + i;
        if (row < r1) {
            offs[row] = s0 + ex[i];
            float deg = (float)ac[i];
            bool nz = deg > 0.f;
            dinv[row] = nz ? rsqrtf(deg) : 0.f;
            dsq[row]  = nz ? 1.f / deg  : 0.f;
            gsc[row]  = nz ? sqrtf(deg) : 0.f;
        }
        h[t0 + i] = ex[i];
    }
    __syncthreads();
    for (int j = s0 + tid; j < e0; j += 256) {
        int2 e = binned[j];
        int p = s0 + atomicAdd(&h[e.x - r0], 1);
        cols[p] = e.y << 7;           // byte offset into a 64-half row
    }
}

// ---------------- mark: layer-2 rows = T ∪ N(T); seed mark2 with T ---------
__global__ void __launch_bounds__(256) k_mark(const int* __restrict__ offs, const int* __restrict__ cols,
                                              const int* __restrict__ uids, const int* __restrict__ iids,
                                              int* __restrict__ mark, int* __restrict__ mark2) {
    int lane = threadIdx.x & 63;
    int t = blockIdx.x * 4 + (threadIdx.x >> 6);
    if (t >= 2048) return;
    int r = (t < BATCH) ? uids[t] : (N_USER + iids[t - BATCH]);
    if (lane == 0) { mark[r] = 1; mark2[r] = 1; }
    int s = offs[r], e = offs[r + 1];
    for (int j = s + lane; j < e; j += 64) mark[(unsigned)cols[j] >> 7] = 1;
}

// ---------------- mark2: layer-1 rows = T ∪ N(mark) ------------------------
__global__ void __launch_bounds__(256) k_mark2(const int* __restrict__ offs, const int* __restrict__ cols,
                                               const int* __restrict__ mark, int* __restrict__ mark2) {
    int lane = threadIdx.x & 63;
    int wid = blockIdx.x * 4 + (threadIdx.x >> 6);
    if (wid >= N_NODES) return;
    if (mark[wid] == 0) return;
    int s = offs[wid], e = offs[wid + 1];
    for (int j = s + lane; j < e; j += 64) mark2[(unsigned)cols[j] >> 7] = 1;
}

// ---------------- f-domain SpMV, half2 layout ------------------------------
// lane = (p, ep): p in [0,32) feature pair, ep edge parity. Each gather covers
// 2 edges per wave (32 lanes x 4B each). Appended blocks [spmvN, spmvN+512)
// do the tacc += g[r] * src[r] update (reads INPUT buffer -> no hazard).
__global__ void __launch_bounds__(256, 8) k_spmv(const __half* __restrict__ src, __half* __restrict__ dst,
                                                 const int* __restrict__ offs, const int* __restrict__ cols,
                                                 const float* __restrict__ dsq, const int* __restrict__ mark,
                                                 int spmvN, float* __restrict__ tacc,
                                                 const int* __restrict__ uids, const int* __restrict__ iids,
                                                 const float* __restrict__ gsc) {
    int tid = threadIdx.x, lane = tid & 63;
    int blk = blockIdx.x;
    if (blk >= spmvN) {                       // fused tacc layer update
        int t = (blk - spmvN) * 4 + (tid >> 6);
        int r = (t < BATCH) ? uids[t] : (N_USER + iids[t - BATCH]);
        tacc[(size_t)t * 64 + lane] += __half2float(src[(size_t)r * 64 + lane]) * gsc[r];
        return;
    }
    int wid = blk * 4 + (tid >> 6);
    if (wid >= N_NODES) return;
    if (mark && mark[wid] == 0) return;
    int s = offs[wid], e = offs[wid + 1];
    int p = lane & 31, ep = lane >> 5;
    const char* sb = (const char*)src + (p << 2);
    float ax = 0.f, ay = 0.f;
    int j0 = s;
    for (; j0 + 16 <= e; j0 += 16) {          // 16 edges per iter, no clamp
        int c[8];
        #pragma unroll
        for (int u = 0; u < 8; ++u) c[u] = cols[j0 + 2 * u + ep];
        float2 v[8];
        #pragma unroll
        for (int u = 0; u < 8; ++u) v[u] = __half22float2(*(const __half2*)(sb + (size_t)(unsigned)c[u]));
        #pragma unroll
        for (int u = 0; u < 8; ++u) { ax += v[u].x; ay += v[u].y; }
    }
    if (j0 < e) {                             // tail <16 edges, clamped
        int c[8]; float w[8];
        #pragma unroll
        for (int u = 0; u < 8; ++u) {
            int j = j0 + 2 * u + ep;
            c[u] = cols[min(j, e - 1)];
            w[u] = (j < e) ? 1.f : 0.f;
        }
        float2 v[8];
        #pragma unroll
        for (int u = 0; u < 8; ++u) v[u] = __half22float2(*(const __half2*)(sb + (size_t)(unsigned)c[u]));
        #pragma unroll
        for (int u = 0; u < 8; ++u) { ax = fmaf(w[u], v[u].x, ax); ay = fmaf(w[u], v[u].y, ay); }
    }
    ax += __shfl_xor(ax, 32);
    ay += __shfl_xor(ay, 32);
    if (ep == 0) {
        float d = dsq[wid];
        *(__half2*)((char*)dst + ((size_t)wid << 7) + (p << 2)) = __floats2half2_rn(ax * d, ay * d);
    }
}

// ---------------- layer-3 SpMV fused into tacc + self term -----------------
// tacc[t] += g[r]*f2[r] + dinv[r]*sum_{c in N(r)} f2[c]
__global__ void __launch_bounds__(256) k_spmv3(const __half* __restrict__ src, float* __restrict__ tacc,
                                               const int* __restrict__ offs, const int* __restrict__ cols,
                                               const float* __restrict__ dinv, const float* __restrict__ gsc,
                                               const int* __restrict__ uids, const int* __restrict__ iids) {
    int tid = threadIdx.x, lane = tid & 63;
    int t = blockIdx.x * 4 + (tid >> 6);
    if (t >= 2048) return;
    int r = (t < BATCH) ? uids[t] : (N_USER + iids[t - BATCH]);
    int s = offs[r], e = offs[r + 1];
    int p = lane & 31, ep = lane >> 5;
    const char* sb = (const char*)src + (p << 2);
    float ax = 0.f, ay = 0.f;
    int j0 = s;
    for (; j0 + 16 <= e; j0 += 16) {
        int c[8];
        #pragma unroll
        for (int u = 0; u < 8; ++u) c[u] = cols[j0 + 2 * u + ep];
        float2 v[8];
        #pragma unroll
        for (int u = 0; u < 8; ++u) v[u] = __half22float2(*(const __half2*)(sb + (size_t)(unsigned)c[u]));
        #pragma unroll
        for (int u = 0; u < 8; ++u) { ax += v[u].x; ay += v[u].y; }
    }
    if (j0 < e) {
        int c[8]; float w[8];
        #pragma unroll
        for (int u = 0; u < 8; ++u) {
            int j = j0 + 2 * u + ep;
            c[u] = cols[min(j, e - 1)];
            w[u] = (j < e) ? 1.f : 0.f;
        }
        float2 v[8];
        #pragma unroll
        for (int u = 0; u < 8; ++u) v[u] = __half22float2(*(const __half2*)(sb + (size_t)(unsigned)c[u]));
        #pragma unroll
        for (int u = 0; u < 8; ++u) { ax = fmaf(w[u], v[u].x, ax); ay = fmaf(w[u], v[u].y, ay); }
    }
    ax += __shfl_xor(ax, 32);
    ay += __shfl_xor(ay, 32);
    if (ep == 0) {
        float2 self = __half22float2(*(const __half2*)((const char*)src + ((size_t)r << 7) + (p << 2)));
        float di = dinv[r], g = gsc[r];
        float* tp = tacc + (size_t)t * 64 + (p << 1);
        tp[0] += di * ax + g * self.x;
        tp[1] += di * ay + g * self.y;
    }
}

// ---------------- multihot as dense MFMA GEMM ----------------------------
__global__ void __launch_bounds__(256) k_mhgemm(const int* __restrict__ aux,
                                                const unsigned short* __restrict__ WtG,
                                                const unsigned short* __restrict__ WtD,
                                                const unsigned short* __restrict__ WtA,
                                                float* __restrict__ Xmh, float* __restrict__ cntf) {
    int blk = blockIdx.x;
    int seg, rb, k0, klen, Kseg, auxoff;
    const unsigned short* Wt;
    if (blk < 16)      { seg = 0; rb = blk;                      k0 = 0;              klen = 25;                    Kseg = 25;   auxoff = 1;    Wt = WtG; }
    else if (blk < 96) { int t = blk - 16; seg = 1; rb = t & 15; k0 = (t >> 4) * 512; klen = min(512, 2186 - k0);   Kseg = 2186; auxoff = 26;   Wt = WtD; }
    else               { int t = blk - 96; seg = 2; rb = t & 15; k0 = (t >> 4) * 512; klen = min(512, 8030 - k0);   Kseg = 8030; auxoff = 2212; Wt = WtA; }
    int lane = threadIdx.x & 63, wave = threadIdx.x >> 6;
    int m = lane & 15, quad = lane >> 4;
    int row = rb * 64 + wave * 16 + m;
    const int* arow = aux + (size_t)row * AUX_W + auxoff;

    f32x4 acc0 = {0.f,0.f,0.f,0.f}, acc1 = acc0, acc2 = acc0, acc3 = acc0;
    float asum = 0.f;
    int nchunk = (klen + 31) >> 5;
    for (int kci = 0; kci < nchunk; ++kci) {
        int kb = k0 + kci * 32 + quad * 8;
        short8 af;
        if (kb + 8 <= Kseg) {
            #pragma unroll
            for (int j = 0; j < 8; ++j) {
                int x = arow[kb + j];
                af[j] = x ? (short)0x3F80 : (short)0;
                asum += (float)x;
            }
        } else {
            #pragma unroll
            for (int j = 0; j < 8; ++j) {
                int x = (kb + j < Kseg) ? arow[kb + j] : 0;
                af[j] = x ? (short)0x3F80 : (short)0;
                asum += (float)x;
            }
        }
        size_t kcg = (size_t)(k0 >> 5) + kci;
        const unsigned short* bp = Wt + ((kcg * 64 + m) * 4 + quad) * 8;
        short8 b0 = *(const short8*)(bp);
        short8 b1 = *(const short8*)(bp + 512);
        short8 b2 = *(const short8*)(bp + 1024);
        short8 b3 = *(const short8*)(bp + 1536);
        acc0 = __builtin_amdgcn_mfma_f32_16x16x32_bf16(af, b0, acc0, 0, 0, 0);
        acc1 = __builtin_amdgcn_mfma_f32_16x16x32_bf16(af, b1, acc1, 0, 0, 0);
        acc2 = __builtin_amdgcn_mfma_f32_16x16x32_bf16(af, b2, acc2, 0, 0, 0);
        acc3 = __builtin_amdgcn_mfma_f32_16x16x32_bf16(af, b3, acc3, 0, 0, 0);
    }
    asum += __shfl_xor(asum, 16);
    asum += __shfl_xor(asum, 32);
    if (quad == 0) atomicAdd(&cntf[seg * BATCH + row], asum);
    float* xbase = Xmh + ((size_t)seg * BATCH + rb * 64 + wave * 16 + quad * 4) * 64;
    #pragma unroll
    for (int reg = 0; reg < 4; ++reg) {
        float* xr = xbase + (size_t)reg * 64;
        atomicAdd(&xr[ 0 + m], acc0[reg]);
        atomicAdd(&xr[16 + m], acc1[reg]);
        atomicAdd(&xr[32 + m], acc2[reg]);
        atomicAdd(&xr[48 + m], acc3[reg]);
    }
}

// ---------------- fused X-assembly + MLP -----------------------------------
// Block = 4 batch rows (one per wave). X row built in LDS (no global X).
__global__ void __launch_bounds__(256) k_mlp(const int* __restrict__ aux,
                                             const float* __restrict__ ratef, const float* __restrict__ genderf,
                                             const float* __restrict__ agef, const float* __restrict__ occf,
                                             const float* __restrict__ areaf, const float* __restrict__ tacc,
                                             const float* __restrict__ Xmh, const float* __restrict__ cntf,
                                             const float* __restrict__ W1, const float* __restrict__ b1,
                                             const float* __restrict__ W2, const float* __restrict__ b2,
                                             const float* __restrict__ Wo, const float* __restrict__ bo,
                                             void* __restrict__ out, const void* probe) {
    __shared__ float sx[4][640];
    __shared__ float sh[4][64];
    int isf32 = detect_f32(probe);
    int lane = threadIdx.x & 63, w = threadIdx.x >> 6;
    int b = blockIdx.x * 4 + w;
    const int* arow = aux + (size_t)b * AUX_W;
    float* xr = sx[w];
    xr[0   + lane] = ratef[arow[0] * 64 + lane];
    xr[64  + lane] = Xmh[((size_t)0 * BATCH + b) * 64 + lane] / cntf[0 * BATCH + b];
    xr[128 + lane] = Xmh[((size_t)1 * BATCH + b) * 64 + lane] / cntf[1 * BATCH + b];
    xr[192 + lane] = Xmh[((size_t)2 * BATCH + b) * 64 + lane] / cntf[2 * BATCH + b];
    xr[256 + lane] = genderf[arow[10242] * 64 + lane];
    xr[320 + lane] = agef[arow[10243] * 64 + lane];
    xr[384 + lane] = occf[arow[10244] * 64 + lane];
    xr[448 + lane] = areaf[arow[10245] * 64 + lane];
    xr[512 + lane] = tacc[(size_t)b * 64 + lane] * 0.25f;
    xr[576 + lane] = tacc[(size_t)(BATCH + b) * 64 + lane] * 0.25f;
    // wave-local LDS: writes then reads within the same wave are ordered.
    float acc = b1[lane];
    #pragma unroll 8
    for (int k = 0; k < 640; ++k) acc += xr[k] * W1[(size_t)k * 64 + lane];
    float h1 = fmaxf(acc, 0.f);
    sh[w][lane] = h1;
    float acc2 = b2[lane];
    #pragma unroll 8
    for (int j = 0; j < 64; ++j) acc2 += sh[w][j] * W2[(size_t)j * 64 + lane];
    float h2 = fmaxf(acc2, 0.f);
    float p = h2 * Wo[lane];
    #pragma unroll
    for (int off = 32; off; off >>= 1) p += __shfl_down(p, off);
    if (lane == 0) {
        float r = p + bo[0];
        if (isf32) ((float*)out)[b] = r;
        else       ((__hip_bfloat16*)out)[b] = __float2bfloat16(r);
    }
}

extern "C" void kernel_launch(void* const* d_in, const int* in_sizes, int n_in,
                              void* d_out, int out_size, void* d_ws, size_t ws_size,
                              hipStream_t stream) {
    const int* aux  = (const int*)d_in[0];
    const int* uids = (const int*)d_in[1];
    const int* iids = (const int*)d_in[2];
    const int* grow = (const int*)d_in[3];
    const int* gcol = (const int*)d_in[4];

    char* p = (char*)d_ws;
    auto alloc = [&](size_t bytes) -> char* {
        char* r = p;
        p += (bytes + 255) / 256 * 256;
        return r;
    };
    // zero-region: mark, mark2, bucket_tot, Xmh, cntf — contiguous, one k_zero
    int*   mark        = (int*)alloc((size_t)180224 * 4);
    int*   mark2       = (int*)alloc((size_t)180224 * 4);
    int*   bucket_tot  = (int*)alloc(512 * 4);
    float* Xmh         = (float*)alloc((size_t)3 * BATCH * 64 * 4);
    float* cntf        = (float*)alloc((size_t)3 * BATCH * 4);
    const int ZERO_N   = 180224 + 180224 + 512 + 3 * BATCH * 64 + 3 * BATCH;
    int*   bucket_base = (int*)alloc(512 * 4);
    int*   bucketcur   = (int*)alloc(512 * 4);
    int*   offs        = (int*)alloc((size_t)180224 * 4);
    float* dinv        = (float*)alloc((size_t)180224 * 4);
    float* dsq         = (float*)alloc((size_t)180224 * 4);
    float* gsc         = (float*)alloc((size_t)180224 * 4);
    int2*  binned      = (int2*)alloc((size_t)E2 * 8);
    int*   cols        = (int*)alloc((size_t)E2 * 4);
    __half* embA       = (__half*)alloc((size_t)N_NODES * 64 * 2);
    __half* embB       = (__half*)alloc((size_t)N_NODES * 64 * 2);
    float* tacc        = (float*)alloc((size_t)2048 * 64 * 4);
    unsigned short* WtG = (unsigned short*)alloc((size_t)KP_G * 64 * 2);
    unsigned short* WtD = (unsigned short*)alloc((size_t)KP_D * 64 * 2);
    unsigned short* WtA = (unsigned short*)alloc((size_t)KP_A * 64 * 2);
    float* ratef   = (float*)alloc(384 * 4);
    float* genderf = (float*)alloc(128 * 4);
    float* agef    = (float*)alloc(448 * 4);
    float* occf    = (float*)alloc(1344 * 4);
    float* areaf   = (float*)alloc((size_t)217728 * 4);
    float* fc1W    = (float*)alloc((size_t)40960 * 4);
    float* fc1b    = (float*)alloc(64 * 4);
    float* fc2W    = (float*)alloc(4096 * 4);
    float* fc2b    = (float*)alloc(64 * 4);
    float* outW    = (float*)alloc(64 * 4);
    float* outb    = (float*)alloc(4);

    const void* probe = d_in[14];   // user_rel, for inline dtype detect

    // 1. convert small float tables (inline detect)
    CvtBatch cb;
    int blk = 0, si = 0;
    auto addseg = [&](const void* s, float* d, int n) {
        cb.seg[si].src = s; cb.seg[si].dst = d; cb.seg[si].n = n; cb.seg[si].blk0 = blk;
        blk += (n + 255) / 256; ++si;
    };
    addseg(d_in[6],  ratef,   384);
    addseg(d_in[10], genderf, 128);
    addseg(d_in[11], agef,    448);
    addseg(d_in[12], occf,    1344);
    addseg(d_in[13], areaf,   217728);
    addseg(d_in[16], fc1W,   40960);
    addseg(d_in[17], fc1b,   64);
    addseg(d_in[18], fc2W,   4096);
    addseg(d_in[19], fc2b,   64);
    addseg(d_in[20], outW,   64);
    addseg(d_in[21], outb,   1);
    for (int i = si; i < 16; ++i) { cb.seg[i].src = nullptr; cb.seg[i].dst = nullptr; cb.seg[i].n = 0; cb.seg[i].blk0 = 0x7fffffff; }
    hipLaunchKernelGGL(k_cvt_batch, dim3(blk), dim3(256), 0, stream, cb, probe);

    // 2. pack multihot W tables
    hipLaunchKernelGGL(k_wt, dim3(((KP_G + KP_D + KP_A) * 64 + 255) / 256), dim3(256), 0, stream,
                       d_in[7], d_in[8], d_in[9], WtG, WtD, WtA, probe);

    // 3. zero accumulators (single contiguous region)
    hipLaunchKernelGGL(k_zero, dim3((ZERO_N + 255) / 256), dim3(256), 0, stream, mark, ZERO_N);

    // 4. CSR build
    hipLaunchKernelGGL(k_bcnt, dim3((E2 + 4095) / 4096), dim3(256), 0, stream, grow, bucket_tot);
    hipLaunchKernelGGL(k_bscan, dim3(1), dim3(512), 0, stream, bucket_tot, bucket_base, bucketcur, offs);
    hipLaunchKernelGGL(k_p1, dim3((E2 + 4095) / 4096), dim3(256), 0, stream, grow, gcol, bucketcur, binned);
    hipLaunchKernelGGL(k_p2, dim3(NBKT), dim3(256), 0, stream, binned, bucket_base, cols, offs, dinv, dsq, gsc);

    // 5. emb conversion (+fused tacc0), mark bitmaps
    const int cvtN = (N_NODES * 16 + 255) / 256;
    hipLaunchKernelGGL(k_cvt_emb, dim3(cvtN + 512), dim3(256), 0, stream,
                       d_in[14], d_in[15], dinv, embA, tacc, uids, iids, cvtN);
    hipLaunchKernelGGL(k_mark, dim3(2048 / 4), dim3(256), 0, stream, offs, cols, uids, iids, mark, mark2);
    hipLaunchKernelGGL(k_mark2, dim3((N_NODES + 3) / 4), dim3(256), 0, stream, offs, cols, mark, mark2);

    // 6. LightGCN: L1 over mark2; L2 over mark (+fused tacc f1); L3 at T (+self)
    const int spmvN = (N_NODES + 3) / 4;
    hipLaunchKernelGGL(k_spmv, dim3(spmvN), dim3(256), 0, stream,
                       embA, embB, offs, cols, dsq, mark2, spmvN, (float*)nullptr, uids, iids, gsc);
    hipLaunchKernelGGL(k_spmv, dim3(spmvN + 512), dim3(256), 0, stream,
                       embB, embA, offs, cols, dsq, mark, spmvN, tacc, uids, iids, gsc);
    hipLaunchKernelGGL(k_spmv3, dim3(2048 / 4), dim3(256), 0, stream,
                       embA, tacc, offs, cols, dinv, gsc, uids, iids);

    // 7. multihot GEMM, fused X+MLP -> out
    hipLaunchKernelGGL(k_mhgemm, dim3(352), dim3(256), 0, stream, aux, WtG, WtD, WtA, Xmh, cntf);
    hipLaunchKernelGGL(k_mlp, dim3(BATCH / 4), dim3(256), 0, stream,
                       aux, ratef, genderf, agef, occf, areaf, tacc, Xmh, cntf,
                       fc1W, fc1b, fc2W, fc2b, outW, outb, d_out, probe);
}

// Round 10
// 353.445 us; speedup vs baseline: 3.4683x; 1.0074x over previous
//
#include <hip/hip_runtime.h>
#include <hip/hip_bf16.h>
#include <hip/hip_fp16.h>

#define N_USER 150000
#define M_ITEM 30000
#define N_NODES 180000
#define E2 1200000
#define BATCH 1024
#define AUX_W 10246
#define KP_G 32
#define KP_D 2208
#define KP_A 8064
#define NBKT 265       // 147 user buckets (1024 rows) + 118 item buckets (256 rows)
#define WT_BLKS 2576   // ((KP_G+KP_D+KP_A)*64 + 255)/256
#define BCNT_BLKS 293  // (E2 + 4095)/4096

typedef __attribute__((ext_vector_type(8))) short short8;
typedef __attribute__((ext_vector_type(4))) float f32x4;

__device__ __forceinline__ int bucket_of(int r) {
    return r < N_USER ? (r >> 10) : 147 + ((r - N_USER) >> 8);
}

// inline dtype detect (wave-uniform): bf16 data reads small; f32-as-bf16 huge.
__device__ __forceinline__ int detect_f32(const void* probe) {
    float v = __bfloat162float(((const __hip_bfloat16*)probe)[threadIdx.x & 63]);
    unsigned long long m = __ballot(!(fabsf(v) < 1000.0f));
    return __popcll(m) > 8;
}

// ---------------- fused prep: table cvt + Wt pack + bucket counts ----------
struct CvtSeg { const void* src; float* dst; int n; int blk0; };
struct CvtBatch { CvtSeg seg[16]; };

__global__ void __launch_bounds__(256) k_prep(CvtBatch cb, int cvtBlks,
                                              const void* Wg, const void* Wd, const void* Wa,
                                              unsigned short* WtG, unsigned short* WtD, unsigned short* WtA,
                                              const int* __restrict__ grow, int* __restrict__ bucket_tot,
                                              const void* probe) {
    int blk = blockIdx.x, tid = threadIdx.x;
    if (blk < cvtBlks) {                       // --- small-table f32 conversion
        int isf32 = detect_f32(probe);
        int si = 0;
        #pragma unroll
        for (int i = 0; i < 16; ++i) if (blk >= cb.seg[i].blk0) si = i;
        const CvtSeg sg = cb.seg[si];
        int i = (blk - sg.blk0) * 256 + tid;
        if (i >= sg.n) return;
        if (isf32) sg.dst[i] = ((const float*)sg.src)[i];
        else       sg.dst[i] = __bfloat162float(((const __hip_bfloat16*)sg.src)[i]);
        return;
    }
    if (blk < cvtBlks + WT_BLKS) {             // --- Wt B-fragment pack
        int isf32 = detect_f32(probe);
        int t = (blk - cvtBlks) * 256 + tid;
        if (t >= (KP_G + KP_D + KP_A) * 64) return;
        int kp = t >> 6, n = t & 63;
        int k, K; const void* src; unsigned short* dst;
        if (kp < KP_G)              { k = kp;               K = 25;   src = Wg; dst = WtG; }
        else if (kp < KP_G + KP_D)  { k = kp - KP_G;        K = 2186; src = Wd; dst = WtD; }
        else                        { k = kp - KP_G - KP_D; K = 8030; src = Wa; dst = WtA; }
        unsigned short v = 0;
        if (k < K) {
            if (isf32) {
                __hip_bfloat16 h = __float2bfloat16(((const float*)src)[(size_t)k * 64 + n]);
                v = *(unsigned short*)&h;
            } else {
                v = ((const unsigned short*)src)[(size_t)k * 64 + n];
            }
        }
        dst[(((size_t)(k >> 5) * 64 + n) * 4 + ((k >> 3) & 3)) * 8 + (k & 7)] = v;
        return;
    }
    // --- bucket counts (bucket_tot pre-zeroed by memset before this launch)
    __shared__ int h[NBKT];
    for (int i = tid; i < NBKT; i += 256) h[i] = 0;
    __syncthreads();
    int idx0 = (blk - cvtBlks - WT_BLKS) * 4096;
    #pragma unroll
    for (int k = 0; k < 16; ++k) {
        int i = idx0 + k * 256 + tid;
        if (i < E2) atomicAdd(&h[bucket_of(grow[i])], 1);
    }
    __syncthreads();
    for (int i = tid; i < NBKT; i += 256) if (h[i]) atomicAdd(&bucket_tot[i], h[i]);
}

// ---------------- bucket scan ----------------
__global__ void __launch_bounds__(512) k_bscan(const int* __restrict__ bucket_tot,
                                               int* __restrict__ bucket_base,
                                               int* __restrict__ bucketcur) {
    __shared__ int s[512];
    int tid = threadIdx.x;
    s[tid] = (tid < NBKT) ? bucket_tot[tid] : 0;
    __syncthreads();
    for (int off = 1; off < 512; off <<= 1) {
        int v = (tid >= off) ? s[tid - off] : 0;
        __syncthreads();
        s[tid] += v;
        __syncthreads();
    }
    int excl = tid ? s[tid - 1] : 0;
    bucket_base[tid] = excl;                 // bucket_base[NBKT] = E2
    if (tid < NBKT) bucketcur[tid] = excl;
}

// ---------------- P1: bin edges into NBKT row-range buckets ----------------
__global__ void __launch_bounds__(256) k_p1(const int* __restrict__ grow, const int* __restrict__ gcol,
                                            int* __restrict__ bucketcur, int2* __restrict__ binned) {
    __shared__ int h1[NBKT], base1[NBKT];
    int tid = threadIdx.x;
    for (int i = tid; i < NBKT; i += 256) h1[i] = 0;
    __syncthreads();
    int idx0 = blockIdx.x * 4096;
    int r[16], c[16];
    #pragma unroll
    for (int k = 0; k < 16; ++k) {
        int i = idx0 + k * 256 + tid;
        if (i < E2) {
            r[k] = grow[i]; c[k] = gcol[i];
            atomicAdd(&h1[bucket_of(r[k])], 1);
        } else r[k] = -1;
    }
    __syncthreads();
    for (int i = tid; i < NBKT; i += 256) {
        base1[i] = h1[i] ? atomicAdd(&bucketcur[i], h1[i]) : 0;
        h1[i] = 0;
    }
    __syncthreads();
    #pragma unroll
    for (int k = 0; k < 16; ++k) {
        if (r[k] >= 0) {
            int b = bucket_of(r[k]);
            int p = base1[b] + atomicAdd(&h1[b], 1);
            binned[p] = make_int2(r[k], c[k]);
        }
    }
}

// ---------------- P2: per-bucket sort + packed (start,end) + factors -------
__global__ void __launch_bounds__(256) k_p2(const int2* __restrict__ binned, const int* __restrict__ bb,
                                            int* __restrict__ cols, int2* __restrict__ moffs,
                                            float* __restrict__ dinv, float* __restrict__ dsq,
                                            float* __restrict__ gsc) {
    __shared__ int h[1024];
    __shared__ int ws2[256];
    int b = blockIdx.x, tid = threadIdx.x;
    int r0, r1;
    if (b < 147) { r0 = b << 10; r1 = min((b + 1) << 10, N_USER); }
    else         { r0 = N_USER + ((b - 147) << 8); r1 = min(N_USER + ((b - 146) << 8), N_NODES); }
    int s0 = bb[b], e0 = bb[b + 1];
    for (int i = tid; i < 1024; i += 256) h[i] = 0;
    __syncthreads();
    for (int j = s0 + tid; j < e0; j += 256) atomicAdd(&h[binned[j].x - r0], 1);
    __syncthreads();
    int t0 = tid * 4;
    int a0 = h[t0], a1 = h[t0 + 1], a2 = h[t0 + 2], a3 = h[t0 + 3];
    ws2[tid] = a0 + a1 + a2 + a3;
    __syncthreads();
    for (int off = 1; off < 256; off <<= 1) {
        int v = (tid >= off) ? ws2[tid - off] : 0;
        __syncthreads();
        ws2[tid] += v;
        __syncthreads();
    }
    int excl = tid ? ws2[tid - 1] : 0;
    int ex[4] = { excl, excl + a0, excl + a0 + a1, excl + a0 + a1 + a2 };
    int ac[4] = { a0, a1, a2, a3 };
    #pragma unroll
    for (int i = 0; i < 4; ++i) {
        int row = r0 + t0 + i;
        if (row < r1) {
            moffs[row] = make_int2(s0 + ex[i], s0 + ex[i] + ac[i]);
            float deg = (float)ac[i];
            bool nz = deg > 0.f;
            dinv[row] = nz ? rsqrtf(deg) : 0.f;
            dsq[row]  = nz ? 1.f / deg  : 0.f;
            gsc[row]  = nz ? sqrtf(deg) : 0.f;
        }
        h[t0 + i] = ex[i];
    }
    __syncthreads();
    for (int j = s0 + tid; j < e0; j += 256) {
        int2 e = binned[j];
        int p = s0 + atomicAdd(&h[e.x - r0], 1);
        cols[p] = e.y << 7;           // byte offset into a 64-half row
    }
}

// ---------------- mhgemm device body (shared by fused launch) --------------
__device__ void mhgemm_body(int blk, const int* __restrict__ aux,
                            const unsigned short* __restrict__ WtG,
                            const unsigned short* __restrict__ WtD,
                            const unsigned short* __restrict__ WtA,
                            float* __restrict__ Xmh, float* __restrict__ cntf) {
    int seg, rb, k0, klen, Kseg, auxoff;
    const unsigned short* Wt;
    if (blk < 16)      { seg = 0; rb = blk;                      k0 = 0;              klen = 25;                  Kseg = 25;   auxoff = 1;    Wt = WtG; }
    else if (blk < 96) { int t = blk - 16; seg = 1; rb = t & 15; k0 = (t >> 4) * 512; klen = min(512, 2186 - k0); Kseg = 2186; auxoff = 26;   Wt = WtD; }
    else               { int t = blk - 96; seg = 2; rb = t & 15; k0 = (t >> 4) * 512; klen = min(512, 8030 - k0); Kseg = 8030; auxoff = 2212; Wt = WtA; }
    int lane = threadIdx.x & 63, wave = threadIdx.x >> 6;
    int m = lane & 15, quad = lane >> 4;
    int row = rb * 64 + wave * 16 + m;
    const int* arow = aux + (size_t)row * AUX_W + auxoff;

    f32x4 acc0 = {0.f,0.f,0.f,0.f}, acc1 = acc0, acc2 = acc0, acc3 = acc0;
    float asum = 0.f;
    int nchunk = (klen + 31) >> 5;
    for (int kci = 0; kci < nchunk; ++kci) {
        int kb = k0 + kci * 32 + quad * 8;
        short8 af;
        if (kb + 8 <= Kseg) {
            #pragma unroll
            for (int j = 0; j < 8; ++j) {
                int x = arow[kb + j];
                af[j] = x ? (short)0x3F80 : (short)0;
                asum += (float)x;
            }
        } else {
            #pragma unroll
            for (int j = 0; j < 8; ++j) {
                int x = (kb + j < Kseg) ? arow[kb + j] : 0;
                af[j] = x ? (short)0x3F80 : (short)0;
                asum += (float)x;
            }
        }
        size_t kcg = (size_t)(k0 >> 5) + kci;
        const unsigned short* bp = Wt + ((kcg * 64 + m) * 4 + quad) * 8;
        short8 b0 = *(const short8*)(bp);
        short8 b1 = *(const short8*)(bp + 512);
        short8 b2 = *(const short8*)(bp + 1024);
        short8 b3 = *(const short8*)(bp + 1536);
        acc0 = __builtin_amdgcn_mfma_f32_16x16x32_bf16(af, b0, acc0, 0, 0, 0);
        acc1 = __builtin_amdgcn_mfma_f32_16x16x32_bf16(af, b1, acc1, 0, 0, 0);
        acc2 = __builtin_amdgcn_mfma_f32_16x16x32_bf16(af, b2, acc2, 0, 0, 0);
        acc3 = __builtin_amdgcn_mfma_f32_16x16x32_bf16(af, b3, acc3, 0, 0, 0);
    }
    asum += __shfl_xor(asum, 16);
    asum += __shfl_xor(asum, 32);
    if (quad == 0) atomicAdd(&cntf[seg * BATCH + row], asum);
    float* xbase = Xmh + ((size_t)seg * BATCH + rb * 64 + wave * 16 + quad * 4) * 64;
    #pragma unroll
    for (int reg = 0; reg < 4; ++reg) {
        float* xr = xbase + (size_t)reg * 64;
        atomicAdd(&xr[ 0 + m], acc0[reg]);
        atomicAdd(&xr[16 + m], acc1[reg]);
        atomicAdd(&xr[32 + m], acc2[reg]);
        atomicAdd(&xr[48 + m], acc3[reg]);
    }
}

// ---------------- fused: emb cvt + tacc0 + mark(moffs2) + mhgemm -----------
// ranges: [0,cvtN) cvt; [cvtN,+512) tacc0; [+512,+1024) mark; [+1024,+1376) mhgemm
__global__ void __launch_bounds__(256) k_cvt_fused(const void* rawU, const void* rawI,
                                                   const float* __restrict__ dinv,
                                                   __half* __restrict__ emb,
                                                   float* __restrict__ tacc,
                                                   const int* __restrict__ uids,
                                                   const int* __restrict__ iids, int cvtN,
                                                   const int2* __restrict__ moffs,
                                                   const int* __restrict__ cols,
                                                   int2* __restrict__ moffs2,
                                                   const int* __restrict__ aux,
                                                   const unsigned short* __restrict__ WtG,
                                                   const unsigned short* __restrict__ WtD,
                                                   const unsigned short* __restrict__ WtA,
                                                   float* __restrict__ Xmh, float* __restrict__ cntf) {
    int blk = blockIdx.x;
    if (blk >= cvtN + 1024) {                 // mhgemm
        mhgemm_body(blk - cvtN - 1024, aux, WtG, WtD, WtA, Xmh, cntf);
        return;
    }
    if (blk >= cvtN + 512) {                  // mark: moffs2[r] for T u N(T)
        int lane = threadIdx.x & 63;
        int t = (blk - cvtN - 512) * 4 + (threadIdx.x >> 6);
        int r = (t < BATCH) ? uids[t] : (N_USER + iids[t - BATCH]);
        int2 se = moffs[r];
        if (lane == 0) moffs2[r] = se;
        for (int j = se.x + lane; j < se.y; j += 64) {
            int c = (unsigned)cols[j] >> 7;
            moffs2[c] = moffs[c];             // benign dup races: same value
        }
        return;
    }
    int isf32 = detect_f32(rawU);
    if (blk >= cvtN) {                        // tacc0: init from RAW rows
        int lane = threadIdx.x & 63;
        int t = (blk - cvtN) * 4 + (threadIdx.x >> 6);
        const void* src; size_t ri;
        if (t < BATCH) { src = rawU; ri = (size_t)uids[t]; }
        else           { src = rawI; ri = (size_t)iids[t - BATCH]; }
        float v;
        if (isf32) v = ((const float*)src)[ri * 64 + lane];
        else       v = __bfloat162float(((const __hip_bfloat16*)src)[ri * 64 + lane]);
        tacc[(size_t)t * 64 + lane] = v;
        return;
    }
    int q = blk * 256 + threadIdx.x;          // quad index (4 elems)
    if (q >= N_NODES * 16) return;
    int r = q >> 4;
    const void* src; size_t qq;
    if (r < N_USER) { src = rawU; qq = (size_t)q; }
    else            { src = rawI; qq = (size_t)q - (size_t)N_USER * 16; }
    float d = dinv[r];
    float4 v;
    if (isf32) {
        v = ((const float4*)src)[qq];
    } else {
        ushort4 u = ((const ushort4*)src)[qq];
        v.x = __bfloat162float(*(__hip_bfloat16*)&u.x);
        v.y = __bfloat162float(*(__hip_bfloat16*)&u.y);
        v.z = __bfloat162float(*(__hip_bfloat16*)&u.z);
        v.w = __bfloat162float(*(__hip_bfloat16*)&u.w);
    }
    __half h0 = __float2half(v.x * d), h1 = __float2half(v.y * d);
    __half h2 = __float2half(v.z * d), h3 = __float2half(v.w * d);
    ushort4 o = { *(unsigned short*)&h0, *(unsigned short*)&h1,
                  *(unsigned short*)&h2, *(unsigned short*)&h3 };
    ((ushort4*)emb)[(size_t)q] = o;
}

// ---------------- f-domain SpMV, half2 layout, packed moffs ----------------
// chain: moffs(8B) -> cols -> gather. Rows with e<=s exit (deg-0 or unmarked).
// Appended blocks [spmvN, spmvN+512): tacc += g[r]*src[r] (reads INPUT buf).
__global__ void __launch_bounds__(256, 8) k_spmv(const __half* __restrict__ src, __half* __restrict__ dst,
                                                 const int2* __restrict__ moffs_in, const int* __restrict__ cols,
                                                 const float* __restrict__ dsq,
                                                 int spmvN, float* __restrict__ tacc,
                                                 const int* __restrict__ uids, const int* __restrict__ iids,
                                                 const float* __restrict__ gsc) {
    int tid = threadIdx.x, lane = tid & 63;
    int blk = blockIdx.x;
    if (blk >= spmvN) {                       // fused tacc layer update
        int t = (blk - spmvN) * 4 + (tid >> 6);
        int r = (t < BATCH) ? uids[t] : (N_USER + iids[t - BATCH]);
        tacc[(size_t)t * 64 + lane] += __half2float(src[(size_t)r * 64 + lane]) * gsc[r];
        return;
    }
    int wid = blk * 4 + (tid >> 6);
    if (wid >= N_NODES) return;
    int2 se = moffs_in[wid];
    int s = se.x, e = se.y;
    if (e <= s) return;
    int p = lane & 31, ep = lane >> 5;
    const char* sb = (const char*)src + (p << 2);
    float ax = 0.f, ay = 0.f;
    int j0 = s;
    for (; j0 + 16 <= e; j0 += 16) {          // 16 edges per iter, no clamp
        int c[8];
        #pragma unroll
        for (int u = 0; u < 8; ++u) c[u] = cols[j0 + 2 * u + ep];
        float2 v[8];
        #pragma unroll
        for (int u = 0; u < 8; ++u) v[u] = __half22float2(*(const __half2*)(sb + (size_t)(unsigned)c[u]));
        #pragma unroll
        for (int u = 0; u < 8; ++u) { ax += v[u].x; ay += v[u].y; }
    }
    if (j0 < e) {                             // tail <16 edges, clamped
        int c[8]; float w[8];
        #pragma unroll
        for (int u = 0; u < 8; ++u) {
            int j = j0 + 2 * u + ep;
            c[u] = cols[min(j, e - 1)];
            w[u] = (j < e) ? 1.f : 0.f;
        }
        float2 v[8];
        #pragma unroll
        for (int u = 0; u < 8; ++u) v[u] = __half22float2(*(const __half2*)(sb + (size_t)(unsigned)c[u]));
        #pragma unroll
        for (int u = 0; u < 8; ++u) { ax = fmaf(w[u], v[u].x, ax); ay = fmaf(w[u], v[u].y, ay); }
    }
    ax += __shfl_xor(ax, 32);
    ay += __shfl_xor(ay, 32);
    if (ep == 0) {
        float d = dsq[wid];
        *(__half2*)((char*)dst + ((size_t)wid << 7) + (p << 2)) = __floats2half2_rn(ax * d, ay * d);
    }
}

// ---------------- layer-3 SpMV fused into tacc + self term -----------------
__global__ void __launch_bounds__(256) k_spmv3(const __half* __restrict__ src, float* __restrict__ tacc,
                                               const int2* __restrict__ moffs, const int* __restrict__ cols,
                                               const float* __restrict__ dinv, const float* __restrict__ gsc,
                                               const int* __restrict__ uids, const int* __restrict__ iids) {
    int tid = threadIdx.x, lane = tid & 63;
    int t = blockIdx.x * 4 + (tid >> 6);
    if (t >= 2048) return;
    int r = (t < BATCH) ? uids[t] : (N_USER + iids[t - BATCH]);
    int2 se = moffs[r];
    int s = se.x, e = se.y;
    int p = lane & 31, ep = lane >> 5;
    const char* sb = (const char*)src + (p << 2);
    float ax = 0.f, ay = 0.f;
    int j0 = s;
    for (; j0 + 16 <= e; j0 += 16) {
        int c[8];
        #pragma unroll
        for (int u = 0; u < 8; ++u) c[u] = cols[j0 + 2 * u + ep];
        float2 v[8];
        #pragma unroll
        for (int u = 0; u < 8; ++u) v[u] = __half22float2(*(const __half2*)(sb + (size_t)(unsigned)c[u]));
        #pragma unroll
        for (int u = 0; u < 8; ++u) { ax += v[u].x; ay += v[u].y; }
    }
    if (j0 < e) {
        int c[8]; float w[8];
        #pragma unroll
        for (int u = 0; u < 8; ++u) {
            int j = j0 + 2 * u + ep;
            c[u] = cols[min(j, e - 1)];
            w[u] = (j < e) ? 1.f : 0.f;
        }
        float2 v[8];
        #pragma unroll
        for (int u = 0; u < 8; ++u) v[u] = __half22float2(*(const __half2*)(sb + (size_t)(unsigned)c[u]));
        #pragma unroll
        for (int u = 0; u < 8; ++u) { ax = fmaf(w[u], v[u].x, ax); ay = fmaf(w[u], v[u].y, ay); }
    }
    ax += __shfl_xor(ax, 32);
    ay += __shfl_xor(ay, 32);
    if (ep == 0) {
        float2 self = __half22float2(*(const __half2*)((const char*)src + ((size_t)r << 7) + (p << 2)));
        float di = dinv[r], g = gsc[r];
        float* tp = tacc + (size_t)t * 64 + (p << 1);
        tp[0] += di * ax + g * self.x;
        tp[1] += di * ay + g * self.y;
    }
}

// ---------------- fused X-assembly + MLP -----------------------------------
__global__ void __launch_bounds__(256) k_mlp(const int* __restrict__ aux,
                                             const float* __restrict__ ratef, const float* __restrict__ genderf,
                                             const float* __restrict__ agef, const float* __restrict__ occf,
                                             const float* __restrict__ areaf, const float* __restrict__ tacc,
                                             const float* __restrict__ Xmh, const float* __restrict__ cntf,
                                             const float* __restrict__ W1, const float* __restrict__ b1,
                                             const float* __restrict__ W2, const float* __restrict__ b2,
                                             const float* __restrict__ Wo, const float* __restrict__ bo,
                                             void* __restrict__ out, const void* probe) {
    __shared__ float sx[4][640];
    __shared__ float sh[4][64];
    int isf32 = detect_f32(probe);
    int lane = threadIdx.x & 63, w = threadIdx.x >> 6;
    int b = blockIdx.x * 4 + w;
    const int* arow = aux + (size_t)b * AUX_W;
    float* xr = sx[w];
    xr[0   + lane] = ratef[arow[0] * 64 + lane];
    xr[64  + lane] = Xmh[((size_t)0 * BATCH + b) * 64 + lane] / cntf[0 * BATCH + b];
    xr[128 + lane] = Xmh[((size_t)1 * BATCH + b) * 64 + lane] / cntf[1 * BATCH + b];
    xr[192 + lane] = Xmh[((size_t)2 * BATCH + b) * 64 + lane] / cntf[2 * BATCH + b];
    xr[256 + lane] = genderf[arow[10242] * 64 + lane];
    xr[320 + lane] = agef[arow[10243] * 64 + lane];
    xr[384 + lane] = occf[arow[10244] * 64 + lane];
    xr[448 + lane] = areaf[arow[10245] * 64 + lane];
    xr[512 + lane] = tacc[(size_t)b * 64 + lane] * 0.25f;
    xr[576 + lane] = tacc[(size_t)(BATCH + b) * 64 + lane] * 0.25f;
    float acc = b1[lane];
    #pragma unroll 8
    for (int k = 0; k < 640; ++k) acc += xr[k] * W1[(size_t)k * 64 + lane];
    float h1 = fmaxf(acc, 0.f);
    sh[w][lane] = h1;
    float acc2 = b2[lane];
    #pragma unroll 8
    for (int j = 0; j < 64; ++j) acc2 += sh[w][j] * W2[(size_t)j * 64 + lane];
    float h2 = fmaxf(acc2, 0.f);
    float p = h2 * Wo[lane];
    #pragma unroll
    for (int off = 32; off; off >>= 1) p += __shfl_down(p, off);
    if (lane == 0) {
        float r = p + bo[0];
        if (isf32) ((float*)out)[b] = r;
        else       ((__hip_bfloat16*)out)[b] = __float2bfloat16(r);
    }
}

extern "C" void kernel_launch(void* const* d_in, const int* in_sizes, int n_in,
                              void* d_out, int out_size, void* d_ws, size_t ws_size,
                              hipStream_t stream) {
    const int* aux  = (const int*)d_in[0];
    const int* uids = (const int*)d_in[1];
    const int* iids = (const int*)d_in[2];
    const int* grow = (const int*)d_in[3];
    const int* gcol = (const int*)d_in[4];

    char* p = (char*)d_ws;
    auto alloc = [&](size_t bytes) -> char* {
        char* r = p;
        p += (bytes + 255) / 256 * 256;
        return r;
    };
    // zero-region (one hipMemsetAsync): bucket_tot, Xmh, cntf, moffs2
    int*   bucket_tot  = (int*)alloc(512 * 4);
    float* Xmh         = (float*)alloc((size_t)3 * BATCH * 64 * 4);
    float* cntf        = (float*)alloc((size_t)3 * BATCH * 4);
    int2*  moffs2      = (int2*)alloc((size_t)180224 * 8);
    char*  zero_end    = p;
    int*   bucket_base = (int*)alloc(512 * 4);
    int*   bucketcur   = (int*)alloc(512 * 4);
    int2*  moffs       = (int2*)alloc((size_t)180224 * 8);
    float* dinv        = (float*)alloc((size_t)180224 * 4);
    float* dsq         = (float*)alloc((size_t)180224 * 4);
    float* gsc         = (float*)alloc((size_t)180224 * 4);
    int2*  binned      = (int2*)alloc((size_t)E2 * 8);
    int*   cols        = (int*)alloc((size_t)E2 * 4);
    __half* embA       = (__half*)alloc((size_t)N_NODES * 64 * 2);
    __half* embB       = (__half*)alloc((size_t)N_NODES * 64 * 2);
    float* tacc        = (float*)alloc((size_t)2048 * 64 * 4);
    unsigned short* WtG = (unsigned short*)alloc((size_t)KP_G * 64 * 2);
    unsigned short* WtD = (unsigned short*)alloc((size_t)KP_D * 64 * 2);
    unsigned short* WtA = (unsigned short*)alloc((size_t)KP_A * 64 * 2);
    float* ratef   = (float*)alloc(384 * 4);
    float* genderf = (float*)alloc(128 * 4);
    float* agef    = (float*)alloc(448 * 4);
    float* occf    = (float*)alloc(1344 * 4);
    float* areaf   = (float*)alloc((size_t)217728 * 4);
    float* fc1W    = (float*)alloc((size_t)40960 * 4);
    float* fc1b    = (float*)alloc(64 * 4);
    float* fc2W    = (float*)alloc(4096 * 4);
    float* fc2b    = (float*)alloc(64 * 4);
    float* outW    = (float*)alloc(64 * 4);
    float* outb    = (float*)alloc(4);

    const void* probe = d_in[14];   // user_rel, for inline dtype detect

    // 0. zero accumulators (single contiguous region, DMA)
    hipMemsetAsync(bucket_tot, 0, (size_t)(zero_end - (char*)bucket_tot), stream);

    // 1. fused prep: table cvt + Wt pack + bucket counts
    CvtBatch cb;
    int blk = 0, si = 0;
    auto addseg = [&](const void* s, float* d, int n) {
        cb.seg[si].src = s; cb.seg[si].dst = d; cb.seg[si].n = n; cb.seg[si].blk0 = blk;
        blk += (n + 255) / 256; ++si;
    };
    addseg(d_in[6],  ratef,   384);
    addseg(d_in[10], genderf, 128);
    addseg(d_in[11], agef,    448);
    addseg(d_in[12], occf,    1344);
    addseg(d_in[13], areaf,   217728);
    addseg(d_in[16], fc1W,   40960);
    addseg(d_in[17], fc1b,   64);
    addseg(d_in[18], fc2W,   4096);
    addseg(d_in[19], fc2b,   64);
    addseg(d_in[20], outW,   64);
    addseg(d_in[21], outb,   1);
    for (int i = si; i < 16; ++i) { cb.seg[i].src = nullptr; cb.seg[i].dst = nullptr; cb.seg[i].n = 0; cb.seg[i].blk0 = 0x7fffffff; }
    const int cvtBlks = blk;
    hipLaunchKernelGGL(k_prep, dim3(cvtBlks + WT_BLKS + BCNT_BLKS), dim3(256), 0, stream,
                       cb, cvtBlks, d_in[7], d_in[8], d_in[9], WtG, WtD, WtA, grow, bucket_tot, probe);

    // 2. CSR build
    hipLaunchKernelGGL(k_bscan, dim3(1), dim3(512), 0, stream, bucket_tot, bucket_base, bucketcur);
    hipLaunchKernelGGL(k_p1, dim3((E2 + 4095) / 4096), dim3(256), 0, stream, grow, gcol, bucketcur, binned);
    hipLaunchKernelGGL(k_p2, dim3(NBKT), dim3(256), 0, stream, binned, bucket_base, cols, moffs, dinv, dsq, gsc);

    // 3. fused: emb cvt + tacc0 + mark(moffs2) + mhgemm
    const int cvtN = (N_NODES * 16 + 255) / 256;
    hipLaunchKernelGGL(k_cvt_fused, dim3(cvtN + 1024 + 352), dim3(256), 0, stream,
                       d_in[14], d_in[15], dinv, embA, tacc, uids, iids, cvtN,
                       moffs, cols, moffs2, aux, WtG, WtD, WtA, Xmh, cntf);

    // 4. LightGCN: L1 unmasked; L2 via moffs2 (+fused tacc f1); L3 at T (+self)
    const int spmvN = (N_NODES + 3) / 4;
    hipLaunchKernelGGL(k_spmv, dim3(spmvN), dim3(256), 0, stream,
                       embA, embB, moffs, cols, dsq, spmvN, (float*)nullptr, uids, iids, gsc);
    hipLaunchKernelGGL(k_spmv, dim3(spmvN + 512), dim3(256), 0, stream,
                       embB, embA, moffs2, cols, dsq, spmvN, tacc, uids, iids, gsc);
    hipLaunchKernelGGL(k_spmv3, dim3(2048 / 4), dim3(256), 0, stream,
                       embA, tacc, moffs, cols, dinv, gsc, uids, iids);

    // 5. fused X+MLP -> out
    hipLaunchKernelGGL(k_mlp, dim3(BATCH / 4), dim3(256), 0, stream,
                       aux, ratef, genderf, agef, occf, areaf, tacc, Xmh, cntf,
                       fc1W, fc1b, fc2W, fc2b, outW, outb, d_out, probe);
}

// Round 11
// 333.660 us; speedup vs baseline: 3.6739x; 1.0593x over previous
//
#include <hip/hip_runtime.h>
#include <hip/hip_bf16.h>
#include <hip/hip_fp16.h>

#define N_USER 150000
#define M_ITEM 30000
#define N_NODES 180000
#define E2 1200000
#define BATCH 1024
#define AUX_W 10246
#define KP_G 32
#define KP_D 2208
#define KP_A 8064
#define NBKT 265       // 147 user buckets (1024 rows) + 118 item buckets (256 rows)
#define WT_BLKS 2576   // ((KP_G+KP_D+KP_A)*64 + 255)/256
#define BCNT_BLKS 293  // (E2 + 4095)/4096

typedef __attribute__((ext_vector_type(8))) short short8;
typedef __attribute__((ext_vector_type(4))) float f32x4;

__device__ __forceinline__ int bucket_of(int r) {
    return r < N_USER ? (r >> 10) : 147 + ((r - N_USER) >> 8);
}

// inline dtype detect (wave-uniform): bf16 data reads small; f32-as-bf16 huge.
__device__ __forceinline__ int detect_f32(const void* probe) {
    float v = __bfloat162float(((const __hip_bfloat16*)probe)[threadIdx.x & 63]);
    unsigned long long m = __ballot(!(fabsf(v) < 1000.0f));
    return __popcll(m) > 8;
}

// ---------------- fused prep: table cvt + Wt pack + bucket counts ----------
struct CvtSeg { const void* src; float* dst; int n; int blk0; };
struct CvtBatch { CvtSeg seg[16]; };

__global__ void __launch_bounds__(256) k_prep(CvtBatch cb, int cvtBlks,
                                              const void* Wg, const void* Wd, const void* Wa,
                                              unsigned short* WtG, unsigned short* WtD, unsigned short* WtA,
                                              const int* __restrict__ grow, int* __restrict__ bucket_tot,
                                              const void* probe) {
    int blk = blockIdx.x, tid = threadIdx.x;
    if (blk < cvtBlks) {                       // --- small-table f32 conversion
        int isf32 = detect_f32(probe);
        int si = 0;
        #pragma unroll
        for (int i = 0; i < 16; ++i) if (blk >= cb.seg[i].blk0) si = i;
        const CvtSeg sg = cb.seg[si];
        int i = (blk - sg.blk0) * 256 + tid;
        if (i >= sg.n) return;
        if (isf32) sg.dst[i] = ((const float*)sg.src)[i];
        else       sg.dst[i] = __bfloat162float(((const __hip_bfloat16*)sg.src)[i]);
        return;
    }
    if (blk < cvtBlks + WT_BLKS) {             // --- Wt B-fragment pack
        int isf32 = detect_f32(probe);
        int t = (blk - cvtBlks) * 256 + tid;
        if (t >= (KP_G + KP_D + KP_A) * 64) return;
        int kp = t >> 6, n = t & 63;
        int k, K; const void* src; unsigned short* dst;
        if (kp < KP_G)              { k = kp;               K = 25;   src = Wg; dst = WtG; }
        else if (kp < KP_G + KP_D)  { k = kp - KP_G;        K = 2186; src = Wd; dst = WtD; }
        else                        { k = kp - KP_G - KP_D; K = 8030; src = Wa; dst = WtA; }
        unsigned short v = 0;
        if (k < K) {
            if (isf32) {
                __hip_bfloat16 h = __float2bfloat16(((const float*)src)[(size_t)k * 64 + n]);
                v = *(unsigned short*)&h;
            } else {
                v = ((const unsigned short*)src)[(size_t)k * 64 + n];
            }
        }
        dst[(((size_t)(k >> 5) * 64 + n) * 4 + ((k >> 3) & 3)) * 8 + (k & 7)] = v;
        return;
    }
    // --- bucket counts (bucket_tot pre-zeroed by memset before this launch)
    __shared__ int h[NBKT];
    for (int i = tid; i < NBKT; i += 256) h[i] = 0;
    __syncthreads();
    int idx0 = (blk - cvtBlks - WT_BLKS) * 4096;
    #pragma unroll
    for (int k = 0; k < 16; ++k) {
        int i = idx0 + k * 256 + tid;
        if (i < E2) atomicAdd(&h[bucket_of(grow[i])], 1);
    }
    __syncthreads();
    for (int i = tid; i < NBKT; i += 256) if (h[i]) atomicAdd(&bucket_tot[i], h[i]);
}

// ---------------- bucket scan ----------------
__global__ void __launch_bounds__(512) k_bscan(const int* __restrict__ bucket_tot,
                                               int* __restrict__ bucket_base,
                                               int* __restrict__ bucketcur) {
    __shared__ int s[512];
    int tid = threadIdx.x;
    s[tid] = (tid < NBKT) ? bucket_tot[tid] : 0;
    __syncthreads();
    for (int off = 1; off < 512; off <<= 1) {
        int v = (tid >= off) ? s[tid - off] : 0;
        __syncthreads();
        s[tid] += v;
        __syncthreads();
    }
    int excl = tid ? s[tid - 1] : 0;
    bucket_base[tid] = excl;                 // bucket_base[NBKT] = E2
    if (tid < NBKT) bucketcur[tid] = excl;
}

// ---------------- P1: bin edges into NBKT row-range buckets ----------------
__global__ void __launch_bounds__(256) k_p1(const int* __restrict__ grow, const int* __restrict__ gcol,
                                            int* __restrict__ bucketcur, int2* __restrict__ binned) {
    __shared__ int h1[NBKT], base1[NBKT];
    int tid = threadIdx.x;
    for (int i = tid; i < NBKT; i += 256) h1[i] = 0;
    __syncthreads();
    int idx0 = blockIdx.x * 4096;
    int r[16], c[16];
    #pragma unroll
    for (int k = 0; k < 16; ++k) {
        int i = idx0 + k * 256 + tid;
        if (i < E2) {
            r[k] = grow[i]; c[k] = gcol[i];
            atomicAdd(&h1[bucket_of(r[k])], 1);
        } else r[k] = -1;
    }
    __syncthreads();
    for (int i = tid; i < NBKT; i += 256) {
        base1[i] = h1[i] ? atomicAdd(&bucketcur[i], h1[i]) : 0;
        h1[i] = 0;
    }
    __syncthreads();
    #pragma unroll
    for (int k = 0; k < 16; ++k) {
        if (r[k] >= 0) {
            int b = bucket_of(r[k]);
            int p = base1[b] + atomicAdd(&h1[b], 1);
            binned[p] = make_int2(r[k], c[k]);
        }
    }
}

// ---------------- P2: per-bucket sort + packed (start,end) + factors -------
__global__ void __launch_bounds__(256) k_p2(const int2* __restrict__ binned, const int* __restrict__ bb,
                                            int* __restrict__ cols, int2* __restrict__ moffs,
                                            float* __restrict__ dinv, float* __restrict__ dsq,
                                            float* __restrict__ gsc) {
    __shared__ int h[1024];
    __shared__ int ws2[256];
    int b = blockIdx.x, tid = threadIdx.x;
    int r0, r1;
    if (b < 147) { r0 = b << 10; r1 = min((b + 1) << 10, N_USER); }
    else         { r0 = N_USER + ((b - 147) << 8); r1 = min(N_USER + ((b - 146) << 8), N_NODES); }
    int s0 = bb[b], e0 = bb[b + 1];
    for (int i = tid; i < 1024; i += 256) h[i] = 0;
    __syncthreads();
    for (int j = s0 + tid; j < e0; j += 256) atomicAdd(&h[binned[j].x - r0], 1);
    __syncthreads();
    int t0 = tid * 4;
    int a0 = h[t0], a1 = h[t0 + 1], a2 = h[t0 + 2], a3 = h[t0 + 3];
    ws2[tid] = a0 + a1 + a2 + a3;
    __syncthreads();
    for (int off = 1; off < 256; off <<= 1) {
        int v = (tid >= off) ? ws2[tid - off] : 0;
        __syncthreads();
        ws2[tid] += v;
        __syncthreads();
    }
    int excl = tid ? ws2[tid - 1] : 0;
    int ex[4] = { excl, excl + a0, excl + a0 + a1, excl + a0 + a1 + a2 };
    int ac[4] = { a0, a1, a2, a3 };
    #pragma unroll
    for (int i = 0; i < 4; ++i) {
        int row = r0 + t0 + i;
        if (row < r1) {
            moffs[row] = make_int2(s0 + ex[i], s0 + ex[i] + ac[i]);
            float deg = (float)ac[i];
            bool nz = deg > 0.f;
            dinv[row] = nz ? rsqrtf(deg) : 0.f;
            dsq[row]  = nz ? 1.f / deg  : 0.f;
            gsc[row]  = nz ? sqrtf(deg) : 0.f;
        }
        h[t0 + i] = ex[i];
    }
    __syncthreads();
    for (int j = s0 + tid; j < e0; j += 256) {
        int2 e = binned[j];
        int p = s0 + atomicAdd(&h[e.x - r0], 1);
        cols[p] = e.y << 7;           // byte offset into a 64-half row
    }
}

// ---------------- mhgemm device body (shared by fused launch) --------------
__device__ void mhgemm_body(int blk, const int* __restrict__ aux,
                            const unsigned short* __restrict__ WtG,
                            const unsigned short* __restrict__ WtD,
                            const unsigned short* __restrict__ WtA,
                            float* __restrict__ Xmh, float* __restrict__ cntf) {
    int seg, rb, k0, klen, Kseg, auxoff;
    const unsigned short* Wt;
    if (blk < 16)      { seg = 0; rb = blk;                      k0 = 0;              klen = 25;                  Kseg = 25;   auxoff = 1;    Wt = WtG; }
    else if (blk < 96) { int t = blk - 16; seg = 1; rb = t & 15; k0 = (t >> 4) * 512; klen = min(512, 2186 - k0); Kseg = 2186; auxoff = 26;   Wt = WtD; }
    else               { int t = blk - 96; seg = 2; rb = t & 15; k0 = (t >> 4) * 512; klen = min(512, 8030 - k0); Kseg = 8030; auxoff = 2212; Wt = WtA; }
    int lane = threadIdx.x & 63, wave = threadIdx.x >> 6;
    int m = lane & 15, quad = lane >> 4;
    int row = rb * 64 + wave * 16 + m;
    const int* arow = aux + (size_t)row * AUX_W + auxoff;

    f32x4 acc0 = {0.f,0.f,0.f,0.f}, acc1 = acc0, acc2 = acc0, acc3 = acc0;
    float asum = 0.f;
    int nchunk = (klen + 31) >> 5;
    for (int kci = 0; kci < nchunk; ++kci) {
        int kb = k0 + kci * 32 + quad * 8;
        short8 af;
        if (kb + 8 <= Kseg) {
            #pragma unroll
            for (int j = 0; j < 8; ++j) {
                int x = arow[kb + j];
                af[j] = x ? (short)0x3F80 : (short)0;
                asum += (float)x;
            }
        } else {
            #pragma unroll
            for (int j = 0; j < 8; ++j) {
                int x = (kb + j < Kseg) ? arow[kb + j] : 0;
                af[j] = x ? (short)0x3F80 : (short)0;
                asum += (float)x;
            }
        }
        size_t kcg = (size_t)(k0 >> 5) + kci;
        const unsigned short* bp = Wt + ((kcg * 64 + m) * 4 + quad) * 8;
        short8 b0 = *(const short8*)(bp);
        short8 b1 = *(const short8*)(bp + 512);
        short8 b2 = *(const short8*)(bp + 1024);
        short8 b3 = *(const short8*)(bp + 1536);
        acc0 = __builtin_amdgcn_mfma_f32_16x16x32_bf16(af, b0, acc0, 0, 0, 0);
        acc1 = __builtin_amdgcn_mfma_f32_16x16x32_bf16(af, b1, acc1, 0, 0, 0);
        acc2 = __builtin_amdgcn_mfma_f32_16x16x32_bf16(af, b2, acc2, 0, 0, 0);
        acc3 = __builtin_amdgcn_mfma_f32_16x16x32_bf16(af, b3, acc3, 0, 0, 0);
    }
    asum += __shfl_xor(asum, 16);
    asum += __shfl_xor(asum, 32);
    if (quad == 0) atomicAdd(&cntf[seg * BATCH + row], asum);
    float* xbase = Xmh + ((size_t)seg * BATCH + rb * 64 + wave * 16 + quad * 4) * 64;
    #pragma unroll
    for (int reg = 0; reg < 4; ++reg) {
        float* xr = xbase + (size_t)reg * 64;
        atomicAdd(&xr[ 0 + m], acc0[reg]);
        atomicAdd(&xr[16 + m], acc1[reg]);
        atomicAdd(&xr[32 + m], acc2[reg]);
        atomicAdd(&xr[48 + m], acc3[reg]);
    }
}

// ---------------- fused: mhgemm + mark + tacc0 + emb cvt -------------------
// LONG-POLE FIRST block order (R10 lesson: blocks dispatch in order, so the
// slow 352-block mhgemm must start at blk 0 to overlap with the cvt stream):
// [0,352) mhgemm; [352,864) mark; [864,1376) tacc0; [1376,1376+cvtN) cvt.
__global__ void __launch_bounds__(256) k_cvt_fused(const void* rawU, const void* rawI,
                                                   const float* __restrict__ dinv,
                                                   __half* __restrict__ emb,
                                                   float* __restrict__ tacc,
                                                   const int* __restrict__ uids,
                                                   const int* __restrict__ iids, int cvtN,
                                                   const int2* __restrict__ moffs,
                                                   const int* __restrict__ cols,
                                                   int2* __restrict__ moffs2,
                                                   const int* __restrict__ aux,
                                                   const unsigned short* __restrict__ WtG,
                                                   const unsigned short* __restrict__ WtD,
                                                   const unsigned short* __restrict__ WtA,
                                                   float* __restrict__ Xmh, float* __restrict__ cntf) {
    int blk = blockIdx.x;
    if (blk < 352) {                          // mhgemm (long pole, starts first)
        mhgemm_body(blk, aux, WtG, WtD, WtA, Xmh, cntf);
        return;
    }
    if (blk < 864) {                          // mark: moffs2[r] for T u N(T)
        int lane = threadIdx.x & 63;
        int t = (blk - 352) * 4 + (threadIdx.x >> 6);
        int r = (t < BATCH) ? uids[t] : (N_USER + iids[t - BATCH]);
        int2 se = moffs[r];
        if (lane == 0) moffs2[r] = se;
        for (int j = se.x + lane; j < se.y; j += 64) {
            int c = (unsigned)cols[j] >> 7;
            moffs2[c] = moffs[c];             // benign dup races: same value
        }
        return;
    }
    int isf32 = detect_f32(rawU);
    if (blk < 1376) {                         // tacc0: init from RAW rows
        int lane = threadIdx.x & 63;
        int t = (blk - 864) * 4 + (threadIdx.x >> 6);
        const void* src; size_t ri;
        if (t < BATCH) { src = rawU; ri = (size_t)uids[t]; }
        else           { src = rawI; ri = (size_t)iids[t - BATCH]; }
        float v;
        if (isf32) v = ((const float*)src)[ri * 64 + lane];
        else       v = __bfloat162float(((const __hip_bfloat16*)src)[ri * 64 + lane]);
        tacc[(size_t)t * 64 + lane] = v;
        return;
    }
    int q = (blk - 1376) * 256 + threadIdx.x; // quad index (4 elems)
    if (q >= N_NODES * 16) return;
    int r = q >> 4;
    const void* src; size_t qq;
    if (r < N_USER) { src = rawU; qq = (size_t)q; }
    else            { src = rawI; qq = (size_t)q - (size_t)N_USER * 16; }
    float d = dinv[r];
    float4 v;
    if (isf32) {
        v = ((const float4*)src)[qq];
    } else {
        ushort4 u = ((const ushort4*)src)[qq];
        v.x = __bfloat162float(*(__hip_bfloat16*)&u.x);
        v.y = __bfloat162float(*(__hip_bfloat16*)&u.y);
        v.z = __bfloat162float(*(__hip_bfloat16*)&u.z);
        v.w = __bfloat162float(*(__hip_bfloat16*)&u.w);
    }
    __half h0 = __float2half(v.x * d), h1 = __float2half(v.y * d);
    __half h2 = __float2half(v.z * d), h3 = __float2half(v.w * d);
    ushort4 o = { *(unsigned short*)&h0, *(unsigned short*)&h1,
                  *(unsigned short*)&h2, *(unsigned short*)&h3 };
    ((ushort4*)emb)[(size_t)q] = o;
}

// ---------------- f-domain SpMV, half2 layout, packed moffs ----------------
// chain: moffs(8B) -> cols -> gather. Rows with e<=s exit (deg-0 or unmarked).
// Appended blocks [spmvN, spmvN+512): tacc += g[r]*src[r] (reads INPUT buf).
__global__ void __launch_bounds__(256, 8) k_spmv(const __half* __restrict__ src, __half* __restrict__ dst,
                                                 const int2* __restrict__ moffs_in, const int* __restrict__ cols,
                                                 const float* __restrict__ dsq,
                                                 int spmvN, float* __restrict__ tacc,
                                                 const int* __restrict__ uids, const int* __restrict__ iids,
                                                 const float* __restrict__ gsc) {
    int tid = threadIdx.x, lane = tid & 63;
    int blk = blockIdx.x;
    if (blk >= spmvN) {                       // fused tacc layer update
        int t = (blk - spmvN) * 4 + (tid >> 6);
        int r = (t < BATCH) ? uids[t] : (N_USER + iids[t - BATCH]);
        tacc[(size_t)t * 64 + lane] += __half2float(src[(size_t)r * 64 + lane]) * gsc[r];
        return;
    }
    int wid = blk * 4 + (tid >> 6);
    if (wid >= N_NODES) return;
    int2 se = moffs_in[wid];
    int s = se.x, e = se.y;
    if (e <= s) return;
    int p = lane & 31, ep = lane >> 5;
    const char* sb = (const char*)src + (p << 2);
    float ax = 0.f, ay = 0.f;
    int j0 = s;
    for (; j0 + 16 <= e; j0 += 16) {          // 16 edges per iter, no clamp
        int c[8];
        #pragma unroll
        for (int u = 0; u < 8; ++u) c[u] = cols[j0 + 2 * u + ep];
        float2 v[8];
        #pragma unroll
        for (int u = 0; u < 8; ++u) v[u] = __half22float2(*(const __half2*)(sb + (size_t)(unsigned)c[u]));
        #pragma unroll
        for (int u = 0; u < 8; ++u) { ax += v[u].x; ay += v[u].y; }
    }
    if (j0 < e) {                             // tail <16 edges, clamped
        int c[8]; float w[8];
        #pragma unroll
        for (int u = 0; u < 8; ++u) {
            int j = j0 + 2 * u + ep;
            c[u] = cols[min(j, e - 1)];
            w[u] = (j < e) ? 1.f : 0.f;
        }
        float2 v[8];
        #pragma unroll
        for (int u = 0; u < 8; ++u) v[u] = __half22float2(*(const __half2*)(sb + (size_t)(unsigned)c[u]));
        #pragma unroll
        for (int u = 0; u < 8; ++u) { ax = fmaf(w[u], v[u].x, ax); ay = fmaf(w[u], v[u].y, ay); }
    }
    ax += __shfl_xor(ax, 32);
    ay += __shfl_xor(ay, 32);
    if (ep == 0) {
        float d = dsq[wid];
        *(__half2*)((char*)dst + ((size_t)wid << 7) + (p << 2)) = __floats2half2_rn(ax * d, ay * d);
    }
}

// ---------------- layer-3 SpMV fused into tacc + self term -----------------
__global__ void __launch_bounds__(256) k_spmv3(const __half* __restrict__ src, float* __restrict__ tacc,
                                               const int2* __restrict__ moffs, const int* __restrict__ cols,
                                               const float* __restrict__ dinv, const float* __restrict__ gsc,
                                               const int* __restrict__ uids, const int* __restrict__ iids) {
    int tid = threadIdx.x, lane = tid & 63;
    int t = blockIdx.x * 4 + (tid >> 6);
    if (t >= 2048) return;
    int r = (t < BATCH) ? uids[t] : (N_USER + iids[t - BATCH]);
    int2 se = moffs[r];
    int s = se.x, e = se.y;
    int p = lane & 31, ep = lane >> 5;
    const char* sb = (const char*)src + (p << 2);
    float ax = 0.f, ay = 0.f;
    int j0 = s;
    for (; j0 + 16 <= e; j0 += 16) {
        int c[8];
        #pragma unroll
        for (int u = 0; u < 8; ++u) c[u] = cols[j0 + 2 * u + ep];
        float2 v[8];
        #pragma unroll
        for (int u = 0; u < 8; ++u) v[u] = __half22float2(*(const __half2*)(sb + (size_t)(unsigned)c[u]));
        #pragma unroll
        for (int u = 0; u < 8; ++u) { ax += v[u].x; ay += v[u].y; }
    }
    if (j0 < e) {
        int c[8]; float w[8];
        #pragma unroll
        for (int u = 0; u < 8; ++u) {
            int j = j0 + 2 * u + ep;
            c[u] = cols[min(j, e - 1)];
            w[u] = (j < e) ? 1.f : 0.f;
        }
        float2 v[8];
        #pragma unroll
        for (int u = 0; u < 8; ++u) v[u] = __half22float2(*(const __half2*)(sb + (size_t)(unsigned)c[u]));
        #pragma unroll
        for (int u = 0; u < 8; ++u) { ax = fmaf(w[u], v[u].x, ax); ay = fmaf(w[u], v[u].y, ay); }
    }
    ax += __shfl_xor(ax, 32);
    ay += __shfl_xor(ay, 32);
    if (ep == 0) {
        float2 self = __half22float2(*(const __half2*)((const char*)src + ((size_t)r << 7) + (p << 2)));
        float di = dinv[r], g = gsc[r];
        float* tp = tacc + (size_t)t * 64 + (p << 1);
        tp[0] += di * ax + g * self.x;
        tp[1] += di * ay + g * self.y;
    }
}

// ---------------- fused X-assembly + MLP -----------------------------------
__global__ void __launch_bounds__(256) k_mlp(const int* __restrict__ aux,
                                             const float* __restrict__ ratef, const float* __restrict__ genderf,
                                             const float* __restrict__ agef, const float* __restrict__ occf,
                                             const float* __restrict__ areaf, const float* __restrict__ tacc,
                                             const float* __restrict__ Xmh, const float* __restrict__ cntf,
                                             const float* __restrict__ W1, const float* __restrict__ b1,
                                             const float* __restrict__ W2, const float* __restrict__ b2,
                                             const float* __restrict__ Wo, const float* __restrict__ bo,
                                             void* __restrict__ out, const void* probe) {
    __shared__ float sx[4][640];
    __shared__ float sh[4][64];
    int isf32 = detect_f32(probe);
    int lane = threadIdx.x & 63, w = threadIdx.x >> 6;
    int b = blockIdx.x * 4 + w;
    const int* arow = aux + (size_t)b * AUX_W;
    float* xr = sx[w];
    xr[0   + lane] = ratef[arow[0] * 64 + lane];
    xr[64  + lane] = Xmh[((size_t)0 * BATCH + b) * 64 + lane] / cntf[0 * BATCH + b];
    xr[128 + lane] = Xmh[((size_t)1 * BATCH + b) * 64 + lane] / cntf[1 * BATCH + b];
    xr[192 + lane] = Xmh[((size_t)2 * BATCH + b) * 64 + lane] / cntf[2 * BATCH + b];
    xr[256 + lane] = genderf[arow[10242] * 64 + lane];
    xr[320 + lane] = agef[arow[10243] * 64 + lane];
    xr[384 + lane] = occf[arow[10244] * 64 + lane];
    xr[448 + lane] = areaf[arow[10245] * 64 + lane];
    xr[512 + lane] = tacc[(size_t)b * 64 + lane] * 0.25f;
    xr[576 + lane] = tacc[(size_t)(BATCH + b) * 64 + lane] * 0.25f;
    float acc = b1[lane];
    #pragma unroll 8
    for (int k = 0; k < 640; ++k) acc += xr[k] * W1[(size_t)k * 64 + lane];
    float h1 = fmaxf(acc, 0.f);
    sh[w][lane] = h1;
    float acc2 = b2[lane];
    #pragma unroll 8
    for (int j = 0; j < 64; ++j) acc2 += sh[w][j] * W2[(size_t)j * 64 + lane];
    float h2 = fmaxf(acc2, 0.f);
    float p = h2 * Wo[lane];
    #pragma unroll
    for (int off = 32; off; off >>= 1) p += __shfl_down(p, off);
    if (lane == 0) {
        float r = p + bo[0];
        if (isf32) ((float*)out)[b] = r;
        else       ((__hip_bfloat16*)out)[b] = __float2bfloat16(r);
    }
}

extern "C" void kernel_launch(void* const* d_in, const int* in_sizes, int n_in,
                              void* d_out, int out_size, void* d_ws, size_t ws_size,
                              hipStream_t stream) {
    const int* aux  = (const int*)d_in[0];
    const int* uids = (const int*)d_in[1];
    const int* iids = (const int*)d_in[2];
    const int* grow = (const int*)d_in[3];
    const int* gcol = (const int*)d_in[4];

    char* p = (char*)d_ws;
    auto alloc = [&](size_t bytes) -> char* {
        char* r = p;
        p += (bytes + 255) / 256 * 256;
        return r;
    };
    // zero-region (one hipMemsetAsync): bucket_tot, Xmh, cntf, moffs2
    int*   bucket_tot  = (int*)alloc(512 * 4);
    float* Xmh         = (float*)alloc((size_t)3 * BATCH * 64 * 4);
    float* cntf        = (float*)alloc((size_t)3 * BATCH * 4);
    int2*  moffs2      = (int2*)alloc((size_t)180224 * 8);
    char*  zero_end    = p;
    int*   bucket_base = (int*)alloc(512 * 4);
    int*   bucketcur   = (int*)alloc(512 * 4);
    int2*  moffs       = (int2*)alloc((size_t)180224 * 8);
    float* dinv        = (float*)alloc((size_t)180224 * 4);
    float* dsq         = (float*)alloc((size_t)180224 * 4);
    float* gsc         = (float*)alloc((size_t)180224 * 4);
    int2*  binned      = (int2*)alloc((size_t)E2 * 8);
    int*   cols        = (int*)alloc((size_t)E2 * 4);
    __half* embA       = (__half*)alloc((size_t)N_NODES * 64 * 2);
    __half* embB       = (__half*)alloc((size_t)N_NODES * 64 * 2);
    float* tacc        = (float*)alloc((size_t)2048 * 64 * 4);
    unsigned short* WtG = (unsigned short*)alloc((size_t)KP_G * 64 * 2);
    unsigned short* WtD = (unsigned short*)alloc((size_t)KP_D * 64 * 2);
    unsigned short* WtA = (unsigned short*)alloc((size_t)KP_A * 64 * 2);
    float* ratef   = (float*)alloc(384 * 4);
    float* genderf = (float*)alloc(128 * 4);
    float* agef    = (float*)alloc(448 * 4);
    float* occf    = (float*)alloc(1344 * 4);
    float* areaf   = (float*)alloc((size_t)217728 * 4);
    float* fc1W    = (float*)alloc((size_t)40960 * 4);
    float* fc1b    = (float*)alloc(64 * 4);
    float* fc2W    = (float*)alloc(4096 * 4);
    float* fc2b    = (float*)alloc(64 * 4);
    float* outW    = (float*)alloc(64 * 4);
    float* outb    = (float*)alloc(4);

    const void* probe = d_in[14];   // user_rel, for inline dtype detect

    // 0. zero accumulators (single contiguous region, DMA)
    hipMemsetAsync(bucket_tot, 0, (size_t)(zero_end - (char*)bucket_tot), stream);

    // 1. fused prep: table cvt + Wt pack + bucket counts
    CvtBatch cb;
    int blk = 0, si = 0;
    auto addseg = [&](const void* s, float* d, int n) {
        cb.seg[si].src = s; cb.seg[si].dst = d; cb.seg[si].n = n; cb.seg[si].blk0 = blk;
        blk += (n + 255) / 256; ++si;
    };
    addseg(d_in[6],  ratef,   384);
    addseg(d_in[10], genderf, 128);
    addseg(d_in[11], agef,    448);
    addseg(d_in[12], occf,    1344);
    addseg(d_in[13], areaf,   217728);
    addseg(d_in[16], fc1W,   40960);
    addseg(d_in[17], fc1b,   64);
    addseg(d_in[18], fc2W,   4096);
    addseg(d_in[19], fc2b,   64);
    addseg(d_in[20], outW,   64);
    addseg(d_in[21], outb,   1);
    for (int i = si; i < 16; ++i) { cb.seg[i].src = nullptr; cb.seg[i].dst = nullptr; cb.seg[i].n = 0; cb.seg[i].blk0 = 0x7fffffff; }
    const int cvtBlks = blk;
    hipLaunchKernelGGL(k_prep, dim3(cvtBlks + WT_BLKS + BCNT_BLKS), dim3(256), 0, stream,
                       cb, cvtBlks, d_in[7], d_in[8], d_in[9], WtG, WtD, WtA, grow, bucket_tot, probe);

    // 2. CSR build
    hipLaunchKernelGGL(k_bscan, dim3(1), dim3(512), 0, stream, bucket_tot, bucket_base, bucketcur);
    hipLaunchKernelGGL(k_p1, dim3((E2 + 4095) / 4096), dim3(256), 0, stream, grow, gcol, bucketcur, binned);
    hipLaunchKernelGGL(k_p2, dim3(NBKT), dim3(256), 0, stream, binned, bucket_base, cols, moffs, dinv, dsq, gsc);

    // 3. fused (long-pole-first): mhgemm + mark + tacc0 + emb cvt
    const int cvtN = (N_NODES * 16 + 255) / 256;
    hipLaunchKernelGGL(k_cvt_fused, dim3(1376 + cvtN), dim3(256), 0, stream,
                       d_in[14], d_in[15], dinv, embA, tacc, uids, iids, cvtN,
                       moffs, cols, moffs2, aux, WtG, WtD, WtA, Xmh, cntf);

    // 4. LightGCN: L1 unmasked; L2 via moffs2 (+fused tacc f1); L3 at T (+self)
    const int spmvN = (N_NODES + 3) / 4;
    hipLaunchKernelGGL(k_spmv, dim3(spmvN), dim3(256), 0, stream,
                       embA, embB, moffs, cols, dsq, spmvN, (float*)nullptr, uids, iids, gsc);
    hipLaunchKernelGGL(k_spmv, dim3(spmvN + 512), dim3(256), 0, stream,
                       embB, embA, moffs2, cols, dsq, spmvN, tacc, uids, iids, gsc);
    hipLaunchKernelGGL(k_spmv3, dim3(2048 / 4), dim3(256), 0, stream,
                       embA, tacc, moffs, cols, dinv, gsc, uids, iids);

    // 5. fused X+MLP -> out
    hipLaunchKernelGGL(k_mlp, dim3(BATCH / 4), dim3(256), 0, stream,
                       aux, ratef, genderf, agef, occf, areaf, tacc, Xmh, cntf,
                       fc1W, fc1b, fc2W, fc2b, outW, outb, d_out, probe);
}